// Round 1
// baseline (13141.241 us; speedup 1.0000x reference)
//
#include <hip/hip_runtime.h>
#include <math.h>

// Problem constants (fixed by setup_inputs)
#define NN   32
#define SS   3200
#define CC   16
#define LDA  17      // padded row stride for 16x16 LDS tiles
#define MSTR 272     // 16*LDA floats per matrix slot
#define D0   136     // C*(C+1)/2
#define DD   152     // D0 + k
#define SQRT2F 1.41421356237309515f

// ---------------- 16x16 symmetric Jacobi eigh, 16 threads/matrix, LDS ----------------
// A: 16x16 in LDS (LDA-padded). On exit: diag(A)=eigenvalues, V columns = eigenvectors.
template<int SWEEPS>
__device__ __forceinline__ void jacobi16(float* __restrict__ A, float* __restrict__ V, int lane) {
  for (int r = 0; r < CC; ++r) V[r*LDA + lane] = (r == lane) ? 1.f : 0.f;
  __syncthreads();
  for (int sw = 0; sw < SWEEPS; ++sw) {
    for (int p = 0; p < CC-1; ++p) {
      for (int q = p+1; q < CC; ++q) {
        float app = A[p*LDA+p];
        float apq = A[p*LDA+q];
        float aqq = A[q*LDA+q];
        float a_pi = A[p*LDA+lane];
        float a_qi = A[q*LDA+lane];
        float vp = V[lane*LDA+p];
        float vq = V[lane*LDA+q];
        float theta = (aqq - app) / (2.f * apq);
        float t = copysignf(1.f, theta) / (fabsf(theta) + sqrtf(1.f + theta*theta));
        t = (apq == 0.f) ? 0.f : t;
        float cs = rsqrtf(1.f + t*t);
        float sn = t * cs;
        float npi = cs*a_pi - sn*a_qi;
        float nqi = sn*a_pi + cs*a_qi;
        if (lane == p) { npi = app - t*apq; nqi = 0.f; }
        if (lane == q) { npi = 0.f;         nqi = aqq + t*apq; }
        float nvp = cs*vp - sn*vq;
        float nvq = sn*vp + cs*vq;
        __syncthreads();
        A[p*LDA+lane] = npi;
        A[q*LDA+lane] = nqi;
        A[lane*LDA+p] = npi;
        A[lane*LDA+q] = nqi;
        V[lane*LDA+p] = nvp;
        V[lane*LDA+q] = nvq;
        __syncthreads();
      }
    }
  }
}

// column c of (M * A * M), M and A in LDS (LDA padded)
__device__ __forceinline__ void sandwich_col(const float* __restrict__ M, const float* __restrict__ A,
                                             int c, float* __restrict__ out) {
  float mcol[CC];
  #pragma unroll
  for (int k = 0; k < CC; ++k) mcol[k] = M[k*LDA+c];
  float t1[CC];
  #pragma unroll
  for (int r = 0; r < CC; ++r) {
    float s = 0.f;
    #pragma unroll
    for (int k = 0; k < CC; ++k) s += A[r*LDA+k] * mcol[k];
    t1[r] = s;
  }
  #pragma unroll
  for (int r = 0; r < CC; ++r) {
    float s = 0.f;
    #pragma unroll
    for (int k = 0; k < CC; ++k) s += M[r*LDA+k] * t1[k];
    out[r] = s;
  }
}

// column c of V diag(f) V^T  (f in LDS, 16 entries)
__device__ __forceinline__ void recon_col(const float* __restrict__ V, const float* __restrict__ f,
                                          int c, float* __restrict__ out) {
  float myV[CC];
  #pragma unroll
  for (int k = 0; k < CC; ++k) myV[k] = V[c*LDA+k];
  #pragma unroll
  for (int r = 0; r < CC; ++r) out[r] = 0.f;
  #pragma unroll
  for (int k = 0; k < CC; ++k) {
    float coef = f[k] * myV[k];
    #pragma unroll
    for (int r = 0; r < CC; ++r) out[r] += coef * V[r*LDA+k];
  }
}

// two reconstructions sharing the V reads
__device__ __forceinline__ void recon2_col(const float* __restrict__ V, const float* __restrict__ f1,
                                           const float* __restrict__ f2, int c,
                                           float* __restrict__ o1, float* __restrict__ o2) {
  float myV[CC];
  #pragma unroll
  for (int k = 0; k < CC; ++k) myV[k] = V[c*LDA+k];
  #pragma unroll
  for (int r = 0; r < CC; ++r) { o1[r] = 0.f; o2[r] = 0.f; }
  #pragma unroll
  for (int k = 0; k < CC; ++k) {
    float c1 = f1[k] * myV[k];
    float c2 = f2[k] * myV[k];
    #pragma unroll
    for (int r = 0; r < CC; ++r) { float vr = V[r*LDA+k]; o1[r] += c1*vr; o2[r] += c2*vr; }
  }
}

// ---------------- Step 1: rm accumulation ----------------
__global__ __launch_bounds__(256) void rm_mean_kernel(const float* __restrict__ x, float* __restrict__ rmsum) {
  int n = blockIdx.y;
  long base = ((long)n*SS + (long)blockIdx.x*400) * 256;
  int tid = threadIdx.x;
  float s = 0.f;
  for (int i = 0; i < 400; ++i) s += x[base + (long)i*256 + tid];
  atomicAdd(&rmsum[n*256 + tid], s);
}

// ---------------- Step 2: eigh(rm) -> sq_rm,isq_rm ; eigh(sym(W)) -> Wsq ----------------
__global__ __launch_bounds__(256) void eigh_rm_kernel(const float* __restrict__ rmsum, const float* __restrict__ W,
                                                      float* __restrict__ sqrm, float* __restrict__ isqrm,
                                                      float* __restrict__ wsqo) {
  __shared__ float Ab[16*MSTR];
  __shared__ float Vb[16*MSTR];
  __shared__ float fb1[16*CC];
  __shared__ float fb2[16*CC];
  int tid = threadIdx.x;
  int m = tid >> 4, c = tid & 15;
  int gid_raw = blockIdx.x*16 + m;
  int gid = gid_raw > 32 ? 32 : gid_raw;
  float* A = Ab + m*MSTR;
  float* V = Vb + m*MSTR;
  if (gid < 32) {
    #pragma unroll
    for (int r = 0; r < CC; ++r) A[r*LDA+c] = rmsum[gid*256 + r*16 + c] * (1.f/(float)SS);
  } else {
    #pragma unroll
    for (int r = 0; r < CC; ++r) A[r*LDA+c] = 0.5f*(W[r*16+c] + W[c*16+r]);
  }
  __syncthreads();
  jacobi16<10>(A, V, c);
  {
    float wv = A[c*LDA+c];
    if (gid < 32) {
      float sq = sqrtf(fmaxf(wv, 1e-10f));
      fb1[m*CC+c] = sq;
      fb2[m*CC+c] = 1.f/sq;
    } else {
      fb1[m*CC+c] = expf(0.5f*wv);   // Wsq = expm(sym(W)/2)
      fb2[m*CC+c] = 0.f;
    }
  }
  __syncthreads();
  float o1[CC], o2[CC];
  recon2_col(V, fb1+m*CC, fb2+m*CC, c, o1, o2);
  if (gid_raw < 32) {
    #pragma unroll
    for (int r = 0; r < CC; ++r) { sqrm[gid*256 + r*16 + c] = o1[r]; isqrm[gid*256 + r*16 + c] = o2[r]; }
  } else if (gid_raw == 32) {
    #pragma unroll
    for (int r = 0; r < CC; ++r) wsqo[r*16+c] = o1[r];
  }
}

// ---------------- Step 3: pass 1 — sum_s logm(isq_rm X isq_rm) ----------------
__global__ __launch_bounds__(256) void pass1_kernel(const float* __restrict__ x, const float* __restrict__ isqrm,
                                                    float* __restrict__ gtsum) {
  __shared__ float Ab[16*MSTR];
  __shared__ float Vb[16*MSTR];
  __shared__ float ISQ[MSTR];
  __shared__ float lwb[16*CC];
  int tid = threadIdx.x;
  int m = tid >> 4, c = tid & 15;
  int n = blockIdx.y;
  int s0 = blockIdx.x * 16;
  { int r = tid >> 4, cc = tid & 15; ISQ[r*LDA+cc] = isqrm[n*256 + tid]; (void)r; (void)cc; }
  long g0 = ((long)n*SS + s0) * 256;
  for (int i = 0; i < 16; ++i) {
    int idx = tid + i*256;
    int mm = idx >> 8, rr = (idx >> 4) & 15, cc2 = idx & 15;
    Ab[mm*MSTR + rr*LDA + cc2] = x[g0 + idx];
  }
  __syncthreads();
  float* A = Ab + m*MSTR;
  float* V = Vb + m*MSTR;
  float q[CC];
  sandwich_col(ISQ, A, c, q);
  __syncthreads();
  #pragma unroll
  for (int r = 0; r < CC; ++r) A[r*LDA+c] = q[r];
  __syncthreads();
  jacobi16<7>(A, V, c);
  lwb[m*CC+c] = logf(fmaxf(A[c*LDA+c], 1e-10f));
  __syncthreads();
  float acc[CC];
  recon_col(V, lwb + m*CC, c, acc);
  __syncthreads();
  #pragma unroll
  for (int r = 0; r < CC; ++r) A[r*LDA+c] = acc[r];
  __syncthreads();
  for (int off = 8; off >= 1; off >>= 1) {
    if (m < off) {
      #pragma unroll
      for (int r = 0; r < CC; ++r) Ab[m*MSTR + r*LDA + c] += Ab[(m+off)*MSTR + r*LDA + c];
    }
    __syncthreads();
  }
  if (m == 0) {
    #pragma unroll
    for (int r = 0; r < CC; ++r) atomicAdd(&gtsum[n*256 + r*16 + c], Ab[r*LDA + c]);
  }
}

// ---------------- Step 4: x_mean chain -> isq_m, lt_mean ----------------
__global__ __launch_bounds__(256) void mean_update_kernel(const float* __restrict__ gtsum, const float* __restrict__ sqrm,
                                                          float* __restrict__ isqm, float* __restrict__ ltmean) {
  __shared__ float Ab[16*MSTR];
  __shared__ float Vb[16*MSTR];
  __shared__ float SQb[16*MSTR];
  __shared__ float fb[16*CC];
  int tid = threadIdx.x;
  int m = tid >> 4, c = tid & 15;
  int n = blockIdx.x*16 + m;
  float* A  = Ab  + m*MSTR;
  float* V  = Vb  + m*MSTR;
  float* SQ = SQb + m*MSTR;
  #pragma unroll
  for (int r = 0; r < CC; ++r) {
    A[r*LDA+c]  = gtsum[n*256 + r*16 + c] * (1.f/(float)SS);
    SQ[r*LDA+c] = sqrm[n*256 + r*16 + c];
  }
  __syncthreads();
  jacobi16<10>(A, V, c);           // eigh(gt_mean)
  fb[m*CC+c] = expf(A[c*LDA+c]);
  __syncthreads();
  float e1[CC];
  recon_col(V, fb+m*CC, c, e1);    // expm(gt_mean)
  __syncthreads();
  #pragma unroll
  for (int r = 0; r < CC; ++r) A[r*LDA+c] = e1[r];
  __syncthreads();
  float xm[CC];
  sandwich_col(SQ, A, c, xm);      // x_mean = sq_rm expm sq_rm
  __syncthreads();
  #pragma unroll
  for (int r = 0; r < CC; ++r) A[r*LDA+c] = xm[r];
  __syncthreads();
  jacobi16<10>(A, V, c);           // eigh(x_mean)
  float wv = fmaxf(A[c*LDA+c], 1e-10f);
  fb[m*CC+c] = 1.f/sqrtf(wv);
  __syncthreads();
  float isq_[CC];
  recon_col(V, fb+m*CC, c, isq_);
  #pragma unroll
  for (int r = 0; r < CC; ++r) isqm[n*256 + r*16 + c] = isq_[r];
  __syncthreads();
  fb[m*CC+c] = logf(wv);
  __syncthreads();
  float lg[CC];
  recon_col(V, fb+m*CC, c, lg);    // logm(x_mean)
  #pragma unroll
  for (int r = 0; r < CC; ++r) {
    if (r >= c) ltmean[n*D0 + (r*(r+1)/2) + c] = lg[r] * ((r == c) ? 1.f : SQRT2F);
  }
}

// ---------------- Step 5: pass 2 — xc = tril(Wsq logm(isq_m X isq_m) Wsq) ----------------
__global__ __launch_bounds__(256) void pass2_kernel(const float* __restrict__ x, const float* __restrict__ isqm,
                                                    const float* __restrict__ wsqi, float* __restrict__ xc) {
  __shared__ float Ab[16*MSTR];
  __shared__ float Vb[16*MSTR];
  __shared__ float ISQ[MSTR];
  __shared__ float WSQ[MSTR];
  __shared__ float lwb[16*CC];
  int tid = threadIdx.x;
  int m = tid >> 4, c = tid & 15;
  int n = blockIdx.y;
  int s0 = blockIdx.x * 16;
  { int r = tid >> 4, cc = tid & 15; ISQ[r*LDA+cc] = isqm[n*256 + tid]; WSQ[r*LDA+cc] = wsqi[tid]; }
  long g0 = ((long)n*SS + s0) * 256;
  for (int i = 0; i < 16; ++i) {
    int idx = tid + i*256;
    int mm = idx >> 8, rr = (idx >> 4) & 15, cc2 = idx & 15;
    Ab[mm*MSTR + rr*LDA + cc2] = x[g0 + idx];
  }
  __syncthreads();
  float* A = Ab + m*MSTR;
  float* V = Vb + m*MSTR;
  float q[CC];
  sandwich_col(ISQ, A, c, q);
  __syncthreads();
  #pragma unroll
  for (int r = 0; r < CC; ++r) A[r*LDA+c] = q[r];
  __syncthreads();
  jacobi16<7>(A, V, c);
  lwb[m*CC+c] = logf(fmaxf(A[c*LDA+c], 1e-10f));
  __syncthreads();
  float acc[CC];
  recon_col(V, lwb + m*CC, c, acc);
  __syncthreads();
  #pragma unroll
  for (int r = 0; r < CC; ++r) A[r*LDA+c] = acc[r];
  __syncthreads();
  float y[CC];
  sandwich_col(WSQ, A, c, y);
  __syncthreads();
  #pragma unroll
  for (int r = 0; r < CC; ++r) {
    if (r >= c) Vb[m*MSTR + (r*(r+1)/2) + c] = y[r] * ((r == c) ? 1.f : SQRT2F);
  }
  __syncthreads();
  long ob = ((long)n*SS + s0) * (long)D0;
  for (int idx = tid; idx < 16*D0; idx += 256) {
    xc[ob + idx] = Vb[(idx/D0)*MSTR + (idx % D0)];
  }
}

// ---------------- Step 6: covariance SYRK ----------------
__global__ __launch_bounds__(256) void syrk_kernel(const float* __restrict__ xc, float* __restrict__ cov) {
  __shared__ float Ap[32][33];
  __shared__ float Bp[32][33];
  int n = blockIdx.y;
  int ti = blockIdx.x / 5, tj = blockIdx.x % 5;
  int tid = threadIdx.x;
  int tx = tid & 15, ty = tid >> 4;
  float a00 = 0.f, a01 = 0.f, a10 = 0.f, a11 = 0.f;
  const float* xb = xc + (long)n*SS*D0;
  for (int s0 = 0; s0 < SS; s0 += 32) {
    for (int l = tid; l < 1024; l += 256) {
      int ss = l >> 5, ii = l & 31;
      int gi = ti*32 + ii, gj = tj*32 + ii;
      const float* row = xb + (long)(s0+ss)*D0;
      Ap[ss][ii] = (gi < D0) ? row[gi] : 0.f;
      Bp[ss][ii] = (gj < D0) ? row[gj] : 0.f;
    }
    __syncthreads();
    #pragma unroll 8
    for (int ss = 0; ss < 32; ++ss) {
      float x0 = Ap[ss][2*ty], x1 = Ap[ss][2*ty+1];
      float y0 = Bp[ss][2*tx], y1 = Bp[ss][2*tx+1];
      a00 += x0*y0; a01 += x0*y1; a10 += x1*y0; a11 += x1*y1;
    }
    __syncthreads();
  }
  int i0 = ti*32 + 2*ty, j0 = tj*32 + 2*tx;
  const float sc = 1.f/(float)(SS - 1);
  long base = (long)n*D0*D0;
  if (i0   < D0 && j0   < D0) cov[base + (long)i0*D0 + j0]       = a00*sc;
  if (i0   < D0 && j0+1 < D0) cov[base + (long)i0*D0 + j0+1]     = a01*sc;
  if (i0+1 < D0 && j0   < D0) cov[base + (long)(i0+1)*D0 + j0]   = a10*sc;
  if (i0+1 < D0 && j0+1 < D0) cov[base + (long)(i0+1)*D0 + j0+1] = a11*sc;
}

// ---------------- Step 7: assemble E skeleton ----------------
__global__ __launch_bounds__(256) void ebuild_kernel(const float* __restrict__ ltmean, float* __restrict__ E) {
  int n = blockIdx.x;
  for (int idx = threadIdx.x; idx < DD*DD; idx += 256) {
    int r = idx / DD, c = idx % DD;
    float v = 0.f;
    if (r >= D0) {
      if (c < D0) v = ltmean[n*D0 + c];
      else        v = (r == c) ? 1.f : 0.f;
    }
    E[(long)n*DD*DD + idx] = v;
  }
}

// ---------------- Cholesky (triangular LDS storage) ----------------
template<int D, int NORM, int WRITE_UPPER>
__global__ __launch_bounds__(256) void chol_kernel(const float* __restrict__ in, long inStride,
                                                   float* __restrict__ out, long outStride, int outLd) {
  __shared__ float As[D*(D+1)/2];
  __shared__ float red[256];
  int b = blockIdx.x;
  int tid = threadIdx.x;
  const float* inp = in + (long)b*inStride;
  for (int idx = tid; idx < D*D; idx += 256) {
    int r = idx / D, c2 = idx % D;
    if (c2 <= r) As[(r*(r+1)/2) + c2] = inp[idx];
  }
  __syncthreads();
  if (NORM) {
    float p = 0.f;
    for (int i = tid; i < D; i += 256) p += As[(i*(i+1)/2)+i];
    red[tid] = p;
    __syncthreads();
    for (int off = 128; off >= 1; off >>= 1) {
      if (tid < off) red[tid] += red[tid+off];
      __syncthreads();
    }
    float inv = 1.f / red[0];
    for (int idx = tid; idx < D*(D+1)/2; idx += 256) As[idx] *= inv;
    __syncthreads();
    for (int i = tid; i < D; i += 256) As[(i*(i+1)/2)+i] += 1e-5f;
    __syncthreads();
  }
  int tx = tid & 15, ty = tid >> 4;
  for (int k = 0; k < D; ++k) {
    float dkk = As[(k*(k+1)/2)+k];
    float d = sqrtf(dkk);
    float invd = 1.f/d;
    __syncthreads();
    for (int i = k+1+tid; i < D; i += 256) As[(i*(i+1)/2)+k] *= invd;
    if (tid == 0) As[(k*(k+1)/2)+k] = d;
    __syncthreads();
    for (int i = k+1+ty; i < D; i += 16) {
      float aik = As[(i*(i+1)/2)+k];
      int ibase = i*(i+1)/2;
      for (int j = k+1+tx; j <= i; j += 16) {
        As[ibase+j] -= aik * As[(j*(j+1)/2)+k];
      }
    }
    __syncthreads();
  }
  float* op = out + (long)b*outStride;
  for (int idx = tid; idx < D*D; idx += 256) {
    int r = idx / D, c2 = idx % D;
    if (c2 <= r)          op[r*outLd + c2] = As[(r*(r+1)/2)+c2];
    else if (WRITE_UPPER) op[r*outLd + c2] = 0.f;
  }
}

// ---------------- generic 152x152 GEMM: C = alpha*A@B (+I) ----------------
__global__ __launch_bounds__(256) void gemm152_kernel(const float* __restrict__ A, long sA,
                                                      const float* __restrict__ B, float* __restrict__ Cm,
                                                      long sC, float alpha, int addI) {
  __shared__ float As[16][17];
  __shared__ float Bs[16][17];
  int b = blockIdx.y;
  const float* Ab_ = A + (long)b*sA;
  float* Cb = Cm + (long)b*sC;
  int tid = threadIdx.x;
  int tx = tid & 15, ty = tid >> 4;
  int row0 = (blockIdx.x / 10) * 16, col0 = (blockIdx.x % 10) * 16;
  float acc = 0.f;
  for (int k0 = 0; k0 < DD; k0 += 16) {
    int ar = row0 + ty, ac = k0 + tx;
    As[ty][tx] = (ar < DD && ac < DD) ? Ab_[ar*DD + ac] : 0.f;
    int br = k0 + ty, bc = col0 + tx;
    Bs[ty][tx] = (br < DD && bc < DD) ? B[br*DD + bc] : 0.f;
    __syncthreads();
    #pragma unroll
    for (int kk = 0; kk < 16; ++kk) acc += As[ty][kk] * Bs[kk][tx];
    __syncthreads();
  }
  int r = row0 + ty, c2 = col0 + tx;
  if (r < DD && c2 < DD) Cb[r*DD + c2] = alpha*acc + ((addI && r == c2) ? 1.f : 0.f);
}

__global__ __launch_bounds__(256) void wlw_prep_kernel(const float* __restrict__ Wlw, float* __restrict__ Bm) {
  int idx = blockIdx.x*256 + threadIdx.x;
  if (idx < DD*DD) {
    int r = idx / DD, c = idx % DD;
    Bm[idx] = 0.5f*(Wlw[idx] + Wlw[c*DD + r]) * (1.f/16.f);
  }
}

__global__ __launch_bounds__(256) void taylor_init_kernel(const float* __restrict__ Bm, float* __restrict__ P) {
  int idx = blockIdx.x*256 + threadIdx.x;
  if (idx < DD*DD) {
    int r = idx / DD, c = idx % DD;
    P[idx] = Bm[idx]*(1.f/8.f) + ((r == c) ? 1.f : 0.f);
  }
}

extern "C" void kernel_launch(void* const* d_in, const int* in_sizes, int n_in,
                              void* d_out, int out_size, void* d_ws, size_t ws_size,
                              hipStream_t stream) {
  (void)in_sizes; (void)n_in; (void)out_size; (void)ws_size;
  const float* x   = (const float*)d_in[0];
  const float* W   = (const float*)d_in[1];
  const float* Wlw = (const float*)d_in[2];
  float* ws = (float*)d_ws;
  size_t off = 0;
  float* rmsum  = ws + off; off += 32*256;
  float* gtsum  = ws + off; off += 32*256;
  float* sqrm   = ws + off; off += 32*256;
  float* isqrm  = ws + off; off += 32*256;
  float* wsqb   = ws + off; off += 256;
  float* isqm   = ws + off; off += 32*256;
  float* ltmean = ws + off; off += 32*D0;
  float* cov    = ws + off; off += (size_t)32*D0*D0;
  float* E      = ws + off; off += (size_t)32*DD*DD;
  float* Bm     = ws + off; off += DD*DD;
  float* Pa     = ws + off; off += DD*DD;
  float* Pb     = ws + off; off += DD*DD;
  float* Rm     = ws + off; off += DD*DD;
  float* xcbuf  = ws + off; off += (size_t)32*SS*D0;   // ~55.7 MB; total ws use ~62 MB
  float* outp   = (float*)d_out;

  // zero the two atomic accumulators (rmsum+gtsum are contiguous)
  hipMemsetAsync(rmsum, 0, 2*32*256*sizeof(float), stream);

  rm_mean_kernel   <<<dim3(8,32),   256, 0, stream>>>(x, rmsum);
  eigh_rm_kernel   <<<3,            256, 0, stream>>>(rmsum, W, sqrm, isqrm, wsqb);
  pass1_kernel     <<<dim3(200,32), 256, 0, stream>>>(x, isqrm, gtsum);
  mean_update_kernel<<<2,           256, 0, stream>>>(gtsum, sqrm, isqm, ltmean);
  pass2_kernel     <<<dim3(200,32), 256, 0, stream>>>(x, isqm, wsqb, xcbuf);
  syrk_kernel      <<<dim3(25,32),  256, 0, stream>>>(xcbuf, cov);
  ebuild_kernel    <<<32,           256, 0, stream>>>(ltmean, E);
  chol_kernel<D0,1,0><<<32,         256, 0, stream>>>(cov, (long)D0*D0, E, (long)DD*DD, DD);

  // R = chol(expm(sym(W_lw))) via scaling-squaring Taylor (scale 1/16, order 8, square 4x)
  wlw_prep_kernel   <<<(DD*DD+255)/256, 256, 0, stream>>>(Wlw, Bm);
  taylor_init_kernel<<<(DD*DD+255)/256, 256, 0, stream>>>(Bm, Pa);
  float* Pcur = Pa; float* Pnext = Pb;
  for (int k = 7; k >= 1; --k) {
    gemm152_kernel<<<dim3(100,1), 256, 0, stream>>>(Bm, 0L, Pcur, Pnext, 0L, 1.f/(float)k, 1);
    float* t = Pcur; Pcur = Pnext; Pnext = t;
  }
  for (int i = 0; i < 4; ++i) {
    gemm152_kernel<<<dim3(100,1), 256, 0, stream>>>(Pcur, 0L, Pcur, Pnext, 0L, 1.f, 0);
    float* t = Pcur; Pcur = Pnext; Pnext = t;
  }
  chol_kernel<DD,0,1><<<1, 256, 0, stream>>>(Pcur, 0L, Rm, 0L, DD);

  // out = E @ R
  gemm152_kernel<<<dim3(100,32), 256, 0, stream>>>(E, (long)DD*DD, Rm, outp, (long)DD*DD, 1.f, 0);
}

// Round 2
// 2500.168 us; speedup vs baseline: 5.2561x; 5.2561x over previous
//
#include <hip/hip_runtime.h>
#include <math.h>

// Problem constants (fixed by setup_inputs)
#define NN   32
#define SS   3200
#define CC   16
#define RLDA 20      // padded row stride (floats) for b128-aligned LDS rows
#define D0   136     // C*(C+1)/2
#define DD   152     // D0 + k
#define SQRT2F 1.41421356237309515f
#define SW_PASS 8    // sweeps for the two big per-sample passes
#define SW_SMALL 10  // sweeps for the tiny per-n chains

// ---------------- cross-lane xor within 16-lane groups ----------------
// DPP for masks expressible as row ops (VALU pipe, no DS); ds_swizzle otherwise.
template<int M> __device__ __forceinline__ float lxor(float x) {
  int v = __float_as_int(x);
  int r;
  if      constexpr (M == 1)  r = __builtin_amdgcn_update_dpp(0, v, 0xB1, 0xF, 0xF, true);  // quad_perm [1,0,3,2]
  else if constexpr (M == 2)  r = __builtin_amdgcn_update_dpp(0, v, 0x4E, 0xF, 0xF, true);  // quad_perm [2,3,0,1]
  else if constexpr (M == 3)  r = __builtin_amdgcn_update_dpp(0, v, 0x1B, 0xF, 0xF, true);  // quad_perm [3,2,1,0]
  else if constexpr (M == 7)  r = __builtin_amdgcn_update_dpp(0, v, 0x141, 0xF, 0xF, true); // row_half_mirror
  else if constexpr (M == 8)  r = __builtin_amdgcn_update_dpp(0, v, 0x128, 0xF, 0xF, true); // row_ror:8
  else if constexpr (M == 15) r = __builtin_amdgcn_update_dpp(0, v, 0x140, 0xF, 0xF, true); // row_mirror
  else r = __builtin_amdgcn_ds_swizzle(v, 0x1F | (M << 10));                                // BitMode xor
  return __int_as_float(r);
}

// ---------------- one-sided Jacobi round: pairs (i, i^M) ----------------
template<int M>
__device__ __forceinline__ void js_round(float a[CC], float& d, int c) {
  float part[CC];
  #pragma unroll
  for (int r = 0; r < CC; ++r) part[r] = lxor<M>(a[r]);
  float pd = lxor<M>(d);
  float apq = a[0] * part[0];
  #pragma unroll
  for (int r = 1; r < CC; ++r) apq += a[r] * part[r];
  int partner = c ^ M;
  bool isp = c < partner;
  float app = isp ? d : pd;
  float aqq = isp ? pd : d;
  float theta = (aqq - app) * 0.5f * __builtin_amdgcn_rcpf(apq);
  float t = copysignf(__builtin_amdgcn_rcpf(fabsf(theta) + __builtin_amdgcn_sqrtf(1.f + theta * theta)), theta);
  t = (apq == 0.f) ? 0.f : t;
  float cs = __builtin_amdgcn_rsqf(1.f + t * t);
  float sn = t * cs;
  float se = isp ? -sn : sn;
  #pragma unroll
  for (int r = 0; r < CC; ++r) a[r] = cs * a[r] + se * part[r];
  d = isp ? (app - t * apq) : (aqq + t * apq);
}

__device__ __forceinline__ void js_sweep(float a[CC], float& d, int c) {
  js_round<1>(a, d, c);  js_round<2>(a, d, c);  js_round<3>(a, d, c);
  js_round<4>(a, d, c);  js_round<5>(a, d, c);  js_round<6>(a, d, c);
  js_round<7>(a, d, c);  js_round<8>(a, d, c);  js_round<9>(a, d, c);
  js_round<10>(a, d, c); js_round<11>(a, d, c); js_round<12>(a, d, c);
  js_round<13>(a, d, c); js_round<14>(a, d, c); js_round<15>(a, d, c);
}

// a: column c of symmetric M in registers. Exit: a = lam_c * v_c, d = lam_c^2 (exact).
__device__ __forceinline__ void jacobi_os(float a[CC], float& d, int c, int sweeps) {
  d = a[0] * a[0];
  #pragma unroll
  for (int r = 1; r < CC; ++r) d += a[r] * a[r];
  #pragma unroll 1
  for (int s = 0; s < sweeps; ++s) js_sweep(a, d, c);
  d = a[0] * a[0];
  #pragma unroll
  for (int r = 1; r < CC; ++r) d += a[r] * a[r];
}

// ---------------- y = Mat(16x16, LDS rows stride S) * v ----------------
template<int S>
__device__ __forceinline__ void mv_lds(const float* __restrict__ M, const float v[CC], float y[CC]) {
  #pragma unroll
  for (int r = 0; r < CC; ++r) {
    const float4 m0 = *(const float4*)(M + r * S + 0);
    const float4 m1 = *(const float4*)(M + r * S + 4);
    const float4 m2 = *(const float4*)(M + r * S + 8);
    const float4 m3 = *(const float4*)(M + r * S + 12);
    y[r] = m0.x * v[0] + m0.y * v[1] + m0.z * v[2] + m0.w * v[3]
         + m1.x * v[4] + m1.y * v[5] + m1.z * v[6] + m1.w * v[7]
         + m2.x * v[8] + m2.y * v[9] + m2.z * v[10] + m2.w * v[11]
         + m3.x * v[12] + m3.y * v[13] + m3.z * v[14] + m3.w * v[15];
  }
}

#define ACC16(out, coef, b0, b1, b2, b3)                                         \
  out[0] += coef * b0.x;  out[1] += coef * b0.y;  out[2] += coef * b0.z;  out[3] += coef * b0.w;  \
  out[4] += coef * b1.x;  out[5] += coef * b1.y;  out[6] += coef * b1.z;  out[7] += coef * b1.w;  \
  out[8] += coef * b2.x;  out[9] += coef * b2.y;  out[10] += coef * b2.z; out[11] += coef * b2.w; \
  out[12] += coef * b3.x; out[13] += coef * b3.y; out[14] += coef * b3.z; out[15] += coef * b3.w;

// out col c of  Sum_i gb[i] * b_i b_i^T ; B row i = b_i (stride 16)
__device__ __forceinline__ void recon16(const float* __restrict__ B, const float* __restrict__ gb,
                                        int c, float out[CC]) {
  #pragma unroll
  for (int r = 0; r < CC; ++r) out[r] = 0.f;
  #pragma unroll
  for (int i = 0; i < CC; ++i) {
    float coef = gb[i] * B[i * 16 + c];
    const float4 b0 = *(const float4*)(B + i * 16 + 0);
    const float4 b1 = *(const float4*)(B + i * 16 + 4);
    const float4 b2 = *(const float4*)(B + i * 16 + 8);
    const float4 b3 = *(const float4*)(B + i * 16 + 12);
    ACC16(out, coef, b0, b1, b2, b3)
  }
}

__device__ __forceinline__ void recon2_16(const float* __restrict__ B, const float* __restrict__ g1,
                                          const float* __restrict__ g2, int c,
                                          float o1[CC], float o2[CC]) {
  #pragma unroll
  for (int r = 0; r < CC; ++r) { o1[r] = 0.f; o2[r] = 0.f; }
  #pragma unroll
  for (int i = 0; i < CC; ++i) {
    float bic = B[i * 16 + c];
    float c1 = g1[i] * bic;
    float c2 = g2[i] * bic;
    const float4 b0 = *(const float4*)(B + i * 16 + 0);
    const float4 b1 = *(const float4*)(B + i * 16 + 4);
    const float4 b2 = *(const float4*)(B + i * 16 + 8);
    const float4 b3 = *(const float4*)(B + i * 16 + 12);
    ACC16(o1, c1, b0, b1, b2, b3)
    ACC16(o2, c2, b0, b1, b2, b3)
  }
}

// ---------------- Step 1: rm accumulation ----------------
__global__ __launch_bounds__(256) void rm_mean_kernel(const float* __restrict__ x, float* __restrict__ rmsum) {
  int n = blockIdx.y;
  long base = ((long)n * SS) * 256 + (long)blockIdx.x * 100 * 256;
  int tid = threadIdx.x;
  float s = 0.f;
  for (int i = 0; i < 100; ++i) s += x[base + (long)i * 256 + tid];
  atomicAdd(&rmsum[n * 256 + tid], s);
}

// ---------------- Step 2: eigh(rm) -> sq,isq ; Wsq = expm(sym(W)/2) ----------------
__global__ __launch_bounds__(256) void eigh_rm_kernel(const float* __restrict__ rmsum, const float* __restrict__ Wg,
                                                      float* __restrict__ sqrm, float* __restrict__ isqrm,
                                                      float* __restrict__ wsqo) {
  __shared__ __align__(16) float lds[4 * 1152];
  int tid = threadIdx.x;
  int wv = tid >> 6, lid = tid & 63, g = lid >> 4, c = lid & 15;
  float* Wr = lds + wv * 1152;
  float* RB = Wr;             // 4 x 256
  float* G1 = Wr + 1024;      // 64
  float* G2 = Wr + 1088;      // 64
  int gid_raw = blockIdx.x * 16 + wv * 4 + g;
  int gid = gid_raw > 32 ? 32 : gid_raw;
  float a[CC];
  if (gid < 32) {
    const float* src = rmsum + gid * 256;
    #pragma unroll
    for (int i = 0; i < 4; ++i) {
      float4 v = *(const float4*)(src + c * 16 + 4 * i);
      a[4 * i] = v.x * (1.f / SS); a[4 * i + 1] = v.y * (1.f / SS);
      a[4 * i + 2] = v.z * (1.f / SS); a[4 * i + 3] = v.w * (1.f / SS);
    }
  } else {
    #pragma unroll
    for (int r = 0; r < CC; ++r) a[r] = 0.5f * (Wg[c * 16 + r] + Wg[r * 16 + c]);
  }
  // Gershgorin shift (only used for the W matrix, which may be indefinite)
  float rs = fabsf(a[0]);
  #pragma unroll
  for (int r = 1; r < CC; ++r) rs += fabsf(a[r]);
  rs = fmaxf(rs, lxor<1>(rs)); rs = fmaxf(rs, lxor<2>(rs));
  rs = fmaxf(rs, lxor<4>(rs)); rs = fmaxf(rs, lxor<8>(rs));
  float sig = (gid == 32) ? (rs + 0.001f) : 0.f;
  #pragma unroll
  for (int r = 0; r < CC; ++r) a[r] += (r == c) ? sig : 0.f;
  float d;
  jacobi_os(a, d, c, SW_SMALL);
  float g1c, g2c;
  if (gid < 32) {
    float sqd = __builtin_amdgcn_sqrtf(d);
    float qd  = __builtin_amdgcn_sqrtf(sqd);            // d^{1/4}
    g1c = qd * __builtin_amdgcn_rcpf(d);                // d^{-3/4}: sqrtm
    g2c = __builtin_amdgcn_rcpf(d * qd);                // d^{-5/4}: invsqrtm
  } else {
    float lam = __builtin_amdgcn_sqrtf(d);
    g1c = __expf(0.5f * (lam - sig)) * __builtin_amdgcn_rcpf(fmaxf(d, 1e-30f));
    g2c = 0.f;
  }
  float* RBg = RB + g * 256;
  #pragma unroll
  for (int i = 0; i < 4; ++i)
    *(float4*)(RBg + c * 16 + 4 * i) = make_float4(a[4 * i], a[4 * i + 1], a[4 * i + 2], a[4 * i + 3]);
  G1[g * 16 + c] = g1c;
  G2[g * 16 + c] = g2c;
  __builtin_amdgcn_wave_barrier();
  float o1[CC], o2[CC];
  recon2_16(RBg, G1 + g * 16, G2 + g * 16, c, o1, o2);
  if (gid_raw < 32) {
    float* s1 = sqrm + gid * 256;
    float* s2 = isqrm + gid * 256;
    #pragma unroll
    for (int i = 0; i < 4; ++i) {
      *(float4*)(s1 + c * 16 + 4 * i) = make_float4(o1[4 * i], o1[4 * i + 1], o1[4 * i + 2], o1[4 * i + 3]);
      *(float4*)(s2 + c * 16 + 4 * i) = make_float4(o2[4 * i], o2[4 * i + 1], o2[4 * i + 2], o2[4 * i + 3]);
    }
  } else if (gid_raw == 32) {
    #pragma unroll
    for (int i = 0; i < 4; ++i)
      *(float4*)(wsqo + c * 16 + 4 * i) = make_float4(o1[4 * i], o1[4 * i + 1], o1[4 * i + 2], o1[4 * i + 3]);
  }
}

// ---------------- Step 3: pass 1 — sum_s logm(isq_rm X isq_rm) ----------------
__global__ __launch_bounds__(256) void pass1_kernel(const float* __restrict__ x, const float* __restrict__ isqrm,
                                                    float* __restrict__ gtsum) {
  __shared__ __align__(16) float lds[4 * 1408 + 1024];
  int tid = threadIdx.x;
  int wv = tid >> 6, lid = tid & 63, g = lid >> 4, c = lid & 15;
  int n = blockIdx.y;
  int s_base = blockIdx.x * 16 + wv * 4;
  float* Wr  = lds + wv * 1408;
  float* Xs  = Wr;              // 1024 (4 matrices, rows stride 16); reused as recon buf
  float* ISQ = Wr + 1024;       // 16 x RLDA
  float* GB  = Wr + 1344;       // 64
  float* red = lds + 4 * 1408;  // 1024 (cross-wave reduce)
  const float* xg = x + ((long)n * SS + s_base) * 256;
  #pragma unroll
  for (int i = 0; i < 4; ++i)
    *(float4*)(Xs + (i * 64 + lid) * 4) = *(const float4*)(xg + (i * 64 + lid) * 4);
  const float* isqn = isqrm + n * 256;
  for (int i = lid; i < 256; i += 64) ISQ[(i >> 4) * RLDA + (i & 15)] = isqn[i];
  __builtin_amdgcn_wave_barrier();
  float mc[CC], y[CC], a[CC];
  #pragma unroll
  for (int i = 0; i < 4; ++i) {
    float4 v = *(const float4*)(ISQ + c * RLDA + 4 * i);
    mc[4 * i] = v.x; mc[4 * i + 1] = v.y; mc[4 * i + 2] = v.z; mc[4 * i + 3] = v.w;
  }
  mv_lds<16>(Xs + g * 256, mc, y);
  mv_lds<RLDA>(ISQ, y, a);
  float d;
  jacobi_os(a, d, c, SW_PASS);
  float gc = 0.5f * __logf(fmaxf(d, 1e-30f)) * __builtin_amdgcn_rcpf(d);
  float* RBg = Xs + g * 256;   // X is dead; reuse
  #pragma unroll
  for (int i = 0; i < 4; ++i)
    *(float4*)(RBg + c * 16 + 4 * i) = make_float4(a[4 * i], a[4 * i + 1], a[4 * i + 2], a[4 * i + 3]);
  GB[g * 16 + c] = gc;
  __builtin_amdgcn_wave_barrier();
  float out[CC];
  recon16(RBg, GB + g * 16, c, out);
  #pragma unroll
  for (int r = 0; r < CC; ++r) out[r] += __shfl_xor(out[r], 16);
  #pragma unroll
  for (int r = 0; r < CC; ++r) out[r] += __shfl_xor(out[r], 32);
  if (g == 0) {
    #pragma unroll
    for (int i = 0; i < 4; ++i)
      *(float4*)(red + wv * 256 + c * 16 + 4 * i) = make_float4(out[4 * i], out[4 * i + 1], out[4 * i + 2], out[4 * i + 3]);
  }
  __syncthreads();
  float v = red[tid] + red[256 + tid] + red[512 + tid] + red[768 + tid];
  atomicAdd(&gtsum[n * 256 + tid], v);
}

// ---------------- Step 4: x_mean chain -> isq_m, lt_mean ----------------
__global__ __launch_bounds__(256) void mean_update_kernel(const float* __restrict__ gtsum, const float* __restrict__ sqrm,
                                                          float* __restrict__ isqm, float* __restrict__ ltmean) {
  __shared__ __align__(16) float lds[4 * 2176];
  int tid = threadIdx.x;
  int wv = tid >> 6, lid = tid & 63, g = lid >> 4, c = lid & 15;
  int n0 = blockIdx.x * 16 + wv * 4 + g;
  float* Wr = lds + wv * 2176;
  float* RB = Wr;               // 1024
  float* SQ = Wr + 1024;        // 1024
  float* G1 = Wr + 2048;        // 64
  float* G2 = Wr + 2112;        // 64
  // ---- eigh(gt) (indefinite -> shift), expm ----
  const float* gsrc = gtsum + n0 * 256;
  float a[CC];
  #pragma unroll
  for (int i = 0; i < 4; ++i) {
    float4 v = *(const float4*)(gsrc + c * 16 + 4 * i);
    a[4 * i] = v.x * (1.f / SS); a[4 * i + 1] = v.y * (1.f / SS);
    a[4 * i + 2] = v.z * (1.f / SS); a[4 * i + 3] = v.w * (1.f / SS);
  }
  float rs = fabsf(a[0]);
  #pragma unroll
  for (int r = 1; r < CC; ++r) rs += fabsf(a[r]);
  rs = fmaxf(rs, lxor<1>(rs)); rs = fmaxf(rs, lxor<2>(rs));
  rs = fmaxf(rs, lxor<4>(rs)); rs = fmaxf(rs, lxor<8>(rs));
  float sig = rs + 0.001f;
  #pragma unroll
  for (int r = 0; r < CC; ++r) a[r] += (r == c) ? sig : 0.f;
  float d;
  jacobi_os(a, d, c, SW_SMALL);
  float lam = __builtin_amdgcn_sqrtf(d);
  float gc = __expf(lam - sig) * __builtin_amdgcn_rcpf(fmaxf(d, 1e-30f));
  float* RBg = RB + g * 256;
  #pragma unroll
  for (int i = 0; i < 4; ++i)
    *(float4*)(RBg + c * 16 + 4 * i) = make_float4(a[4 * i], a[4 * i + 1], a[4 * i + 2], a[4 * i + 3]);
  G1[g * 16 + c] = gc;
  __builtin_amdgcn_wave_barrier();
  float e1[CC];
  recon16(RBg, G1 + g * 16, c, e1);
  // ---- stage sq_rm (4 consecutive n for this wave) ----
  const float* sqsrc = sqrm + (blockIdx.x * 16 + wv * 4) * 256;
  #pragma unroll
  for (int i = 0; i < 4; ++i)
    *(float4*)(SQ + (i * 64 + lid) * 4) = *(const float4*)(sqsrc + (i * 64 + lid) * 4);
  // e1 -> RB rows (a is dead after recon16 read)
  __builtin_amdgcn_wave_barrier();
  #pragma unroll
  for (int i = 0; i < 4; ++i)
    *(float4*)(RBg + c * 16 + 4 * i) = make_float4(e1[4 * i], e1[4 * i + 1], e1[4 * i + 2], e1[4 * i + 3]);
  __builtin_amdgcn_wave_barrier();
  float* SQg = SQ + g * 256;
  float mc[CC], y[CC], a2[CC];
  #pragma unroll
  for (int i = 0; i < 4; ++i) {
    float4 v = *(const float4*)(SQg + c * 16 + 4 * i);
    mc[4 * i] = v.x; mc[4 * i + 1] = v.y; mc[4 * i + 2] = v.z; mc[4 * i + 3] = v.w;
  }
  mv_lds<16>(RBg, mc, y);    // e1 * mc
  mv_lds<16>(SQg, y, a2);    // sq * y  -> col c of x_mean
  float d2;
  jacobi_os(a2, d2, c, SW_SMALL);
  float sqd = __builtin_amdgcn_sqrtf(d2);
  float qd  = __builtin_amdgcn_sqrtf(sqd);
  float g1c = __builtin_amdgcn_rcpf(d2 * qd);                                  // d^{-5/4}: invsqrtm
  float g2c = 0.5f * __logf(fmaxf(d2, 1e-30f)) * __builtin_amdgcn_rcpf(d2);   // logm
  #pragma unroll
  for (int i = 0; i < 4; ++i)
    *(float4*)(RBg + c * 16 + 4 * i) = make_float4(a2[4 * i], a2[4 * i + 1], a2[4 * i + 2], a2[4 * i + 3]);
  G1[g * 16 + c] = g1c;
  G2[g * 16 + c] = g2c;
  __builtin_amdgcn_wave_barrier();
  float o1[CC], o2[CC];
  recon2_16(RBg, G1 + g * 16, G2 + g * 16, c, o1, o2);
  float* idst = isqm + n0 * 256;
  #pragma unroll
  for (int i = 0; i < 4; ++i)
    *(float4*)(idst + c * 16 + 4 * i) = make_float4(o1[4 * i], o1[4 * i + 1], o1[4 * i + 2], o1[4 * i + 3]);
  #pragma unroll
  for (int r = 0; r < CC; ++r) {
    if (r >= c) ltmean[n0 * D0 + (r * (r + 1) / 2) + c] = o2[r] * ((r == c) ? 1.f : SQRT2F);
  }
}

// ---------------- Step 5: pass 2 — xc = tril(Wsq logm(isq_m X isq_m) Wsq) ----------------
__global__ __launch_bounds__(256) void pass2_kernel(const float* __restrict__ x, const float* __restrict__ isqm,
                                                    const float* __restrict__ wsqg, float* __restrict__ xc) {
  __shared__ __align__(16) float lds[4 * 1728];
  int tid = threadIdx.x;
  int wv = tid >> 6, lid = tid & 63, g = lid >> 4, c = lid & 15;
  int n = blockIdx.y;
  int s_base = blockIdx.x * 16 + wv * 4;
  float* Wr  = lds + wv * 1728;
  float* Xs  = Wr;              // 1024; reused as recon buf
  float* ISQ = Wr + 1024;       // 320
  float* WSQ = Wr + 1344;       // 320
  float* GB  = Wr + 1664;       // 64
  const float* xg = x + ((long)n * SS + s_base) * 256;
  #pragma unroll
  for (int i = 0; i < 4; ++i)
    *(float4*)(Xs + (i * 64 + lid) * 4) = *(const float4*)(xg + (i * 64 + lid) * 4);
  const float* isqn = isqm + n * 256;
  for (int i = lid; i < 256; i += 64) {
    int r = i >> 4, cc = i & 15;
    ISQ[r * RLDA + cc] = isqn[i];
    WSQ[r * RLDA + cc] = wsqg[i];
  }
  __builtin_amdgcn_wave_barrier();
  float mc[CC], y[CC], a[CC];
  #pragma unroll
  for (int i = 0; i < 4; ++i) {
    float4 v = *(const float4*)(ISQ + c * RLDA + 4 * i);
    mc[4 * i] = v.x; mc[4 * i + 1] = v.y; mc[4 * i + 2] = v.z; mc[4 * i + 3] = v.w;
  }
  mv_lds<16>(Xs + g * 256, mc, y);
  mv_lds<RLDA>(ISQ, y, a);
  float d;
  jacobi_os(a, d, c, SW_PASS);
  float gc = 0.5f * __logf(fmaxf(d, 1e-30f)) * __builtin_amdgcn_rcpf(d);
  // b = Wsq * a  (fold outer sandwich into the reconstruction columns)
  float b[CC];
  mv_lds<RLDA>(WSQ, a, b);
  float* RBg = Xs + g * 256;
  #pragma unroll
  for (int i = 0; i < 4; ++i)
    *(float4*)(RBg + c * 16 + 4 * i) = make_float4(b[4 * i], b[4 * i + 1], b[4 * i + 2], b[4 * i + 3]);
  GB[g * 16 + c] = gc;
  __builtin_amdgcn_wave_barrier();
  float out[CC];
  recon16(RBg, GB + g * 16, c, out);
  long ob = ((long)n * SS + s_base + g) * (long)D0;
  #pragma unroll
  for (int r = 0; r < CC; ++r) {
    if (r >= c) xc[ob + (r * (r + 1) / 2) + c] = out[r] * ((r == c) ? 1.f : SQRT2F);
  }
}

// ---------------- Step 6: covariance SYRK ----------------
__global__ __launch_bounds__(256) void syrk_kernel(const float* __restrict__ xc, float* __restrict__ cov) {
  __shared__ float Ap[32][33];
  __shared__ float Bp[32][33];
  int n = blockIdx.y;
  int ti = blockIdx.x / 5, tj = blockIdx.x % 5;
  int tid = threadIdx.x;
  int tx = tid & 15, ty = tid >> 4;
  float a00 = 0.f, a01 = 0.f, a10 = 0.f, a11 = 0.f;
  const float* xb = xc + (long)n * SS * D0;
  for (int s0 = 0; s0 < SS; s0 += 32) {
    for (int l = tid; l < 1024; l += 256) {
      int ss = l >> 5, ii = l & 31;
      int gi = ti * 32 + ii, gj = tj * 32 + ii;
      const float* row = xb + (long)(s0 + ss) * D0;
      Ap[ss][ii] = (gi < D0) ? row[gi] : 0.f;
      Bp[ss][ii] = (gj < D0) ? row[gj] : 0.f;
    }
    __syncthreads();
    #pragma unroll 8
    for (int ss = 0; ss < 32; ++ss) {
      float x0 = Ap[ss][2 * ty], x1 = Ap[ss][2 * ty + 1];
      float y0 = Bp[ss][2 * tx], y1 = Bp[ss][2 * tx + 1];
      a00 += x0 * y0; a01 += x0 * y1; a10 += x1 * y0; a11 += x1 * y1;
    }
    __syncthreads();
  }
  int i0 = ti * 32 + 2 * ty, j0 = tj * 32 + 2 * tx;
  const float sc = 1.f / (float)(SS - 1);
  long base = (long)n * D0 * D0;
  if (i0 < D0 && j0 < D0)         cov[base + (long)i0 * D0 + j0]           = a00 * sc;
  if (i0 < D0 && j0 + 1 < D0)     cov[base + (long)i0 * D0 + j0 + 1]       = a01 * sc;
  if (i0 + 1 < D0 && j0 < D0)     cov[base + (long)(i0 + 1) * D0 + j0]     = a10 * sc;
  if (i0 + 1 < D0 && j0 + 1 < D0) cov[base + (long)(i0 + 1) * D0 + j0 + 1] = a11 * sc;
}

// ---------------- Step 7: assemble E skeleton ----------------
__global__ __launch_bounds__(256) void ebuild_kernel(const float* __restrict__ ltmean, float* __restrict__ E) {
  int n = blockIdx.x;
  for (int idx = threadIdx.x; idx < DD * DD; idx += 256) {
    int r = idx / DD, c = idx % DD;
    float v = 0.f;
    if (r >= D0) {
      if (c < D0) v = ltmean[n * D0 + c];
      else        v = (r == c) ? 1.f : 0.f;
    }
    E[(long)n * DD * DD + idx] = v;
  }
}

// ---------------- Cholesky (triangular LDS storage) ----------------
template<int D, int NORM, int WRITE_UPPER>
__global__ __launch_bounds__(256) void chol_kernel(const float* __restrict__ in, long inStride,
                                                   float* __restrict__ out, long outStride, int outLd) {
  __shared__ float As[D * (D + 1) / 2];
  __shared__ float red[256];
  int b = blockIdx.x;
  int tid = threadIdx.x;
  const float* inp = in + (long)b * inStride;
  for (int idx = tid; idx < D * D; idx += 256) {
    int r = idx / D, c2 = idx % D;
    if (c2 <= r) As[(r * (r + 1) / 2) + c2] = inp[idx];
  }
  __syncthreads();
  if (NORM) {
    float p = 0.f;
    for (int i = tid; i < D; i += 256) p += As[(i * (i + 1) / 2) + i];
    red[tid] = p;
    __syncthreads();
    for (int off = 128; off >= 1; off >>= 1) {
      if (tid < off) red[tid] += red[tid + off];
      __syncthreads();
    }
    float inv = 1.f / red[0];
    for (int idx = tid; idx < D * (D + 1) / 2; idx += 256) As[idx] *= inv;
    __syncthreads();
    for (int i = tid; i < D; i += 256) As[(i * (i + 1) / 2) + i] += 1e-5f;
    __syncthreads();
  }
  int tx = tid & 15, ty = tid >> 4;
  for (int k = 0; k < D; ++k) {
    float dkk = As[(k * (k + 1) / 2) + k];
    float dv = sqrtf(dkk);
    float invd = 1.f / dv;
    __syncthreads();
    for (int i = k + 1 + tid; i < D; i += 256) As[(i * (i + 1) / 2) + k] *= invd;
    if (tid == 0) As[(k * (k + 1) / 2) + k] = dv;
    __syncthreads();
    for (int i = k + 1 + ty; i < D; i += 16) {
      float aik = As[(i * (i + 1) / 2) + k];
      int ibase = i * (i + 1) / 2;
      for (int j = k + 1 + tx; j <= i; j += 16) {
        As[ibase + j] -= aik * As[(j * (j + 1) / 2) + k];
      }
    }
    __syncthreads();
  }
  float* op = out + (long)b * outStride;
  for (int idx = tid; idx < D * D; idx += 256) {
    int r = idx / D, c2 = idx % D;
    if (c2 <= r)          op[r * outLd + c2] = As[(r * (r + 1) / 2) + c2];
    else if (WRITE_UPPER) op[r * outLd + c2] = 0.f;
  }
}

// ---------------- generic 152x152 GEMM: C = alpha*A@B (+I) ----------------
__global__ __launch_bounds__(256) void gemm152_kernel(const float* __restrict__ A, long sA,
                                                      const float* __restrict__ B, float* __restrict__ Cm,
                                                      long sC, float alpha, int addI) {
  __shared__ float As[16][17];
  __shared__ float Bs[16][17];
  int b = blockIdx.y;
  const float* Ab_ = A + (long)b * sA;
  float* Cb = Cm + (long)b * sC;
  int tid = threadIdx.x;
  int tx = tid & 15, ty = tid >> 4;
  int row0 = (blockIdx.x / 10) * 16, col0 = (blockIdx.x % 10) * 16;
  float acc = 0.f;
  for (int k0 = 0; k0 < DD; k0 += 16) {
    int ar = row0 + ty, ac = k0 + tx;
    As[ty][tx] = (ar < DD && ac < DD) ? Ab_[ar * DD + ac] : 0.f;
    int br = k0 + ty, bc = col0 + tx;
    Bs[ty][tx] = (br < DD && bc < DD) ? B[br * DD + bc] : 0.f;
    __syncthreads();
    #pragma unroll
    for (int kk = 0; kk < 16; ++kk) acc += As[ty][kk] * Bs[kk][tx];
    __syncthreads();
  }
  int r = row0 + ty, c2 = col0 + tx;
  if (r < DD && c2 < DD) Cb[r * DD + c2] = alpha * acc + ((addI && r == c2) ? 1.f : 0.f);
}

__global__ __launch_bounds__(256) void wlw_prep_kernel(const float* __restrict__ Wlw, float* __restrict__ Bm) {
  int idx = blockIdx.x * 256 + threadIdx.x;
  if (idx < DD * DD) {
    int r = idx / DD, c = idx % DD;
    Bm[idx] = 0.5f * (Wlw[idx] + Wlw[c * DD + r]) * (1.f / 16.f);
  }
}

__global__ __launch_bounds__(256) void taylor_init_kernel(const float* __restrict__ Bm, float* __restrict__ P) {
  int idx = blockIdx.x * 256 + threadIdx.x;
  if (idx < DD * DD) {
    int r = idx / DD, c = idx % DD;
    P[idx] = Bm[idx] * (1.f / 8.f) + ((r == c) ? 1.f : 0.f);
  }
}

extern "C" void kernel_launch(void* const* d_in, const int* in_sizes, int n_in,
                              void* d_out, int out_size, void* d_ws, size_t ws_size,
                              hipStream_t stream) {
  (void)in_sizes; (void)n_in; (void)out_size; (void)ws_size;
  const float* x   = (const float*)d_in[0];
  const float* W   = (const float*)d_in[1];
  const float* Wlw = (const float*)d_in[2];
  float* ws = (float*)d_ws;
  size_t off = 0;
  float* rmsum  = ws + off; off += 32 * 256;
  float* gtsum  = ws + off; off += 32 * 256;
  float* sqrm   = ws + off; off += 32 * 256;
  float* isqrm  = ws + off; off += 32 * 256;
  float* wsqb   = ws + off; off += 256;
  float* isqm   = ws + off; off += 32 * 256;
  float* ltmean = ws + off; off += 32 * D0;
  float* cov    = ws + off; off += (size_t)32 * D0 * D0;
  float* E      = ws + off; off += (size_t)32 * DD * DD;
  float* Bm     = ws + off; off += DD * DD;
  float* Pa     = ws + off; off += DD * DD;
  float* Pb     = ws + off; off += DD * DD;
  float* Rm     = ws + off; off += DD * DD;
  float* xcbuf  = ws + off; off += (size_t)32 * SS * D0;
  float* outp   = (float*)d_out;

  hipMemsetAsync(rmsum, 0, 2 * 32 * 256 * sizeof(float), stream);

  rm_mean_kernel    <<<dim3(32, 32),  256, 0, stream>>>(x, rmsum);
  eigh_rm_kernel    <<<3,             256, 0, stream>>>(rmsum, W, sqrm, isqrm, wsqb);
  pass1_kernel      <<<dim3(200, 32), 256, 0, stream>>>(x, isqrm, gtsum);
  mean_update_kernel<<<2,             256, 0, stream>>>(gtsum, sqrm, isqm, ltmean);
  pass2_kernel      <<<dim3(200, 32), 256, 0, stream>>>(x, isqm, wsqb, xcbuf);
  syrk_kernel       <<<dim3(25, 32),  256, 0, stream>>>(xcbuf, cov);
  ebuild_kernel     <<<32,            256, 0, stream>>>(ltmean, E);
  chol_kernel<D0, 1, 0><<<32,         256, 0, stream>>>(cov, (long)D0 * D0, E, (long)DD * DD, DD);

  wlw_prep_kernel   <<<(DD * DD + 255) / 256, 256, 0, stream>>>(Wlw, Bm);
  taylor_init_kernel<<<(DD * DD + 255) / 256, 256, 0, stream>>>(Bm, Pa);
  float* Pcur = Pa; float* Pnext = Pb;
  for (int k = 7; k >= 1; --k) {
    gemm152_kernel<<<dim3(100, 1), 256, 0, stream>>>(Bm, 0L, Pcur, Pnext, 0L, 1.f / (float)k, 1);
    float* t = Pcur; Pcur = Pnext; Pnext = t;
  }
  for (int i = 0; i < 4; ++i) {
    gemm152_kernel<<<dim3(100, 1), 256, 0, stream>>>(Pcur, 0L, Pcur, Pnext, 0L, 1.f, 0);
    float* t = Pcur; Pcur = Pnext; Pnext = t;
  }
  chol_kernel<DD, 0, 1><<<1, 256, 0, stream>>>(Pcur, 0L, Rm, 0L, DD);

  gemm152_kernel<<<dim3(100, 32), 256, 0, stream>>>(E, (long)DD * DD, Rm, outp, (long)DD * DD, 1.f, 0);
}

// Round 3
// 2198.427 us; speedup vs baseline: 5.9776x; 1.1373x over previous
//
#include <hip/hip_runtime.h>
#include <math.h>

// Problem constants (fixed by setup_inputs)
#define NN   32
#define SS   3200
#define CC   16
#define XLD  20      // row stride (floats) inside a 16x16 matrix slot
#define GSTR 328     // per-group matrix slot stride: bank offsets {0,8,16,24} across groups
#define D0   136     // C*(C+1)/2
#define DD   152     // D0 + k
#define SQRT2F 1.41421356237309515f
#define SW_PASS 6    // sweeps for the two big per-sample passes
#define SW_SMALL 10  // sweeps for the tiny per-n chains

// ---------------- cross-lane xor within 16-lane groups ----------------
template<int M> __device__ __forceinline__ float lxor(float x) {
  int v = __float_as_int(x);
  int r;
  if      constexpr (M == 1)  r = __builtin_amdgcn_update_dpp(0, v, 0xB1, 0xF, 0xF, true);  // quad_perm [1,0,3,2]
  else if constexpr (M == 2)  r = __builtin_amdgcn_update_dpp(0, v, 0x4E, 0xF, 0xF, true);  // quad_perm [2,3,0,1]
  else if constexpr (M == 3)  r = __builtin_amdgcn_update_dpp(0, v, 0x1B, 0xF, 0xF, true);  // quad_perm [3,2,1,0]
  else if constexpr (M == 7)  r = __builtin_amdgcn_update_dpp(0, v, 0x141, 0xF, 0xF, true); // row_half_mirror
  else if constexpr (M == 8)  r = __builtin_amdgcn_update_dpp(0, v, 0x128, 0xF, 0xF, true); // row_ror:8
  else if constexpr (M == 15) r = __builtin_amdgcn_update_dpp(0, v, 0x140, 0xF, 0xF, true); // row_mirror
  else r = __builtin_amdgcn_ds_swizzle(v, 0x1F | (M << 10));                                // BitMode xor
  return __int_as_float(r);
}

// ---------------- one-sided Jacobi round: pairs (i, i^M) ----------------
template<int M>
__device__ __forceinline__ void js_round(float a[CC], float& d, int c) {
  float part[CC];
  #pragma unroll
  for (int r = 0; r < CC; ++r) part[r] = lxor<M>(a[r]);
  float pd = lxor<M>(d);
  // balanced-tree dot product (4 chains of 4, then 2-level add)
  float s0 = a[0] * part[0], s1 = a[1] * part[1], s2 = a[2] * part[2], s3 = a[3] * part[3];
  s0 = fmaf(a[4], part[4], s0);   s1 = fmaf(a[5], part[5], s1);
  s2 = fmaf(a[6], part[6], s2);   s3 = fmaf(a[7], part[7], s3);
  s0 = fmaf(a[8], part[8], s0);   s1 = fmaf(a[9], part[9], s1);
  s2 = fmaf(a[10], part[10], s2); s3 = fmaf(a[11], part[11], s3);
  s0 = fmaf(a[12], part[12], s0); s1 = fmaf(a[13], part[13], s1);
  s2 = fmaf(a[14], part[14], s2); s3 = fmaf(a[15], part[15], s3);
  float apq = (s0 + s1) + (s2 + s3);
  int partner = c ^ M;
  bool isp = c < partner;
  float app = isp ? d : pd;
  float aqq = isp ? pd : d;
  float theta = (aqq - app) * 0.5f * __builtin_amdgcn_rcpf(apq);
  float t = copysignf(__builtin_amdgcn_rcpf(fabsf(theta) + __builtin_amdgcn_sqrtf(1.f + theta * theta)), theta);
  t = (apq == 0.f) ? 0.f : t;
  float cs = __builtin_amdgcn_rsqf(1.f + t * t);
  float sn = t * cs;
  float se = isp ? -sn : sn;
  #pragma unroll
  for (int r = 0; r < CC; ++r) a[r] = cs * a[r] + se * part[r];
  d = isp ? (app - t * apq) : (aqq + t * apq);
}

__device__ __forceinline__ void js_sweep(float a[CC], float& d, int c) {
  js_round<1>(a, d, c);  js_round<2>(a, d, c);  js_round<3>(a, d, c);
  js_round<4>(a, d, c);  js_round<5>(a, d, c);  js_round<6>(a, d, c);
  js_round<7>(a, d, c);  js_round<8>(a, d, c);  js_round<9>(a, d, c);
  js_round<10>(a, d, c); js_round<11>(a, d, c); js_round<12>(a, d, c);
  js_round<13>(a, d, c); js_round<14>(a, d, c); js_round<15>(a, d, c);
}

__device__ __forceinline__ float colnorm2(const float a[CC]) {
  float s0 = a[0] * a[0], s1 = a[1] * a[1], s2 = a[2] * a[2], s3 = a[3] * a[3];
  s0 = fmaf(a[4], a[4], s0);   s1 = fmaf(a[5], a[5], s1);
  s2 = fmaf(a[6], a[6], s2);   s3 = fmaf(a[7], a[7], s3);
  s0 = fmaf(a[8], a[8], s0);   s1 = fmaf(a[9], a[9], s1);
  s2 = fmaf(a[10], a[10], s2); s3 = fmaf(a[11], a[11], s3);
  s0 = fmaf(a[12], a[12], s0); s1 = fmaf(a[13], a[13], s1);
  s2 = fmaf(a[14], a[14], s2); s3 = fmaf(a[15], a[15], s3);
  return (s0 + s1) + (s2 + s3);
}

// a: column c of symmetric M. Exit: a = lam_c * v_c, d = lam_c^2.
__device__ __forceinline__ void jacobi_os(float a[CC], float& d, int c, int sweeps) {
  d = colnorm2(a);
  #pragma unroll 1
  for (int s = 0; s < sweeps; ++s) js_sweep(a, d, c);
  d = colnorm2(a);
}

// ---------------- y = Mat(16x16, LDS rows stride S) * v ----------------
template<int S>
__device__ __forceinline__ void mv_lds(const float* __restrict__ M, const float v[CC], float y[CC]) {
  #pragma unroll
  for (int r = 0; r < CC; ++r) {
    const float4 m0 = *(const float4*)(M + r * S + 0);
    const float4 m1 = *(const float4*)(M + r * S + 4);
    const float4 m2 = *(const float4*)(M + r * S + 8);
    const float4 m3 = *(const float4*)(M + r * S + 12);
    y[r] = m0.x * v[0] + m0.y * v[1] + m0.z * v[2] + m0.w * v[3]
         + m1.x * v[4] + m1.y * v[5] + m1.z * v[6] + m1.w * v[7]
         + m2.x * v[8] + m2.y * v[9] + m2.z * v[10] + m2.w * v[11]
         + m3.x * v[12] + m3.y * v[13] + m3.z * v[14] + m3.w * v[15];
  }
}

#define ACC16(out, coef, b0, b1, b2, b3)                                         \
  out[0] += coef * b0.x;  out[1] += coef * b0.y;  out[2] += coef * b0.z;  out[3] += coef * b0.w;  \
  out[4] += coef * b1.x;  out[5] += coef * b1.y;  out[6] += coef * b1.z;  out[7] += coef * b1.w;  \
  out[8] += coef * b2.x;  out[9] += coef * b2.y;  out[10] += coef * b2.z; out[11] += coef * b2.w; \
  out[12] += coef * b3.x; out[13] += coef * b3.y; out[14] += coef * b3.z; out[15] += coef * b3.w;

// out col c of Sum_i gb[i] * b_i b_i^T ; B row i = b_i (row stride S)
template<int S>
__device__ __forceinline__ void recon16(const float* __restrict__ B, const float* __restrict__ gb,
                                        int c, float out[CC]) {
  #pragma unroll
  for (int r = 0; r < CC; ++r) out[r] = 0.f;
  #pragma unroll
  for (int i = 0; i < CC; ++i) {
    float coef = gb[i] * B[i * S + c];
    const float4 b0 = *(const float4*)(B + i * S + 0);
    const float4 b1 = *(const float4*)(B + i * S + 4);
    const float4 b2 = *(const float4*)(B + i * S + 8);
    const float4 b3 = *(const float4*)(B + i * S + 12);
    ACC16(out, coef, b0, b1, b2, b3)
  }
}

template<int S>
__device__ __forceinline__ void recon2_16(const float* __restrict__ B, const float* __restrict__ g1,
                                          const float* __restrict__ g2, int c,
                                          float o1[CC], float o2[CC]) {
  #pragma unroll
  for (int r = 0; r < CC; ++r) { o1[r] = 0.f; o2[r] = 0.f; }
  #pragma unroll
  for (int i = 0; i < CC; ++i) {
    float bic = B[i * S + c];
    float c1 = g1[i] * bic;
    float c2 = g2[i] * bic;
    const float4 b0 = *(const float4*)(B + i * S + 0);
    const float4 b1 = *(const float4*)(B + i * S + 4);
    const float4 b2 = *(const float4*)(B + i * S + 8);
    const float4 b3 = *(const float4*)(B + i * S + 12);
    ACC16(o1, c1, b0, b1, b2, b3)
    ACC16(o2, c2, b0, b1, b2, b3)
  }
}

// stage 4 contiguous 16x16 matrices (1024 floats) from global into XLD/GSTR layout
__device__ __forceinline__ void stage4(const float* __restrict__ src, float* __restrict__ dst, int lid) {
  #pragma unroll
  for (int i = 0; i < 4; ++i) {
    int f = (i * 64 + lid) * 4;       // float index in the contiguous source
    int m = f >> 8, w = f & 255;      // matrix, within-matrix
    *(float4*)(dst + m * GSTR + (w >> 4) * XLD + (w & 15)) = *(const float4*)(src + f);
  }
}

__device__ __forceinline__ void store_rows(float* __restrict__ RBg, int c, const float a[CC]) {
  #pragma unroll
  for (int i = 0; i < 4; ++i)
    *(float4*)(RBg + c * XLD + 4 * i) = make_float4(a[4 * i], a[4 * i + 1], a[4 * i + 2], a[4 * i + 3]);
}

// ---------------- Step 1: rm accumulation ----------------
__global__ __launch_bounds__(256) void rm_mean_kernel(const float* __restrict__ x, float* __restrict__ rmsum) {
  int n = blockIdx.y;
  long base = ((long)n * SS) * 256 + (long)blockIdx.x * 100 * 256;
  int tid = threadIdx.x;
  float s = 0.f;
  for (int i = 0; i < 100; ++i) s += x[base + (long)i * 256 + tid];
  atomicAdd(&rmsum[n * 256 + tid], s);
}

// ---------------- Step 2: eigh(rm) -> sq,isq ; Wsq = expm(sym(W)/2) ----------------
__global__ __launch_bounds__(256) void eigh_rm_kernel(const float* __restrict__ rmsum, const float* __restrict__ Wg,
                                                      float* __restrict__ sqrm, float* __restrict__ isqrm,
                                                      float* __restrict__ wsqo) {
  __shared__ __align__(16) float lds[4 * 1440];
  int tid = threadIdx.x;
  int wv = tid >> 6, lid = tid & 63, g = lid >> 4, c = lid & 15;
  float* Wr = lds + wv * 1440;
  float* RB = Wr;                 // 4 x GSTR
  float* G1 = Wr + 4 * GSTR;      // 64
  float* G2 = Wr + 4 * GSTR + 64; // 64
  int gid_raw = blockIdx.x * 16 + wv * 4 + g;
  int gid = gid_raw > 32 ? 32 : gid_raw;
  float a[CC];
  if (gid < 32) {
    const float* src = rmsum + gid * 256;
    #pragma unroll
    for (int i = 0; i < 4; ++i) {
      float4 v = *(const float4*)(src + c * 16 + 4 * i);
      a[4 * i] = v.x * (1.f / SS); a[4 * i + 1] = v.y * (1.f / SS);
      a[4 * i + 2] = v.z * (1.f / SS); a[4 * i + 3] = v.w * (1.f / SS);
    }
  } else {
    #pragma unroll
    for (int r = 0; r < CC; ++r) a[r] = 0.5f * (Wg[c * 16 + r] + Wg[r * 16 + c]);
  }
  // Gershgorin shift (only applied to the possibly-indefinite W matrix)
  float rs = fabsf(a[0]);
  #pragma unroll
  for (int r = 1; r < CC; ++r) rs += fabsf(a[r]);
  rs = fmaxf(rs, lxor<1>(rs)); rs = fmaxf(rs, lxor<2>(rs));
  rs = fmaxf(rs, lxor<4>(rs)); rs = fmaxf(rs, lxor<8>(rs));
  float sig = (gid == 32) ? (rs + 0.001f) : 0.f;
  #pragma unroll
  for (int r = 0; r < CC; ++r) a[r] += (r == c) ? sig : 0.f;
  float d;
  jacobi_os(a, d, c, SW_SMALL);
  float g1c, g2c;
  if (gid < 32) {
    float sqd = __builtin_amdgcn_sqrtf(d);
    float qd  = __builtin_amdgcn_sqrtf(sqd);            // d^{1/4}
    g1c = qd * __builtin_amdgcn_rcpf(d);                // d^{-3/4}: sqrtm
    g2c = __builtin_amdgcn_rcpf(d * qd);                // d^{-5/4}: invsqrtm
  } else {
    float lam = __builtin_amdgcn_sqrtf(d);
    g1c = __expf(0.5f * (lam - sig)) * __builtin_amdgcn_rcpf(fmaxf(d, 1e-30f));
    g2c = 0.f;
  }
  float* RBg = RB + g * GSTR;
  store_rows(RBg, c, a);
  G1[g * 16 + c] = g1c;
  G2[g * 16 + c] = g2c;
  __builtin_amdgcn_wave_barrier();
  float o1[CC], o2[CC];
  recon2_16<XLD>(RBg, G1 + g * 16, G2 + g * 16, c, o1, o2);
  if (gid_raw < 32) {
    float* s1 = sqrm + gid * 256;
    float* s2 = isqrm + gid * 256;
    #pragma unroll
    for (int i = 0; i < 4; ++i) {
      *(float4*)(s1 + c * 16 + 4 * i) = make_float4(o1[4 * i], o1[4 * i + 1], o1[4 * i + 2], o1[4 * i + 3]);
      *(float4*)(s2 + c * 16 + 4 * i) = make_float4(o2[4 * i], o2[4 * i + 1], o2[4 * i + 2], o2[4 * i + 3]);
    }
  } else if (gid_raw == 32) {
    #pragma unroll
    for (int i = 0; i < 4; ++i)
      *(float4*)(wsqo + c * 16 + 4 * i) = make_float4(o1[4 * i], o1[4 * i + 1], o1[4 * i + 2], o1[4 * i + 3]);
  }
}

// ---------------- Step 3: pass 1 — sum_s logm(isq_rm X isq_rm) ----------------
#define WSZ1 (4 * GSTR + XLD * 16 + 64)   // 1696
__global__ __launch_bounds__(256, 4) void pass1_kernel(const float* __restrict__ x, const float* __restrict__ isqrm,
                                                       float* __restrict__ gtsum) {
  __shared__ __align__(16) float lds[4 * WSZ1 + 1024];
  int tid = threadIdx.x;
  int wv = tid >> 6, lid = tid & 63, g = lid >> 4, c = lid & 15;
  int n = blockIdx.y;
  int s_base = blockIdx.x * 16 + wv * 4;
  float* Wr  = lds + wv * WSZ1;
  float* Xs  = Wr;                      // 4 x GSTR; reused as recon buf
  float* ISQ = Wr + 4 * GSTR;           // 16 x XLD
  float* GB  = Wr + 4 * GSTR + XLD * 16;// 64
  float* red = lds + 4 * WSZ1;          // 1024 (cross-wave reduce)
  stage4(x + ((long)n * SS + s_base) * 256, Xs, lid);
  const float* isqn = isqrm + n * 256;
  for (int i = lid; i < 256; i += 64) ISQ[(i >> 4) * XLD + (i & 15)] = isqn[i];
  __builtin_amdgcn_wave_barrier();
  float mc[CC], y[CC], a[CC];
  #pragma unroll
  for (int i = 0; i < 4; ++i) {
    float4 v = *(const float4*)(ISQ + c * XLD + 4 * i);
    mc[4 * i] = v.x; mc[4 * i + 1] = v.y; mc[4 * i + 2] = v.z; mc[4 * i + 3] = v.w;
  }
  mv_lds<XLD>(Xs + g * GSTR, mc, y);
  mv_lds<XLD>(ISQ, y, a);
  float d;
  jacobi_os(a, d, c, SW_PASS);
  float gc = 0.5f * __logf(fmaxf(d, 1e-30f)) * __builtin_amdgcn_rcpf(d);
  float* RBg = Xs + g * GSTR;   // X is dead; reuse
  store_rows(RBg, c, a);
  GB[g * 16 + c] = gc;
  __builtin_amdgcn_wave_barrier();
  float out[CC];
  recon16<XLD>(RBg, GB + g * 16, c, out);
  #pragma unroll
  for (int r = 0; r < CC; ++r) out[r] += __shfl_xor(out[r], 16);
  #pragma unroll
  for (int r = 0; r < CC; ++r) out[r] += __shfl_xor(out[r], 32);
  if (g == 0) {
    #pragma unroll
    for (int i = 0; i < 4; ++i)
      *(float4*)(red + wv * 256 + c * 16 + 4 * i) = make_float4(out[4 * i], out[4 * i + 1], out[4 * i + 2], out[4 * i + 3]);
  }
  __syncthreads();
  float v = red[tid] + red[256 + tid] + red[512 + tid] + red[768 + tid];
  atomicAdd(&gtsum[n * 256 + tid], v);
}

// ---------------- Step 4: x_mean chain -> isq_m, lt_mean ----------------
#define WSZ4 (8 * GSTR + 128)   // 2752
__global__ __launch_bounds__(256) void mean_update_kernel(const float* __restrict__ gtsum, const float* __restrict__ sqrm,
                                                          float* __restrict__ isqm, float* __restrict__ ltmean) {
  __shared__ __align__(16) float lds[4 * WSZ4];
  int tid = threadIdx.x;
  int wv = tid >> 6, lid = tid & 63, g = lid >> 4, c = lid & 15;
  int n0 = blockIdx.x * 16 + wv * 4 + g;
  float* Wr = lds + wv * WSZ4;
  float* RB = Wr;                  // 4 x GSTR
  float* SQ = Wr + 4 * GSTR;       // 4 x GSTR
  float* G1 = Wr + 8 * GSTR;       // 64
  float* G2 = Wr + 8 * GSTR + 64;  // 64
  // ---- eigh(gt) (indefinite -> shift), expm ----
  const float* gsrc = gtsum + n0 * 256;
  float a[CC];
  #pragma unroll
  for (int i = 0; i < 4; ++i) {
    float4 v = *(const float4*)(gsrc + c * 16 + 4 * i);
    a[4 * i] = v.x * (1.f / SS); a[4 * i + 1] = v.y * (1.f / SS);
    a[4 * i + 2] = v.z * (1.f / SS); a[4 * i + 3] = v.w * (1.f / SS);
  }
  float rs = fabsf(a[0]);
  #pragma unroll
  for (int r = 1; r < CC; ++r) rs += fabsf(a[r]);
  rs = fmaxf(rs, lxor<1>(rs)); rs = fmaxf(rs, lxor<2>(rs));
  rs = fmaxf(rs, lxor<4>(rs)); rs = fmaxf(rs, lxor<8>(rs));
  float sig = rs + 0.001f;
  #pragma unroll
  for (int r = 0; r < CC; ++r) a[r] += (r == c) ? sig : 0.f;
  float d;
  jacobi_os(a, d, c, SW_SMALL);
  float lam = __builtin_amdgcn_sqrtf(d);
  float gc = __expf(lam - sig) * __builtin_amdgcn_rcpf(fmaxf(d, 1e-30f));
  float* RBg = RB + g * GSTR;
  store_rows(RBg, c, a);
  G1[g * 16 + c] = gc;
  __builtin_amdgcn_wave_barrier();
  float e1[CC];
  recon16<XLD>(RBg, G1 + g * 16, c, e1);
  // ---- stage sq_rm (4 consecutive n for this wave) ----
  stage4(sqrm + (blockIdx.x * 16 + wv * 4) * 256, SQ, lid);
  __builtin_amdgcn_wave_barrier();
  store_rows(RBg, c, e1);
  __builtin_amdgcn_wave_barrier();
  float* SQg = SQ + g * GSTR;
  float mc[CC], y[CC], a2[CC];
  #pragma unroll
  for (int i = 0; i < 4; ++i) {
    float4 v = *(const float4*)(SQg + c * XLD + 4 * i);
    mc[4 * i] = v.x; mc[4 * i + 1] = v.y; mc[4 * i + 2] = v.z; mc[4 * i + 3] = v.w;
  }
  mv_lds<XLD>(RBg, mc, y);    // expm(gt) * sq_col
  mv_lds<XLD>(SQg, y, a2);    // sq * y -> col c of x_mean
  float d2;
  jacobi_os(a2, d2, c, SW_SMALL);
  float sqd = __builtin_amdgcn_sqrtf(d2);
  float qd  = __builtin_amdgcn_sqrtf(sqd);
  float g1c = __builtin_amdgcn_rcpf(d2 * qd);                                  // d^{-5/4}: invsqrtm
  float g2c = 0.5f * __logf(fmaxf(d2, 1e-30f)) * __builtin_amdgcn_rcpf(d2);   // logm
  store_rows(RBg, c, a2);
  G1[g * 16 + c] = g1c;
  G2[g * 16 + c] = g2c;
  __builtin_amdgcn_wave_barrier();
  float o1[CC], o2[CC];
  recon2_16<XLD>(RBg, G1 + g * 16, G2 + g * 16, c, o1, o2);
  float* idst = isqm + n0 * 256;
  #pragma unroll
  for (int i = 0; i < 4; ++i)
    *(float4*)(idst + c * 16 + 4 * i) = make_float4(o1[4 * i], o1[4 * i + 1], o1[4 * i + 2], o1[4 * i + 3]);
  #pragma unroll
  for (int r = 0; r < CC; ++r) {
    if (r >= c) ltmean[n0 * D0 + (r * (r + 1) / 2) + c] = o2[r] * ((r == c) ? 1.f : SQRT2F);
  }
}

// ---------------- Step 5: pass 2 — xc = tril(Wsq logm(isq_m X isq_m) Wsq) ----------------
#define WSZ2 (4 * GSTR + 2 * XLD * 16 + 64)   // 2016
__global__ __launch_bounds__(256, 4) void pass2_kernel(const float* __restrict__ x, const float* __restrict__ isqm,
                                                       const float* __restrict__ wsqg, float* __restrict__ xc) {
  __shared__ __align__(16) float lds[4 * WSZ2];
  int tid = threadIdx.x;
  int wv = tid >> 6, lid = tid & 63, g = lid >> 4, c = lid & 15;
  int n = blockIdx.y;
  int s_base = blockIdx.x * 16 + wv * 4;
  float* Wr  = lds + wv * WSZ2;
  float* Xs  = Wr;                           // 4 x GSTR; reused as recon buf
  float* ISQ = Wr + 4 * GSTR;                // 16 x XLD
  float* WSQ = Wr + 4 * GSTR + XLD * 16;     // 16 x XLD
  float* GB  = Wr + 4 * GSTR + 2 * XLD * 16; // 64
  stage4(x + ((long)n * SS + s_base) * 256, Xs, lid);
  const float* isqn = isqm + n * 256;
  for (int i = lid; i < 256; i += 64) {
    int r = i >> 4, cc = i & 15;
    ISQ[r * XLD + cc] = isqn[i];
    WSQ[r * XLD + cc] = wsqg[i];
  }
  __builtin_amdgcn_wave_barrier();
  float mc[CC], y[CC], a[CC];
  #pragma unroll
  for (int i = 0; i < 4; ++i) {
    float4 v = *(const float4*)(ISQ + c * XLD + 4 * i);
    mc[4 * i] = v.x; mc[4 * i + 1] = v.y; mc[4 * i + 2] = v.z; mc[4 * i + 3] = v.w;
  }
  mv_lds<XLD>(Xs + g * GSTR, mc, y);
  mv_lds<XLD>(ISQ, y, a);
  float d;
  jacobi_os(a, d, c, SW_PASS);
  float gc = 0.5f * __logf(fmaxf(d, 1e-30f)) * __builtin_amdgcn_rcpf(d);
  float b[CC];
  mv_lds<XLD>(WSQ, a, b);   // fold outer Wsq sandwich into the recon columns
  float* RBg = Xs + g * GSTR;
  store_rows(RBg, c, b);
  GB[g * 16 + c] = gc;
  __builtin_amdgcn_wave_barrier();
  float out[CC];
  recon16<XLD>(RBg, GB + g * 16, c, out);
  long ob = ((long)n * SS + s_base + g) * (long)D0;
  #pragma unroll
  for (int r = 0; r < CC; ++r) {
    if (r >= c) xc[ob + (r * (r + 1) / 2) + c] = out[r] * ((r == c) ? 1.f : SQRT2F);
  }
}

// ---------------- Step 6: covariance SYRK (symmetric: 15 of 25 tile pairs) ----------------
__global__ __launch_bounds__(256) void syrk_kernel(const float* __restrict__ xc, float* __restrict__ cov) {
  __shared__ float Ap[32][33];
  __shared__ float Bp[32][33];
  const int TI[15] = {0,0,0,0,0,1,1,1,1,2,2,2,3,3,4};
  const int TJ[15] = {0,1,2,3,4,1,2,3,4,2,3,4,3,4,4};
  int n = blockIdx.y;
  int ti = TI[blockIdx.x], tj = TJ[blockIdx.x];
  int tid = threadIdx.x;
  int tx = tid & 15, ty = tid >> 4;
  float a00 = 0.f, a01 = 0.f, a10 = 0.f, a11 = 0.f;
  const float* xb = xc + (long)n * SS * D0;
  for (int s0 = 0; s0 < SS; s0 += 32) {
    for (int l = tid; l < 1024; l += 256) {
      int ss = l >> 5, ii = l & 31;
      int gi = ti * 32 + ii, gj = tj * 32 + ii;
      const float* row = xb + (long)(s0 + ss) * D0;
      Ap[ss][ii] = (gi < D0) ? row[gi] : 0.f;
      Bp[ss][ii] = (gj < D0) ? row[gj] : 0.f;
    }
    __syncthreads();
    #pragma unroll 8
    for (int ss = 0; ss < 32; ++ss) {
      float x0 = Ap[ss][2 * ty], x1 = Ap[ss][2 * ty + 1];
      float y0 = Bp[ss][2 * tx], y1 = Bp[ss][2 * tx + 1];
      a00 += x0 * y0; a01 += x0 * y1; a10 += x1 * y0; a11 += x1 * y1;
    }
    __syncthreads();
  }
  int i0 = ti * 32 + 2 * ty, j0 = tj * 32 + 2 * tx;
  const float sc = 1.f / (float)(SS - 1);
  long base = (long)n * D0 * D0;
  if (i0 < D0 && j0 < D0)         cov[base + (long)i0 * D0 + j0]           = a00 * sc;
  if (i0 < D0 && j0 + 1 < D0)     cov[base + (long)i0 * D0 + j0 + 1]       = a01 * sc;
  if (i0 + 1 < D0 && j0 < D0)     cov[base + (long)(i0 + 1) * D0 + j0]     = a10 * sc;
  if (i0 + 1 < D0 && j0 + 1 < D0) cov[base + (long)(i0 + 1) * D0 + j0 + 1] = a11 * sc;
  if (ti != tj) {
    if (i0 < D0 && j0 < D0)         cov[base + (long)j0 * D0 + i0]           = a00 * sc;
    if (i0 < D0 && j0 + 1 < D0)     cov[base + (long)(j0 + 1) * D0 + i0]     = a01 * sc;
    if (i0 + 1 < D0 && j0 < D0)     cov[base + (long)j0 * D0 + i0 + 1]       = a10 * sc;
    if (i0 + 1 < D0 && j0 + 1 < D0) cov[base + (long)(j0 + 1) * D0 + i0 + 1] = a11 * sc;
  }
}

// ---------------- Step 7: assemble E skeleton ----------------
__global__ __launch_bounds__(256) void ebuild_kernel(const float* __restrict__ ltmean, float* __restrict__ E) {
  int n = blockIdx.x;
  for (int idx = threadIdx.x; idx < DD * DD; idx += 256) {
    int r = idx / DD, c = idx % DD;
    float v = 0.f;
    if (r >= D0) {
      if (c < D0) v = ltmean[n * D0 + c];
      else        v = (r == c) ? 1.f : 0.f;
    }
    E[(long)n * DD * DD + idx] = v;
  }
}

// ---------------- Cholesky (triangular LDS storage) ----------------
template<int D, int NORM, int WRITE_UPPER>
__global__ __launch_bounds__(256) void chol_kernel(const float* __restrict__ in, long inStride,
                                                   float* __restrict__ out, long outStride, int outLd) {
  __shared__ float As[D * (D + 1) / 2];
  __shared__ float red[256];
  int b = blockIdx.x;
  int tid = threadIdx.x;
  const float* inp = in + (long)b * inStride;
  for (int idx = tid; idx < D * D; idx += 256) {
    int r = idx / D, c2 = idx % D;
    if (c2 <= r) As[(r * (r + 1) / 2) + c2] = inp[idx];
  }
  __syncthreads();
  if (NORM) {
    float p = 0.f;
    for (int i = tid; i < D; i += 256) p += As[(i * (i + 1) / 2) + i];
    red[tid] = p;
    __syncthreads();
    for (int off = 128; off >= 1; off >>= 1) {
      if (tid < off) red[tid] += red[tid + off];
      __syncthreads();
    }
    float inv = 1.f / red[0];
    for (int idx = tid; idx < D * (D + 1) / 2; idx += 256) As[idx] *= inv;
    __syncthreads();
    for (int i = tid; i < D; i += 256) As[(i * (i + 1) / 2) + i] += 1e-5f;
    __syncthreads();
  }
  int tx = tid & 15, ty = tid >> 4;
  for (int k = 0; k < D; ++k) {
    float dkk = As[(k * (k + 1) / 2) + k];
    float dv = sqrtf(dkk);
    float invd = 1.f / dv;
    __syncthreads();
    for (int i = k + 1 + tid; i < D; i += 256) As[(i * (i + 1) / 2) + k] *= invd;
    if (tid == 0) As[(k * (k + 1) / 2) + k] = dv;
    __syncthreads();
    for (int i = k + 1 + ty; i < D; i += 16) {
      float aik = As[(i * (i + 1) / 2) + k];
      int ibase = i * (i + 1) / 2;
      for (int j = k + 1 + tx; j <= i; j += 16) {
        As[ibase + j] -= aik * As[(j * (j + 1) / 2) + k];
      }
    }
    __syncthreads();
  }
  float* op = out + (long)b * outStride;
  for (int idx = tid; idx < D * D; idx += 256) {
    int r = idx / D, c2 = idx % D;
    if (c2 <= r)          op[r * outLd + c2] = As[(r * (r + 1) / 2) + c2];
    else if (WRITE_UPPER) op[r * outLd + c2] = 0.f;
  }
}

// ---------------- generic 152x152 GEMM: C = alpha*A@B (+I) ----------------
__global__ __launch_bounds__(256) void gemm152_kernel(const float* __restrict__ A, long sA,
                                                      const float* __restrict__ B, float* __restrict__ Cm,
                                                      long sC, float alpha, int addI) {
  __shared__ float As[16][17];
  __shared__ float Bs[16][17];
  int b = blockIdx.y;
  const float* Ab_ = A + (long)b * sA;
  float* Cb = Cm + (long)b * sC;
  int tid = threadIdx.x;
  int tx = tid & 15, ty = tid >> 4;
  int row0 = (blockIdx.x / 10) * 16, col0 = (blockIdx.x % 10) * 16;
  float acc = 0.f;
  for (int k0 = 0; k0 < DD; k0 += 16) {
    int ar = row0 + ty, ac = k0 + tx;
    As[ty][tx] = (ar < DD && ac < DD) ? Ab_[ar * DD + ac] : 0.f;
    int br = k0 + ty, bc = col0 + tx;
    Bs[ty][tx] = (br < DD && bc < DD) ? B[br * DD + bc] : 0.f;
    __syncthreads();
    #pragma unroll
    for (int kk = 0; kk < 16; ++kk) acc += As[ty][kk] * Bs[kk][tx];
    __syncthreads();
  }
  int r = row0 + ty, c2 = col0 + tx;
  if (r < DD && c2 < DD) Cb[r * DD + c2] = alpha * acc + ((addI && r == c2) ? 1.f : 0.f);
}

__global__ __launch_bounds__(256) void wlw_prep_kernel(const float* __restrict__ Wlw, float* __restrict__ Bm) {
  int idx = blockIdx.x * 256 + threadIdx.x;
  if (idx < DD * DD) {
    int r = idx / DD, c = idx % DD;
    Bm[idx] = 0.5f * (Wlw[idx] + Wlw[c * DD + r]) * (1.f / 16.f);
  }
}

__global__ __launch_bounds__(256) void taylor_init_kernel(const float* __restrict__ Bm, float* __restrict__ P) {
  int idx = blockIdx.x * 256 + threadIdx.x;
  if (idx < DD * DD) {
    int r = idx / DD, c = idx % DD;
    P[idx] = Bm[idx] * (1.f / 6.f) + ((r == c) ? 1.f : 0.f);
  }
}

extern "C" void kernel_launch(void* const* d_in, const int* in_sizes, int n_in,
                              void* d_out, int out_size, void* d_ws, size_t ws_size,
                              hipStream_t stream) {
  (void)in_sizes; (void)n_in; (void)out_size; (void)ws_size;
  const float* x   = (const float*)d_in[0];
  const float* W   = (const float*)d_in[1];
  const float* Wlw = (const float*)d_in[2];
  float* ws = (float*)d_ws;
  size_t off = 0;
  float* rmsum  = ws + off; off += 32 * 256;
  float* gtsum  = ws + off; off += 32 * 256;
  float* sqrm   = ws + off; off += 32 * 256;
  float* isqrm  = ws + off; off += 32 * 256;
  float* wsqb   = ws + off; off += 256;
  float* isqm   = ws + off; off += 32 * 256;
  float* ltmean = ws + off; off += 32 * D0;
  float* cov    = ws + off; off += (size_t)32 * D0 * D0;
  float* E      = ws + off; off += (size_t)32 * DD * DD;
  float* Bm     = ws + off; off += DD * DD;
  float* Pa     = ws + off; off += DD * DD;
  float* Pb     = ws + off; off += DD * DD;
  float* Rm     = ws + off; off += DD * DD;
  float* xcbuf  = ws + off; off += (size_t)32 * SS * D0;
  float* outp   = (float*)d_out;

  hipMemsetAsync(rmsum, 0, 2 * 32 * 256 * sizeof(float), stream);

  rm_mean_kernel    <<<dim3(32, 32),  256, 0, stream>>>(x, rmsum);
  eigh_rm_kernel    <<<3,             256, 0, stream>>>(rmsum, W, sqrm, isqrm, wsqb);
  pass1_kernel      <<<dim3(200, 32), 256, 0, stream>>>(x, isqrm, gtsum);
  mean_update_kernel<<<2,             256, 0, stream>>>(gtsum, sqrm, isqm, ltmean);
  pass2_kernel      <<<dim3(200, 32), 256, 0, stream>>>(x, isqm, wsqb, xcbuf);
  syrk_kernel       <<<dim3(15, 32),  256, 0, stream>>>(xcbuf, cov);
  ebuild_kernel     <<<32,            256, 0, stream>>>(ltmean, E);
  chol_kernel<D0, 1, 0><<<32,         256, 0, stream>>>(cov, (long)D0 * D0, E, (long)DD * DD, DD);

  // R = chol(expm(sym(W_lw))): scaling 1/16, Taylor order 6 (err ~7e-10), square 4x
  wlw_prep_kernel   <<<(DD * DD + 255) / 256, 256, 0, stream>>>(Wlw, Bm);
  taylor_init_kernel<<<(DD * DD + 255) / 256, 256, 0, stream>>>(Bm, Pa);
  float* Pcur = Pa; float* Pnext = Pb;
  for (int k = 5; k >= 1; --k) {
    gemm152_kernel<<<dim3(100, 1), 256, 0, stream>>>(Bm, 0L, Pcur, Pnext, 0L, 1.f / (float)k, 1);
    float* t = Pcur; Pcur = Pnext; Pnext = t;
  }
  for (int i = 0; i < 4; ++i) {
    gemm152_kernel<<<dim3(100, 1), 256, 0, stream>>>(Pcur, 0L, Pcur, Pnext, 0L, 1.f, 0);
    float* t = Pcur; Pcur = Pnext; Pnext = t;
  }
  chol_kernel<DD, 0, 1><<<1, 256, 0, stream>>>(Pcur, 0L, Rm, 0L, DD);

  gemm152_kernel<<<dim3(100, 32), 256, 0, stream>>>(E, (long)DD * DD, Rm, outp, (long)DD * DD, 1.f, 0);
}

// Round 4
// 2069.459 us; speedup vs baseline: 6.3501x; 1.0623x over previous
//
#include <hip/hip_runtime.h>
#include <math.h>

// Problem constants (fixed by setup_inputs)
#define NN   32
#define SS   3200
#define CC   16
#define XLD  20      // row stride (floats) inside a 16x16 matrix slot
#define GSTR 328     // per-group matrix slot stride: bank offsets {0,8,16,24} across groups
#define D0   136     // C*(C+1)/2
#define DD   152     // D0 + k
#define SQRT2F 1.41421356237309515f
#define SW_PASS 5    // sweeps for the two big per-sample passes
#define SW_SMALL 8   // sweeps for the tiny per-n chains

typedef float f2 __attribute__((ext_vector_type(2)));
__device__ __forceinline__ f2 mk2(float x, float y) { f2 r; r.x = x; r.y = y; return r; }

// ---------------- cross-lane xor within 16-lane groups ----------------
template<int M> __device__ __forceinline__ float lxor(float x) {
  int v = __float_as_int(x);
  int r;
  if      constexpr (M == 1)  r = __builtin_amdgcn_update_dpp(0, v, 0xB1, 0xF, 0xF, true);  // quad_perm [1,0,3,2]
  else if constexpr (M == 2)  r = __builtin_amdgcn_update_dpp(0, v, 0x4E, 0xF, 0xF, true);  // quad_perm [2,3,0,1]
  else if constexpr (M == 3)  r = __builtin_amdgcn_update_dpp(0, v, 0x1B, 0xF, 0xF, true);  // quad_perm [3,2,1,0]
  else if constexpr (M == 7)  r = __builtin_amdgcn_update_dpp(0, v, 0x141, 0xF, 0xF, true); // row_half_mirror
  else if constexpr (M == 8)  r = __builtin_amdgcn_update_dpp(0, v, 0x128, 0xF, 0xF, true); // row_ror:8
  else if constexpr (M == 15) r = __builtin_amdgcn_update_dpp(0, v, 0x140, 0xF, 0xF, true); // row_mirror
  else r = __builtin_amdgcn_ds_swizzle(v, 0x1F | (M << 10));                                // BitMode xor
  return __int_as_float(r);
}

// ---------------- one-sided Jacobi round: pairs (i, i^M) ----------------
template<int M>
__device__ __forceinline__ void js_round(f2 a[8], float& d, int c) {
  f2 part[8];
  #pragma unroll
  for (int r = 0; r < 8; ++r) {
    part[r].x = lxor<M>(a[r].x);
    part[r].y = lxor<M>(a[r].y);
  }
  float pd = lxor<M>(d);
  f2 s0 = a[0] * part[0];
  f2 s1 = a[1] * part[1];
  f2 s2 = a[2] * part[2];
  f2 s3 = a[3] * part[3];
  s0 += a[4] * part[4];
  s1 += a[5] * part[5];
  s2 += a[6] * part[6];
  s3 += a[7] * part[7];
  f2 sv = (s0 + s1) + (s2 + s3);
  float apq = sv.x + sv.y;
  int partner = c ^ M;
  bool isp = c < partner;
  float app = isp ? d : pd;
  float aqq = isp ? pd : d;
  float theta = (aqq - app) * 0.5f * __builtin_amdgcn_rcpf(apq);
  float t = copysignf(__builtin_amdgcn_rcpf(fabsf(theta) + __builtin_amdgcn_sqrtf(1.f + theta * theta)), theta);
  t = (apq == 0.f) ? 0.f : t;
  float cs = __builtin_amdgcn_rsqf(1.f + t * t);
  float sn = t * cs;
  float se = isp ? -sn : sn;
  f2 pcs = mk2(cs, cs);
  f2 pse = mk2(se, se);
  #pragma unroll
  for (int r = 0; r < 8; ++r) a[r] = pcs * a[r] + pse * part[r];
  d = isp ? (app - t * apq) : (aqq + t * apq);
}

__device__ __forceinline__ void js_sweep(f2 a[8], float& d, int c) {
  js_round<1>(a, d, c);  js_round<2>(a, d, c);  js_round<3>(a, d, c);
  js_round<4>(a, d, c);  js_round<5>(a, d, c);  js_round<6>(a, d, c);
  js_round<7>(a, d, c);  js_round<8>(a, d, c);  js_round<9>(a, d, c);
  js_round<10>(a, d, c); js_round<11>(a, d, c); js_round<12>(a, d, c);
  js_round<13>(a, d, c); js_round<14>(a, d, c); js_round<15>(a, d, c);
}

__device__ __forceinline__ float colnorm2(const f2 a[8]) {
  f2 s0 = a[0] * a[0], s1 = a[1] * a[1], s2 = a[2] * a[2], s3 = a[3] * a[3];
  s0 += a[4] * a[4]; s1 += a[5] * a[5]; s2 += a[6] * a[6]; s3 += a[7] * a[7];
  f2 s = (s0 + s1) + (s2 + s3);
  return s.x + s.y;
}

// a: column c of symmetric M (packed pairs). Exit: a = lam_c * v_c, d = lam_c^2.
__device__ __forceinline__ void jacobi_os(f2 a[8], float& d, int c, int sweeps) {
  d = colnorm2(a);
  #pragma unroll 1
  for (int s = 0; s < sweeps; ++s) js_sweep(a, d, c);
  d = colnorm2(a);
}

// ---------------- row dot: dot(M_row, v) ----------------
__device__ __forceinline__ float dotrow(const float* __restrict__ row, const f2 v[8]) {
  const float4 q0 = *(const float4*)(row + 0);
  const float4 q1 = *(const float4*)(row + 4);
  const float4 q2 = *(const float4*)(row + 8);
  const float4 q3 = *(const float4*)(row + 12);
  f2 s0 = mk2(q0.x, q0.y) * v[0] + mk2(q0.z, q0.w) * v[1];
  f2 s1 = mk2(q1.x, q1.y) * v[2] + mk2(q1.z, q1.w) * v[3];
  s0 += mk2(q2.x, q2.y) * v[4] + mk2(q2.z, q2.w) * v[5];
  s1 += mk2(q3.x, q3.y) * v[6] + mk2(q3.z, q3.w) * v[7];
  f2 s = s0 + s1;
  return s.x + s.y;
}

// y = Mat(16x16, LDS rows stride S) * v  (v, y packed by row pairs)
template<int S>
__device__ __forceinline__ void mv_lds(const float* __restrict__ M, const f2 v[8], f2 y[8]) {
  #pragma unroll
  for (int k = 0; k < 8; ++k) {
    float r0 = dotrow(M + (2 * k) * S, v);
    float r1 = dotrow(M + (2 * k + 1) * S, v);
    y[k] = mk2(r0, r1);
  }
}

// out (packed rows) = col c of Sum_i gb[i] * b_i b_i^T ; B row i = b_i (row stride S)
template<int S>
__device__ __forceinline__ void recon16(const float* __restrict__ B, const float* __restrict__ gb,
                                        int c, f2 o[8]) {
  #pragma unroll
  for (int k = 0; k < 8; ++k) o[k] = mk2(0.f, 0.f);
  #pragma unroll
  for (int i = 0; i < CC; ++i) {
    const float* row = B + i * S;
    float coef = gb[i] * row[c];
    f2 pc = mk2(coef, coef);
    const float4 q0 = *(const float4*)(row + 0);
    const float4 q1 = *(const float4*)(row + 4);
    const float4 q2 = *(const float4*)(row + 8);
    const float4 q3 = *(const float4*)(row + 12);
    o[0] += pc * mk2(q0.x, q0.y); o[1] += pc * mk2(q0.z, q0.w);
    o[2] += pc * mk2(q1.x, q1.y); o[3] += pc * mk2(q1.z, q1.w);
    o[4] += pc * mk2(q2.x, q2.y); o[5] += pc * mk2(q2.z, q2.w);
    o[6] += pc * mk2(q3.x, q3.y); o[7] += pc * mk2(q3.z, q3.w);
  }
}

template<int S>
__device__ __forceinline__ void recon2_16(const float* __restrict__ B, const float* __restrict__ g1,
                                          const float* __restrict__ g2, int c,
                                          f2 o1[8], f2 o2[8]) {
  #pragma unroll
  for (int k = 0; k < 8; ++k) { o1[k] = mk2(0.f, 0.f); o2[k] = mk2(0.f, 0.f); }
  #pragma unroll
  for (int i = 0; i < CC; ++i) {
    const float* row = B + i * S;
    float bic = row[c];
    f2 c1 = mk2(g1[i] * bic, g1[i] * bic);
    f2 c2 = mk2(g2[i] * bic, g2[i] * bic);
    const float4 q0 = *(const float4*)(row + 0);
    const float4 q1 = *(const float4*)(row + 4);
    const float4 q2 = *(const float4*)(row + 8);
    const float4 q3 = *(const float4*)(row + 12);
    f2 b0 = mk2(q0.x, q0.y), b1 = mk2(q0.z, q0.w), b2 = mk2(q1.x, q1.y), b3 = mk2(q1.z, q1.w);
    f2 b4 = mk2(q2.x, q2.y), b5 = mk2(q2.z, q2.w), b6 = mk2(q3.x, q3.y), b7 = mk2(q3.z, q3.w);
    o1[0] += c1 * b0; o1[1] += c1 * b1; o1[2] += c1 * b2; o1[3] += c1 * b3;
    o1[4] += c1 * b4; o1[5] += c1 * b5; o1[6] += c1 * b6; o1[7] += c1 * b7;
    o2[0] += c2 * b0; o2[1] += c2 * b1; o2[2] += c2 * b2; o2[3] += c2 * b3;
    o2[4] += c2 * b4; o2[5] += c2 * b5; o2[6] += c2 * b6; o2[7] += c2 * b7;
  }
}

// stage 4 contiguous 16x16 matrices (1024 floats) from global into XLD/GSTR layout
__device__ __forceinline__ void stage4(const float* __restrict__ src, float* __restrict__ dst, int lid) {
  #pragma unroll
  for (int i = 0; i < 4; ++i) {
    int f = (i * 64 + lid) * 4;       // float index in the contiguous source
    int m = f >> 8, w = f & 255;      // matrix, within-matrix
    *(float4*)(dst + m * GSTR + (w >> 4) * XLD + (w & 15)) = *(const float4*)(src + f);
  }
}

__device__ __forceinline__ void store_rows(float* __restrict__ RBg, int c, const f2 a[8]) {
  #pragma unroll
  for (int i = 0; i < 4; ++i)
    *(float4*)(RBg + c * XLD + 4 * i) = make_float4(a[2 * i].x, a[2 * i].y, a[2 * i + 1].x, a[2 * i + 1].y);
}

__device__ __forceinline__ void load_pairs(const float* __restrict__ src, f2 a[8], float scale) {
  #pragma unroll
  for (int i = 0; i < 4; ++i) {
    float4 v = *(const float4*)(src + 4 * i);
    a[2 * i]     = mk2(v.x * scale, v.y * scale);
    a[2 * i + 1] = mk2(v.z * scale, v.w * scale);
  }
}

__device__ __forceinline__ void store_pairs_g(float* __restrict__ dst, const f2 a[8]) {
  #pragma unroll
  for (int i = 0; i < 4; ++i)
    *(float4*)(dst + 4 * i) = make_float4(a[2 * i].x, a[2 * i].y, a[2 * i + 1].x, a[2 * i + 1].y);
}

// ---------------- Step 1: rm accumulation (float4 loads) ----------------
__global__ __launch_bounds__(256) void rm_mean_kernel(const float* __restrict__ x, float* __restrict__ rmsum) {
  int n = blockIdx.y;
  int tid = threadIdx.x;
  long base = (long)n * SS * 256 + (long)blockIdx.x * 128 * 256 + tid * 4;
  float4 s = make_float4(0.f, 0.f, 0.f, 0.f);
  for (int i = 0; i < 32; ++i) {
    float4 v = *(const float4*)(x + base + (long)i * 1024);
    s.x += v.x; s.y += v.y; s.z += v.z; s.w += v.w;
  }
  int o = (tid * 4) & 255;
  atomicAdd(&rmsum[n * 256 + o],     s.x);
  atomicAdd(&rmsum[n * 256 + o + 1], s.y);
  atomicAdd(&rmsum[n * 256 + o + 2], s.z);
  atomicAdd(&rmsum[n * 256 + o + 3], s.w);
}

// ---------------- Step 2: eigh(rm) -> sq,isq ; Wsq = expm(sym(W)/2) ----------------
__global__ __launch_bounds__(256) void eigh_rm_kernel(const float* __restrict__ rmsum, const float* __restrict__ Wg,
                                                      float* __restrict__ sqrm, float* __restrict__ isqrm,
                                                      float* __restrict__ wsqo) {
  __shared__ __align__(16) float lds[4 * 1440];
  int tid = threadIdx.x;
  int wv = tid >> 6, lid = tid & 63, g = lid >> 4, c = lid & 15;
  float* Wr = lds + wv * 1440;
  float* RB = Wr;                 // 4 x GSTR
  float* G1 = Wr + 4 * GSTR;      // 64
  float* G2 = Wr + 4 * GSTR + 64; // 64
  int gid_raw = blockIdx.x * 16 + wv * 4 + g;
  int gid = gid_raw > 32 ? 32 : gid_raw;
  f2 a[8];
  if (gid < 32) {
    load_pairs(rmsum + gid * 256 + c * 16, a, 1.f / (float)SS);
  } else {
    #pragma unroll
    for (int k = 0; k < 8; ++k) {
      a[k].x = 0.5f * (Wg[c * 16 + 2 * k]     + Wg[(2 * k) * 16 + c]);
      a[k].y = 0.5f * (Wg[c * 16 + 2 * k + 1] + Wg[(2 * k + 1) * 16 + c]);
    }
  }
  // Gershgorin shift (only applied to the possibly-indefinite W matrix)
  float rs = 0.f;
  #pragma unroll
  for (int k = 0; k < 8; ++k) rs += fabsf(a[k].x) + fabsf(a[k].y);
  rs = fmaxf(rs, lxor<1>(rs)); rs = fmaxf(rs, lxor<2>(rs));
  rs = fmaxf(rs, lxor<4>(rs)); rs = fmaxf(rs, lxor<8>(rs));
  float sig = (gid == 32) ? (rs + 0.001f) : 0.f;
  #pragma unroll
  for (int k = 0; k < 8; ++k) {
    a[k].x += (2 * k     == c) ? sig : 0.f;
    a[k].y += (2 * k + 1 == c) ? sig : 0.f;
  }
  float d;
  jacobi_os(a, d, c, SW_SMALL);
  float g1c, g2c;
  if (gid < 32) {
    float sqd = __builtin_amdgcn_sqrtf(d);
    float qd  = __builtin_amdgcn_sqrtf(sqd);            // d^{1/4}
    g1c = qd * __builtin_amdgcn_rcpf(d);                // d^{-3/4}: sqrtm
    g2c = __builtin_amdgcn_rcpf(d * qd);                // d^{-5/4}: invsqrtm
  } else {
    float lam = __builtin_amdgcn_sqrtf(d);
    g1c = __expf(0.5f * (lam - sig)) * __builtin_amdgcn_rcpf(fmaxf(d, 1e-30f));
    g2c = 0.f;
  }
  float* RBg = RB + g * GSTR;
  store_rows(RBg, c, a);
  G1[g * 16 + c] = g1c;
  G2[g * 16 + c] = g2c;
  __builtin_amdgcn_wave_barrier();
  f2 o1[8], o2[8];
  recon2_16<XLD>(RBg, G1 + g * 16, G2 + g * 16, c, o1, o2);
  if (gid_raw < 32) {
    store_pairs_g(sqrm  + gid * 256 + c * 16, o1);
    store_pairs_g(isqrm + gid * 256 + c * 16, o2);
  } else if (gid_raw == 32) {
    store_pairs_g(wsqo + c * 16, o1);
  }
}

// ---------------- Step 3: pass 1 — sum_s logm(isq_rm X isq_rm) ----------------
#define WSZ1 (4 * GSTR + XLD * 16 + 64)   // 1696
__global__ __launch_bounds__(256) __attribute__((amdgpu_waves_per_eu(4, 4)))
void pass1_kernel(const float* __restrict__ x, const float* __restrict__ isqrm,
                  float* __restrict__ gtsum) {
  __shared__ __align__(16) float lds[4 * WSZ1 + 1024];
  int tid = threadIdx.x;
  int wv = tid >> 6, lid = tid & 63, g = lid >> 4, c = lid & 15;
  int n = blockIdx.y;
  int s_base = blockIdx.x * 16 + wv * 4;
  float* Wr  = lds + wv * WSZ1;
  float* Xs  = Wr;                      // 4 x GSTR; reused as recon buf
  float* ISQ = Wr + 4 * GSTR;           // 16 x XLD
  float* GB  = Wr + 4 * GSTR + XLD * 16;// 64
  float* red = lds + 4 * WSZ1;          // 1024 (cross-wave reduce)
  stage4(x + ((long)n * SS + s_base) * 256, Xs, lid);
  const float* isqn = isqrm + n * 256;
  for (int i = lid; i < 256; i += 64) ISQ[(i >> 4) * XLD + (i & 15)] = isqn[i];
  __builtin_amdgcn_wave_barrier();
  f2 mc[8], y[8], a[8];
  load_pairs(ISQ + c * XLD, mc, 1.f);
  mv_lds<XLD>(Xs + g * GSTR, mc, y);
  mv_lds<XLD>(ISQ, y, a);
  float d;
  jacobi_os(a, d, c, SW_PASS);
  float gc = 0.5f * __logf(fmaxf(d, 1e-30f)) * __builtin_amdgcn_rcpf(d);
  float* RBg = Xs + g * GSTR;   // X is dead; reuse
  store_rows(RBg, c, a);
  GB[g * 16 + c] = gc;
  __builtin_amdgcn_wave_barrier();
  f2 out[8];
  recon16<XLD>(RBg, GB + g * 16, c, out);
  #pragma unroll
  for (int k = 0; k < 8; ++k) {
    out[k].x += __shfl_xor(out[k].x, 16);
    out[k].y += __shfl_xor(out[k].y, 16);
  }
  #pragma unroll
  for (int k = 0; k < 8; ++k) {
    out[k].x += __shfl_xor(out[k].x, 32);
    out[k].y += __shfl_xor(out[k].y, 32);
  }
  if (g == 0) store_pairs_g(red + wv * 256 + c * 16, out);
  __syncthreads();
  float v = red[tid] + red[256 + tid] + red[512 + tid] + red[768 + tid];
  atomicAdd(&gtsum[n * 256 + tid], v);
}

// ---------------- Step 4: x_mean chain -> isq_m, lt_mean ----------------
#define WSZ4 (8 * GSTR + 128)   // 2752
__global__ __launch_bounds__(256) void mean_update_kernel(const float* __restrict__ gtsum, const float* __restrict__ sqrm,
                                                          float* __restrict__ isqm, float* __restrict__ ltmean) {
  __shared__ __align__(16) float lds[4 * WSZ4];
  int tid = threadIdx.x;
  int wv = tid >> 6, lid = tid & 63, g = lid >> 4, c = lid & 15;
  int n0 = blockIdx.x * 16 + wv * 4 + g;
  float* Wr = lds + wv * WSZ4;
  float* RB = Wr;                  // 4 x GSTR
  float* SQ = Wr + 4 * GSTR;       // 4 x GSTR
  float* G1 = Wr + 8 * GSTR;       // 64
  float* G2 = Wr + 8 * GSTR + 64;  // 64
  // ---- eigh(gt) (indefinite -> shift), expm ----
  f2 a[8];
  load_pairs(gtsum + n0 * 256 + c * 16, a, 1.f / (float)SS);
  float rs = 0.f;
  #pragma unroll
  for (int k = 0; k < 8; ++k) rs += fabsf(a[k].x) + fabsf(a[k].y);
  rs = fmaxf(rs, lxor<1>(rs)); rs = fmaxf(rs, lxor<2>(rs));
  rs = fmaxf(rs, lxor<4>(rs)); rs = fmaxf(rs, lxor<8>(rs));
  float sig = rs + 0.001f;
  #pragma unroll
  for (int k = 0; k < 8; ++k) {
    a[k].x += (2 * k     == c) ? sig : 0.f;
    a[k].y += (2 * k + 1 == c) ? sig : 0.f;
  }
  float d;
  jacobi_os(a, d, c, SW_SMALL);
  float lam = __builtin_amdgcn_sqrtf(d);
  float gc = __expf(lam - sig) * __builtin_amdgcn_rcpf(fmaxf(d, 1e-30f));
  float* RBg = RB + g * GSTR;
  store_rows(RBg, c, a);
  G1[g * 16 + c] = gc;
  __builtin_amdgcn_wave_barrier();
  f2 e1[8];
  recon16<XLD>(RBg, G1 + g * 16, c, e1);
  // ---- stage sq_rm (4 consecutive n for this wave) ----
  stage4(sqrm + (blockIdx.x * 16 + wv * 4) * 256, SQ, lid);
  __builtin_amdgcn_wave_barrier();
  store_rows(RBg, c, e1);
  __builtin_amdgcn_wave_barrier();
  float* SQg = SQ + g * GSTR;
  f2 mc[8], y[8], a2[8];
  load_pairs(SQg + c * XLD, mc, 1.f);
  mv_lds<XLD>(RBg, mc, y);    // expm(gt) * sq_col
  mv_lds<XLD>(SQg, y, a2);    // sq * y -> col c of x_mean
  float d2;
  jacobi_os(a2, d2, c, SW_SMALL);
  float sqd = __builtin_amdgcn_sqrtf(d2);
  float qd  = __builtin_amdgcn_sqrtf(sqd);
  float g1c = __builtin_amdgcn_rcpf(d2 * qd);                                  // d^{-5/4}: invsqrtm
  float g2c = 0.5f * __logf(fmaxf(d2, 1e-30f)) * __builtin_amdgcn_rcpf(d2);   // logm
  store_rows(RBg, c, a2);
  G1[g * 16 + c] = g1c;
  G2[g * 16 + c] = g2c;
  __builtin_amdgcn_wave_barrier();
  f2 o1[8], o2[8];
  recon2_16<XLD>(RBg, G1 + g * 16, G2 + g * 16, c, o1, o2);
  store_pairs_g(isqm + n0 * 256 + c * 16, o1);
  #pragma unroll
  for (int k = 0; k < 8; ++k) {
    int r0 = 2 * k, r1 = 2 * k + 1;
    if (r0 >= c) ltmean[n0 * D0 + (r0 * (r0 + 1) / 2) + c] = o2[k].x * ((r0 == c) ? 1.f : SQRT2F);
    if (r1 >= c) ltmean[n0 * D0 + (r1 * (r1 + 1) / 2) + c] = o2[k].y * ((r1 == c) ? 1.f : SQRT2F);
  }
}

// ---------------- Step 5: pass 2 — xc = tril(Wsq logm(isq_m X isq_m) Wsq) ----------------
#define WSZ2 (4 * GSTR + 2 * XLD * 16 + 64)   // 2016
__global__ __launch_bounds__(256) __attribute__((amdgpu_waves_per_eu(4, 4)))
void pass2_kernel(const float* __restrict__ x, const float* __restrict__ isqm,
                  const float* __restrict__ wsqg, float* __restrict__ xc) {
  __shared__ __align__(16) float lds[4 * WSZ2];
  int tid = threadIdx.x;
  int wv = tid >> 6, lid = tid & 63, g = lid >> 4, c = lid & 15;
  int n = blockIdx.y;
  int s_base = blockIdx.x * 16 + wv * 4;
  float* Wr  = lds + wv * WSZ2;
  float* Xs  = Wr;                           // 4 x GSTR; reused as recon buf
  float* ISQ = Wr + 4 * GSTR;                // 16 x XLD
  float* WSQ = Wr + 4 * GSTR + XLD * 16;     // 16 x XLD
  float* GB  = Wr + 4 * GSTR + 2 * XLD * 16; // 64
  stage4(x + ((long)n * SS + s_base) * 256, Xs, lid);
  const float* isqn = isqm + n * 256;
  for (int i = lid; i < 256; i += 64) {
    int r = i >> 4, cc = i & 15;
    ISQ[r * XLD + cc] = isqn[i];
    WSQ[r * XLD + cc] = wsqg[i];
  }
  __builtin_amdgcn_wave_barrier();
  f2 mc[8], y[8], a[8];
  load_pairs(ISQ + c * XLD, mc, 1.f);
  mv_lds<XLD>(Xs + g * GSTR, mc, y);
  mv_lds<XLD>(ISQ, y, a);
  float d;
  jacobi_os(a, d, c, SW_PASS);
  float gc = 0.5f * __logf(fmaxf(d, 1e-30f)) * __builtin_amdgcn_rcpf(d);
  f2 b[8];
  mv_lds<XLD>(WSQ, a, b);   // fold outer Wsq sandwich into the recon columns
  float* RBg = Xs + g * GSTR;
  store_rows(RBg, c, b);
  GB[g * 16 + c] = gc;
  __builtin_amdgcn_wave_barrier();
  f2 out[8];
  recon16<XLD>(RBg, GB + g * 16, c, out);
  long ob = ((long)n * SS + s_base + g) * (long)D0;
  #pragma unroll
  for (int k = 0; k < 8; ++k) {
    int r0 = 2 * k, r1 = 2 * k + 1;
    if (r0 >= c) xc[ob + (r0 * (r0 + 1) / 2) + c] = out[k].x * ((r0 == c) ? 1.f : SQRT2F);
    if (r1 >= c) xc[ob + (r1 * (r1 + 1) / 2) + c] = out[k].y * ((r1 == c) ? 1.f : SQRT2F);
  }
}

// ---------------- Step 6: covariance SYRK (symmetric: 15 of 25 tile pairs) ----------------
__global__ __launch_bounds__(256) void syrk_kernel(const float* __restrict__ xc, float* __restrict__ cov) {
  __shared__ float Ap[32][33];
  __shared__ float Bp[32][33];
  const int TI[15] = {0,0,0,0,0,1,1,1,1,2,2,2,3,3,4};
  const int TJ[15] = {0,1,2,3,4,1,2,3,4,2,3,4,3,4,4};
  int n = blockIdx.y;
  int ti = TI[blockIdx.x], tj = TJ[blockIdx.x];
  int tid = threadIdx.x;
  int tx = tid & 15, ty = tid >> 4;
  float a00 = 0.f, a01 = 0.f, a10 = 0.f, a11 = 0.f;
  const float* xb = xc + (long)n * SS * D0;
  for (int s0 = 0; s0 < SS; s0 += 32) {
    for (int l = tid; l < 1024; l += 256) {
      int ss = l >> 5, ii = l & 31;
      int gi = ti * 32 + ii, gj = tj * 32 + ii;
      const float* row = xb + (long)(s0 + ss) * D0;
      Ap[ss][ii] = (gi < D0) ? row[gi] : 0.f;
      Bp[ss][ii] = (gj < D0) ? row[gj] : 0.f;
    }
    __syncthreads();
    #pragma unroll 8
    for (int ss = 0; ss < 32; ++ss) {
      float x0 = Ap[ss][2 * ty], x1 = Ap[ss][2 * ty + 1];
      float y0 = Bp[ss][2 * tx], y1 = Bp[ss][2 * tx + 1];
      a00 += x0 * y0; a01 += x0 * y1; a10 += x1 * y0; a11 += x1 * y1;
    }
    __syncthreads();
  }
  int i0 = ti * 32 + 2 * ty, j0 = tj * 32 + 2 * tx;
  const float sc = 1.f / (float)(SS - 1);
  long base = (long)n * D0 * D0;
  if (i0 < D0 && j0 < D0)         cov[base + (long)i0 * D0 + j0]           = a00 * sc;
  if (i0 < D0 && j0 + 1 < D0)     cov[base + (long)i0 * D0 + j0 + 1]       = a01 * sc;
  if (i0 + 1 < D0 && j0 < D0)     cov[base + (long)(i0 + 1) * D0 + j0]     = a10 * sc;
  if (i0 + 1 < D0 && j0 + 1 < D0) cov[base + (long)(i0 + 1) * D0 + j0 + 1] = a11 * sc;
  if (ti != tj) {
    if (i0 < D0 && j0 < D0)         cov[base + (long)j0 * D0 + i0]           = a00 * sc;
    if (i0 < D0 && j0 + 1 < D0)     cov[base + (long)(j0 + 1) * D0 + i0]     = a01 * sc;
    if (i0 + 1 < D0 && j0 < D0)     cov[base + (long)j0 * D0 + i0 + 1]       = a10 * sc;
    if (i0 + 1 < D0 && j0 + 1 < D0) cov[base + (long)(j0 + 1) * D0 + i0 + 1] = a11 * sc;
  }
}

// ---------------- Step 7: assemble E skeleton ----------------
__global__ __launch_bounds__(256) void ebuild_kernel(const float* __restrict__ ltmean, float* __restrict__ E) {
  int n = blockIdx.x;
  for (int idx = threadIdx.x; idx < DD * DD; idx += 256) {
    int r = idx / DD, c = idx % DD;
    float v = 0.f;
    if (r >= D0) {
      if (c < D0) v = ltmean[n * D0 + c];
      else        v = (r == c) ? 1.f : 0.f;
    }
    E[(long)n * DD * DD + idx] = v;
  }
}

// ---------------- Cholesky (triangular LDS storage) ----------------
template<int D, int NORM, int WRITE_UPPER>
__global__ __launch_bounds__(256) void chol_kernel(const float* __restrict__ in, long inStride,
                                                   float* __restrict__ out, long outStride, int outLd) {
  __shared__ float As[D * (D + 1) / 2];
  __shared__ float red[256];
  int b = blockIdx.x;
  int tid = threadIdx.x;
  const float* inp = in + (long)b * inStride;
  for (int idx = tid; idx < D * D; idx += 256) {
    int r = idx / D, c2 = idx % D;
    if (c2 <= r) As[(r * (r + 1) / 2) + c2] = inp[idx];
  }
  __syncthreads();
  if (NORM) {
    float p = 0.f;
    for (int i = tid; i < D; i += 256) p += As[(i * (i + 1) / 2) + i];
    red[tid] = p;
    __syncthreads();
    for (int off = 128; off >= 1; off >>= 1) {
      if (tid < off) red[tid] += red[tid + off];
      __syncthreads();
    }
    float inv = 1.f / red[0];
    for (int idx = tid; idx < D * (D + 1) / 2; idx += 256) As[idx] *= inv;
    __syncthreads();
    for (int i = tid; i < D; i += 256) As[(i * (i + 1) / 2) + i] += 1e-5f;
    __syncthreads();
  }
  int tx = tid & 15, ty = tid >> 4;
  for (int k = 0; k < D; ++k) {
    float dkk = As[(k * (k + 1) / 2) + k];
    float dv = sqrtf(dkk);
    float invd = 1.f / dv;
    __syncthreads();
    for (int i = k + 1 + tid; i < D; i += 256) As[(i * (i + 1) / 2) + k] *= invd;
    if (tid == 0) As[(k * (k + 1) / 2) + k] = dv;
    __syncthreads();
    for (int i = k + 1 + ty; i < D; i += 16) {
      float aik = As[(i * (i + 1) / 2) + k];
      int ibase = i * (i + 1) / 2;
      for (int j = k + 1 + tx; j <= i; j += 16) {
        As[ibase + j] -= aik * As[(j * (j + 1) / 2) + k];
      }
    }
    __syncthreads();
  }
  float* op = out + (long)b * outStride;
  for (int idx = tid; idx < D * D; idx += 256) {
    int r = idx / D, c2 = idx % D;
    if (c2 <= r)          op[r * outLd + c2] = As[(r * (r + 1) / 2) + c2];
    else if (WRITE_UPPER) op[r * outLd + c2] = 0.f;
  }
}

// ---------------- generic 152x152 GEMM: C = alpha*A@B (+I) ----------------
__global__ __launch_bounds__(256) void gemm152_kernel(const float* __restrict__ A, long sA,
                                                      const float* __restrict__ B, float* __restrict__ Cm,
                                                      long sC, float alpha, int addI) {
  __shared__ float As[16][17];
  __shared__ float Bs[16][17];
  int b = blockIdx.y;
  const float* Ab_ = A + (long)b * sA;
  float* Cb = Cm + (long)b * sC;
  int tid = threadIdx.x;
  int tx = tid & 15, ty = tid >> 4;
  int row0 = (blockIdx.x / 10) * 16, col0 = (blockIdx.x % 10) * 16;
  float acc = 0.f;
  for (int k0 = 0; k0 < DD; k0 += 16) {
    int ar = row0 + ty, ac = k0 + tx;
    As[ty][tx] = (ar < DD && ac < DD) ? Ab_[ar * DD + ac] : 0.f;
    int br = k0 + ty, bc = col0 + tx;
    Bs[ty][tx] = (br < DD && bc < DD) ? B[br * DD + bc] : 0.f;
    __syncthreads();
    #pragma unroll
    for (int kk = 0; kk < 16; ++kk) acc += As[ty][kk] * Bs[kk][tx];
    __syncthreads();
  }
  int r = row0 + ty, c2 = col0 + tx;
  if (r < DD && c2 < DD) Cb[r * DD + c2] = alpha * acc + ((addI && r == c2) ? 1.f : 0.f);
}

__global__ __launch_bounds__(256) void wlw_prep_kernel(const float* __restrict__ Wlw, float* __restrict__ Bm) {
  int idx = blockIdx.x * 256 + threadIdx.x;
  if (idx < DD * DD) {
    int r = idx / DD, c = idx % DD;
    Bm[idx] = 0.5f * (Wlw[idx] + Wlw[c * DD + r]) * (1.f / 16.f);
  }
}

__global__ __launch_bounds__(256) void taylor_init_kernel(const float* __restrict__ Bm, float* __restrict__ P) {
  int idx = blockIdx.x * 256 + threadIdx.x;
  if (idx < DD * DD) {
    int r = idx / DD, c = idx % DD;
    P[idx] = Bm[idx] * (1.f / 6.f) + ((r == c) ? 1.f : 0.f);
  }
}

extern "C" void kernel_launch(void* const* d_in, const int* in_sizes, int n_in,
                              void* d_out, int out_size, void* d_ws, size_t ws_size,
                              hipStream_t stream) {
  (void)in_sizes; (void)n_in; (void)out_size; (void)ws_size;
  const float* x   = (const float*)d_in[0];
  const float* W   = (const float*)d_in[1];
  const float* Wlw = (const float*)d_in[2];
  float* ws = (float*)d_ws;
  size_t off = 0;
  float* rmsum  = ws + off; off += 32 * 256;
  float* gtsum  = ws + off; off += 32 * 256;
  float* sqrm   = ws + off; off += 32 * 256;
  float* isqrm  = ws + off; off += 32 * 256;
  float* wsqb   = ws + off; off += 256;
  float* isqm   = ws + off; off += 32 * 256;
  float* ltmean = ws + off; off += 32 * D0;
  float* cov    = ws + off; off += (size_t)32 * D0 * D0;
  float* E      = ws + off; off += (size_t)32 * DD * DD;
  float* Bm     = ws + off; off += DD * DD;
  float* Pa     = ws + off; off += DD * DD;
  float* Pb     = ws + off; off += DD * DD;
  float* Rm     = ws + off; off += DD * DD;
  float* xcbuf  = ws + off; off += (size_t)32 * SS * D0;
  float* outp   = (float*)d_out;

  hipMemsetAsync(rmsum, 0, 2 * 32 * 256 * sizeof(float), stream);

  rm_mean_kernel    <<<dim3(25, 32),  256, 0, stream>>>(x, rmsum);
  eigh_rm_kernel    <<<3,             256, 0, stream>>>(rmsum, W, sqrm, isqrm, wsqb);
  pass1_kernel      <<<dim3(200, 32), 256, 0, stream>>>(x, isqrm, gtsum);
  mean_update_kernel<<<2,             256, 0, stream>>>(gtsum, sqrm, isqm, ltmean);
  pass2_kernel      <<<dim3(200, 32), 256, 0, stream>>>(x, isqm, wsqb, xcbuf);
  syrk_kernel       <<<dim3(15, 32),  256, 0, stream>>>(xcbuf, cov);
  ebuild_kernel     <<<32,            256, 0, stream>>>(ltmean, E);
  chol_kernel<D0, 1, 0><<<32,         256, 0, stream>>>(cov, (long)D0 * D0, E, (long)DD * DD, DD);

  // R = chol(expm(sym(W_lw))): scaling 1/16, Taylor order 6 (err ~7e-10), square 4x
  wlw_prep_kernel   <<<(DD * DD + 255) / 256, 256, 0, stream>>>(Wlw, Bm);
  taylor_init_kernel<<<(DD * DD + 255) / 256, 256, 0, stream>>>(Bm, Pa);
  float* Pcur = Pa; float* Pnext = Pb;
  for (int k = 5; k >= 1; --k) {
    gemm152_kernel<<<dim3(100, 1), 256, 0, stream>>>(Bm, 0L, Pcur, Pnext, 0L, 1.f / (float)k, 1);
    float* t = Pcur; Pcur = Pnext; Pnext = t;
  }
  for (int i = 0; i < 4; ++i) {
    gemm152_kernel<<<dim3(100, 1), 256, 0, stream>>>(Pcur, 0L, Pcur, Pnext, 0L, 1.f, 0);
    float* t = Pcur; Pcur = Pnext; Pnext = t;
  }
  chol_kernel<DD, 0, 1><<<1, 256, 0, stream>>>(Pcur, 0L, Rm, 0L, DD);

  gemm152_kernel<<<dim3(100, 32), 256, 0, stream>>>(E, (long)DD * DD, Rm, outp, (long)DD * DD, 1.f, 0);
}

// Round 5
// 1998.427 us; speedup vs baseline: 6.5758x; 1.0355x over previous
//
#include <hip/hip_runtime.h>
#include <math.h>

// Problem constants (fixed by setup_inputs)
#define NN   32
#define SS   3200
#define CC   16
#define XLD  20      // row stride (floats) inside a 16x16 matrix slot
#define GSTR 328     // per-group matrix slot stride: bank offsets {0,8,16,24} across groups
#define D0   136     // C*(C+1)/2
#define DD   152     // D0 + k
#define SQRT2F 1.41421356237309515f
#define SW_PASS 5    // sweeps for the two big per-sample passes
#define SW_SMALL 8   // sweeps for the tiny per-n chains

typedef float f2 __attribute__((ext_vector_type(2)));
__device__ __forceinline__ f2 mk2(float x, float y) { f2 r; r.x = x; r.y = y; return r; }

#define PHASE __builtin_amdgcn_sched_barrier(0)

// ---------------- cross-lane xor within 16-lane groups ----------------
template<int M> __device__ __forceinline__ float lxor(float x) {
  int v = __float_as_int(x);
  int r;
  if      constexpr (M == 1)  r = __builtin_amdgcn_update_dpp(0, v, 0xB1, 0xF, 0xF, true);  // quad_perm [1,0,3,2]
  else if constexpr (M == 2)  r = __builtin_amdgcn_update_dpp(0, v, 0x4E, 0xF, 0xF, true);  // quad_perm [2,3,0,1]
  else if constexpr (M == 3)  r = __builtin_amdgcn_update_dpp(0, v, 0x1B, 0xF, 0xF, true);  // quad_perm [3,2,1,0]
  else if constexpr (M == 7)  r = __builtin_amdgcn_update_dpp(0, v, 0x141, 0xF, 0xF, true); // row_half_mirror
  else if constexpr (M == 8)  r = __builtin_amdgcn_update_dpp(0, v, 0x128, 0xF, 0xF, true); // row_ror:8
  else if constexpr (M == 15) r = __builtin_amdgcn_update_dpp(0, v, 0x140, 0xF, 0xF, true); // row_mirror
  else r = __builtin_amdgcn_ds_swizzle(v, 0x1F | (M << 10));                                // BitMode xor
  return __int_as_float(r);
}

// ---------------- one-sided Jacobi round: pairs (i, i^M) ----------------
template<int M>
__device__ __forceinline__ void js_round(f2 a[8], float& d, int c) {
  f2 part[8];
  #pragma unroll
  for (int r = 0; r < 8; ++r) {
    part[r].x = lxor<M>(a[r].x);
    part[r].y = lxor<M>(a[r].y);
  }
  float pd = lxor<M>(d);
  f2 s0 = a[0] * part[0];
  f2 s1 = a[1] * part[1];
  f2 s2 = a[2] * part[2];
  f2 s3 = a[3] * part[3];
  s0 += a[4] * part[4];
  s1 += a[5] * part[5];
  s2 += a[6] * part[6];
  s3 += a[7] * part[7];
  f2 sv = (s0 + s1) + (s2 + s3);
  float apq = sv.x + sv.y;
  int partner = c ^ M;
  bool isp = c < partner;
  float app = isp ? d : pd;
  float aqq = isp ? pd : d;
  float theta = (aqq - app) * 0.5f * __builtin_amdgcn_rcpf(apq);
  float t = copysignf(__builtin_amdgcn_rcpf(fabsf(theta) + __builtin_amdgcn_sqrtf(1.f + theta * theta)), theta);
  t = (apq == 0.f) ? 0.f : t;
  float cs = __builtin_amdgcn_rsqf(1.f + t * t);
  float sn = t * cs;
  float se = isp ? -sn : sn;
  f2 pcs = mk2(cs, cs);
  f2 pse = mk2(se, se);
  #pragma unroll
  for (int r = 0; r < 8; ++r) a[r] = pcs * a[r] + pse * part[r];
  d = isp ? (app - t * apq) : (aqq + t * apq);
}

__device__ __forceinline__ void js_sweep(f2 a[8], float& d, int c) {
  js_round<1>(a, d, c);  js_round<2>(a, d, c);  js_round<3>(a, d, c);
  js_round<4>(a, d, c);  js_round<5>(a, d, c);  js_round<6>(a, d, c);
  js_round<7>(a, d, c);  js_round<8>(a, d, c);  js_round<9>(a, d, c);
  js_round<10>(a, d, c); js_round<11>(a, d, c); js_round<12>(a, d, c);
  js_round<13>(a, d, c); js_round<14>(a, d, c); js_round<15>(a, d, c);
}

__device__ __forceinline__ float colnorm2(const f2 a[8]) {
  f2 s0 = a[0] * a[0], s1 = a[1] * a[1], s2 = a[2] * a[2], s3 = a[3] * a[3];
  s0 += a[4] * a[4]; s1 += a[5] * a[5]; s2 += a[6] * a[6]; s3 += a[7] * a[7];
  f2 s = (s0 + s1) + (s2 + s3);
  return s.x + s.y;
}

// a: column c of symmetric M (packed pairs). Exit: a = lam_c * v_c, d = lam_c^2.
__device__ __forceinline__ void jacobi_os(f2 a[8], float& d, int c, int sweeps) {
  d = colnorm2(a);
  #pragma unroll 1
  for (int s = 0; s < sweeps; ++s) js_sweep(a, d, c);
  d = colnorm2(a);
}

// ---------------- row dot: dot(M_row, v) ----------------
__device__ __forceinline__ float dotrow(const float* __restrict__ row, const f2 v[8]) {
  const float4 q0 = *(const float4*)(row + 0);
  const float4 q1 = *(const float4*)(row + 4);
  const float4 q2 = *(const float4*)(row + 8);
  const float4 q3 = *(const float4*)(row + 12);
  f2 s0 = mk2(q0.x, q0.y) * v[0] + mk2(q0.z, q0.w) * v[1];
  f2 s1 = mk2(q1.x, q1.y) * v[2] + mk2(q1.z, q1.w) * v[3];
  s0 += mk2(q2.x, q2.y) * v[4] + mk2(q2.z, q2.w) * v[5];
  s1 += mk2(q3.x, q3.y) * v[6] + mk2(q3.z, q3.w) * v[7];
  f2 s = s0 + s1;
  return s.x + s.y;
}

// y = Mat(16x16, LDS rows stride S) * v  (v, y packed by row pairs)
template<int S>
__device__ __forceinline__ void mv_lds(const float* __restrict__ M, const f2 v[8], f2 y[8]) {
  #pragma unroll
  for (int k = 0; k < 8; ++k) {
    float r0 = dotrow(M + (2 * k) * S, v);
    float r1 = dotrow(M + (2 * k + 1) * S, v);
    y[k] = mk2(r0, r1);
  }
}

// out (packed rows) = col c of Sum_i gb[i] * b_i b_i^T ; B row i = b_i (row stride S)
template<int S>
__device__ __forceinline__ void recon16(const float* __restrict__ B, const float* __restrict__ gb,
                                        int c, f2 o[8]) {
  #pragma unroll
  for (int k = 0; k < 8; ++k) o[k] = mk2(0.f, 0.f);
  #pragma unroll
  for (int i = 0; i < CC; ++i) {
    const float* row = B + i * S;
    float coef = gb[i] * row[c];
    f2 pc = mk2(coef, coef);
    const float4 q0 = *(const float4*)(row + 0);
    const float4 q1 = *(const float4*)(row + 4);
    const float4 q2 = *(const float4*)(row + 8);
    const float4 q3 = *(const float4*)(row + 12);
    o[0] += pc * mk2(q0.x, q0.y); o[1] += pc * mk2(q0.z, q0.w);
    o[2] += pc * mk2(q1.x, q1.y); o[3] += pc * mk2(q1.z, q1.w);
    o[4] += pc * mk2(q2.x, q2.y); o[5] += pc * mk2(q2.z, q2.w);
    o[6] += pc * mk2(q3.x, q3.y); o[7] += pc * mk2(q3.z, q3.w);
  }
}

template<int S>
__device__ __forceinline__ void recon2_16(const float* __restrict__ B, const float* __restrict__ g1,
                                          const float* __restrict__ g2, int c,
                                          f2 o1[8], f2 o2[8]) {
  #pragma unroll
  for (int k = 0; k < 8; ++k) { o1[k] = mk2(0.f, 0.f); o2[k] = mk2(0.f, 0.f); }
  #pragma unroll
  for (int i = 0; i < CC; ++i) {
    const float* row = B + i * S;
    float bic = row[c];
    f2 c1 = mk2(g1[i] * bic, g1[i] * bic);
    f2 c2 = mk2(g2[i] * bic, g2[i] * bic);
    const float4 q0 = *(const float4*)(row + 0);
    const float4 q1 = *(const float4*)(row + 4);
    const float4 q2 = *(const float4*)(row + 8);
    const float4 q3 = *(const float4*)(row + 12);
    f2 b0 = mk2(q0.x, q0.y), b1 = mk2(q0.z, q0.w), b2 = mk2(q1.x, q1.y), b3 = mk2(q1.z, q1.w);
    f2 b4 = mk2(q2.x, q2.y), b5 = mk2(q2.z, q2.w), b6 = mk2(q3.x, q3.y), b7 = mk2(q3.z, q3.w);
    o1[0] += c1 * b0; o1[1] += c1 * b1; o1[2] += c1 * b2; o1[3] += c1 * b3;
    o1[4] += c1 * b4; o1[5] += c1 * b5; o1[6] += c1 * b6; o1[7] += c1 * b7;
    o2[0] += c2 * b0; o2[1] += c2 * b1; o2[2] += c2 * b2; o2[3] += c2 * b3;
    o2[4] += c2 * b4; o2[5] += c2 * b5; o2[6] += c2 * b6; o2[7] += c2 * b7;
  }
}

// stage 4 contiguous 16x16 matrices (1024 floats) from global into XLD/GSTR layout
__device__ __forceinline__ void stage4(const float* __restrict__ src, float* __restrict__ dst, int lid) {
  #pragma unroll
  for (int i = 0; i < 4; ++i) {
    int f = (i * 64 + lid) * 4;       // float index in the contiguous source
    int m = f >> 8, w = f & 255;      // matrix, within-matrix
    *(float4*)(dst + m * GSTR + (w >> 4) * XLD + (w & 15)) = *(const float4*)(src + f);
  }
}

__device__ __forceinline__ void store_rows(float* __restrict__ RBg, int c, const f2 a[8]) {
  #pragma unroll
  for (int i = 0; i < 4; ++i)
    *(float4*)(RBg + c * XLD + 4 * i) = make_float4(a[2 * i].x, a[2 * i].y, a[2 * i + 1].x, a[2 * i + 1].y);
}

__device__ __forceinline__ void load_pairs(const float* __restrict__ src, f2 a[8], float scale) {
  #pragma unroll
  for (int i = 0; i < 4; ++i) {
    float4 v = *(const float4*)(src + 4 * i);
    a[2 * i]     = mk2(v.x * scale, v.y * scale);
    a[2 * i + 1] = mk2(v.z * scale, v.w * scale);
  }
}

__device__ __forceinline__ void store_pairs_g(float* __restrict__ dst, const f2 a[8]) {
  #pragma unroll
  for (int i = 0; i < 4; ++i)
    *(float4*)(dst + 4 * i) = make_float4(a[2 * i].x, a[2 * i].y, a[2 * i + 1].x, a[2 * i + 1].y);
}

// ---------------- Step 1: rm accumulation (float4 loads) ----------------
__global__ __launch_bounds__(256) void rm_mean_kernel(const float* __restrict__ x, float* __restrict__ rmsum) {
  int n = blockIdx.y;
  int tid = threadIdx.x;
  long base = (long)n * SS * 256 + (long)blockIdx.x * 128 * 256 + tid * 4;
  float4 s = make_float4(0.f, 0.f, 0.f, 0.f);
  for (int i = 0; i < 32; ++i) {
    float4 v = *(const float4*)(x + base + (long)i * 1024);
    s.x += v.x; s.y += v.y; s.z += v.z; s.w += v.w;
  }
  int o = (tid * 4) & 255;
  atomicAdd(&rmsum[n * 256 + o],     s.x);
  atomicAdd(&rmsum[n * 256 + o + 1], s.y);
  atomicAdd(&rmsum[n * 256 + o + 2], s.z);
  atomicAdd(&rmsum[n * 256 + o + 3], s.w);
}

// ---------------- Step 2: eigh(rm) -> sq,isq ; Wsq = expm(sym(W)/2) ----------------
__global__ __launch_bounds__(256) void eigh_rm_kernel(const float* __restrict__ rmsum, const float* __restrict__ Wg,
                                                      float* __restrict__ sqrm, float* __restrict__ isqrm,
                                                      float* __restrict__ wsqo) {
  __shared__ __align__(16) float lds[4 * 1440];
  int tid = threadIdx.x;
  int wv = tid >> 6, lid = tid & 63, g = lid >> 4, c = lid & 15;
  float* Wr = lds + wv * 1440;
  float* RB = Wr;                 // 4 x GSTR
  float* G1 = Wr + 4 * GSTR;      // 64
  float* G2 = Wr + 4 * GSTR + 64; // 64
  int gid_raw = blockIdx.x * 16 + wv * 4 + g;
  int gid = gid_raw > 32 ? 32 : gid_raw;
  f2 a[8];
  if (gid < 32) {
    load_pairs(rmsum + gid * 256 + c * 16, a, 1.f / (float)SS);
  } else {
    #pragma unroll
    for (int k = 0; k < 8; ++k) {
      a[k].x = 0.5f * (Wg[c * 16 + 2 * k]     + Wg[(2 * k) * 16 + c]);
      a[k].y = 0.5f * (Wg[c * 16 + 2 * k + 1] + Wg[(2 * k + 1) * 16 + c]);
    }
  }
  // Gershgorin shift (only applied to the possibly-indefinite W matrix)
  float rs = 0.f;
  #pragma unroll
  for (int k = 0; k < 8; ++k) rs += fabsf(a[k].x) + fabsf(a[k].y);
  rs = fmaxf(rs, lxor<1>(rs)); rs = fmaxf(rs, lxor<2>(rs));
  rs = fmaxf(rs, lxor<4>(rs)); rs = fmaxf(rs, lxor<8>(rs));
  float sig = (gid == 32) ? (rs + 0.001f) : 0.f;
  #pragma unroll
  for (int k = 0; k < 8; ++k) {
    a[k].x += (2 * k     == c) ? sig : 0.f;
    a[k].y += (2 * k + 1 == c) ? sig : 0.f;
  }
  float d;
  jacobi_os(a, d, c, SW_SMALL);
  float g1c, g2c;
  if (gid < 32) {
    float sqd = __builtin_amdgcn_sqrtf(d);
    float qd  = __builtin_amdgcn_sqrtf(sqd);            // d^{1/4}
    g1c = qd * __builtin_amdgcn_rcpf(d);                // d^{-3/4}: sqrtm
    g2c = __builtin_amdgcn_rcpf(d * qd);                // d^{-5/4}: invsqrtm
  } else {
    float lam = __builtin_amdgcn_sqrtf(d);
    g1c = __expf(0.5f * (lam - sig)) * __builtin_amdgcn_rcpf(fmaxf(d, 1e-30f));
    g2c = 0.f;
  }
  float* RBg = RB + g * GSTR;
  store_rows(RBg, c, a);
  G1[g * 16 + c] = g1c;
  G2[g * 16 + c] = g2c;
  __builtin_amdgcn_wave_barrier();
  f2 o1[8], o2[8];
  recon2_16<XLD>(RBg, G1 + g * 16, G2 + g * 16, c, o1, o2);
  if (gid_raw < 32) {
    store_pairs_g(sqrm  + gid * 256 + c * 16, o1);
    store_pairs_g(isqrm + gid * 256 + c * 16, o2);
  } else if (gid_raw == 32) {
    store_pairs_g(wsqo + c * 16, o1);
  }
}

// ---------------- Step 3: pass 1 — sum_s logm(isq_rm X isq_rm) ----------------
#define WSZ1 (4 * GSTR + XLD * 16 + 64)   // 1696
__global__ __launch_bounds__(256)
void pass1_kernel(const float* __restrict__ x, const float* __restrict__ isqrm,
                  float* __restrict__ gtsum) {
  __shared__ __align__(16) float lds[4 * WSZ1 + 1024];
  int tid = threadIdx.x;
  int wv = tid >> 6, lid = tid & 63, g = lid >> 4, c = lid & 15;
  int n = blockIdx.y;
  int s_base = blockIdx.x * 16 + wv * 4;
  float* Wr  = lds + wv * WSZ1;
  float* Xs  = Wr;                      // 4 x GSTR; reused as recon buf
  float* ISQ = Wr + 4 * GSTR;           // 16 x XLD
  float* GB  = Wr + 4 * GSTR + XLD * 16;// 64
  float* red = lds + 4 * WSZ1;          // 1024 (cross-wave reduce)
  stage4(x + ((long)n * SS + s_base) * 256, Xs, lid);
  const float* isqn = isqrm + n * 256;
  for (int i = lid; i < 256; i += 64) ISQ[(i >> 4) * XLD + (i & 15)] = isqn[i];
  __builtin_amdgcn_wave_barrier();
  PHASE;
  f2 mc[8], y[8], a[8];
  load_pairs(ISQ + c * XLD, mc, 1.f);
  mv_lds<XLD>(Xs + g * GSTR, mc, y);
  mv_lds<XLD>(ISQ, y, a);
  PHASE;
  float d;
  jacobi_os(a, d, c, SW_PASS);
  PHASE;
  float gc = 0.5f * __logf(fmaxf(d, 1e-30f)) * __builtin_amdgcn_rcpf(d);
  float* RBg = Xs + g * GSTR;   // X is dead; reuse
  store_rows(RBg, c, a);
  GB[g * 16 + c] = gc;
  __builtin_amdgcn_wave_barrier();
  PHASE;
  f2 out[8];
  recon16<XLD>(RBg, GB + g * 16, c, out);
  PHASE;
  #pragma unroll
  for (int k = 0; k < 8; ++k) {
    out[k].x += __shfl_xor(out[k].x, 16);
    out[k].y += __shfl_xor(out[k].y, 16);
  }
  #pragma unroll
  for (int k = 0; k < 8; ++k) {
    out[k].x += __shfl_xor(out[k].x, 32);
    out[k].y += __shfl_xor(out[k].y, 32);
  }
  if (g == 0) store_pairs_g(red + wv * 256 + c * 16, out);
  __syncthreads();
  float v = red[tid] + red[256 + tid] + red[512 + tid] + red[768 + tid];
  atomicAdd(&gtsum[n * 256 + tid], v);
}

// ---------------- Step 4: x_mean chain -> isq_m, lt_mean ----------------
#define WSZ4 (8 * GSTR + 128)   // 2752
__global__ __launch_bounds__(256) void mean_update_kernel(const float* __restrict__ gtsum, const float* __restrict__ sqrm,
                                                          float* __restrict__ isqm, float* __restrict__ ltmean) {
  __shared__ __align__(16) float lds[4 * WSZ4];
  int tid = threadIdx.x;
  int wv = tid >> 6, lid = tid & 63, g = lid >> 4, c = lid & 15;
  int n0 = blockIdx.x * 16 + wv * 4 + g;
  float* Wr = lds + wv * WSZ4;
  float* RB = Wr;                  // 4 x GSTR
  float* SQ = Wr + 4 * GSTR;       // 4 x GSTR
  float* G1 = Wr + 8 * GSTR;       // 64
  float* G2 = Wr + 8 * GSTR + 64;  // 64
  // ---- eigh(gt) (indefinite -> shift), expm ----
  f2 a[8];
  load_pairs(gtsum + n0 * 256 + c * 16, a, 1.f / (float)SS);
  float rs = 0.f;
  #pragma unroll
  for (int k = 0; k < 8; ++k) rs += fabsf(a[k].x) + fabsf(a[k].y);
  rs = fmaxf(rs, lxor<1>(rs)); rs = fmaxf(rs, lxor<2>(rs));
  rs = fmaxf(rs, lxor<4>(rs)); rs = fmaxf(rs, lxor<8>(rs));
  float sig = rs + 0.001f;
  #pragma unroll
  for (int k = 0; k < 8; ++k) {
    a[k].x += (2 * k     == c) ? sig : 0.f;
    a[k].y += (2 * k + 1 == c) ? sig : 0.f;
  }
  float d;
  jacobi_os(a, d, c, SW_SMALL);
  float lam = __builtin_amdgcn_sqrtf(d);
  float gc = __expf(lam - sig) * __builtin_amdgcn_rcpf(fmaxf(d, 1e-30f));
  float* RBg = RB + g * GSTR;
  store_rows(RBg, c, a);
  G1[g * 16 + c] = gc;
  __builtin_amdgcn_wave_barrier();
  f2 e1[8];
  recon16<XLD>(RBg, G1 + g * 16, c, e1);
  // ---- stage sq_rm (4 consecutive n for this wave) ----
  stage4(sqrm + (blockIdx.x * 16 + wv * 4) * 256, SQ, lid);
  __builtin_amdgcn_wave_barrier();
  store_rows(RBg, c, e1);
  __builtin_amdgcn_wave_barrier();
  float* SQg = SQ + g * GSTR;
  f2 mc[8], y[8], a2[8];
  load_pairs(SQg + c * XLD, mc, 1.f);
  mv_lds<XLD>(RBg, mc, y);    // expm(gt) * sq_col
  mv_lds<XLD>(SQg, y, a2);    // sq * y -> col c of x_mean
  float d2;
  jacobi_os(a2, d2, c, SW_SMALL);
  float sqd = __builtin_amdgcn_sqrtf(d2);
  float qd  = __builtin_amdgcn_sqrtf(sqd);
  float g1c = __builtin_amdgcn_rcpf(d2 * qd);                                  // d^{-5/4}: invsqrtm
  float g2c = 0.5f * __logf(fmaxf(d2, 1e-30f)) * __builtin_amdgcn_rcpf(d2);   // logm
  store_rows(RBg, c, a2);
  G1[g * 16 + c] = g1c;
  G2[g * 16 + c] = g2c;
  __builtin_amdgcn_wave_barrier();
  f2 o1[8], o2[8];
  recon2_16<XLD>(RBg, G1 + g * 16, G2 + g * 16, c, o1, o2);
  store_pairs_g(isqm + n0 * 256 + c * 16, o1);
  #pragma unroll
  for (int k = 0; k < 8; ++k) {
    int r0 = 2 * k, r1 = 2 * k + 1;
    if (r0 >= c) ltmean[n0 * D0 + (r0 * (r0 + 1) / 2) + c] = o2[k].x * ((r0 == c) ? 1.f : SQRT2F);
    if (r1 >= c) ltmean[n0 * D0 + (r1 * (r1 + 1) / 2) + c] = o2[k].y * ((r1 == c) ? 1.f : SQRT2F);
  }
}

// ---------------- Step 5: pass 2 — xc = tril(Wsq logm(isq_m X isq_m) Wsq) ----------------
#define WSZ2 (4 * GSTR + 2 * XLD * 16 + 64)   // 2016
__global__ __launch_bounds__(256)
void pass2_kernel(const float* __restrict__ x, const float* __restrict__ isqm,
                  const float* __restrict__ wsqg, float* __restrict__ xc) {
  __shared__ __align__(16) float lds[4 * WSZ2];
  int tid = threadIdx.x;
  int wv = tid >> 6, lid = tid & 63, g = lid >> 4, c = lid & 15;
  int n = blockIdx.y;
  int s_base = blockIdx.x * 16 + wv * 4;
  float* Wr  = lds + wv * WSZ2;
  float* Xs  = Wr;                           // 4 x GSTR; reused as recon buf
  float* ISQ = Wr + 4 * GSTR;                // 16 x XLD
  float* WSQ = Wr + 4 * GSTR + XLD * 16;     // 16 x XLD
  float* GB  = Wr + 4 * GSTR + 2 * XLD * 16; // 64
  stage4(x + ((long)n * SS + s_base) * 256, Xs, lid);
  const float* isqn = isqm + n * 256;
  for (int i = lid; i < 256; i += 64) {
    int r = i >> 4, cc = i & 15;
    ISQ[r * XLD + cc] = isqn[i];
    WSQ[r * XLD + cc] = wsqg[i];
  }
  __builtin_amdgcn_wave_barrier();
  PHASE;
  f2 mc[8], y[8], a[8];
  load_pairs(ISQ + c * XLD, mc, 1.f);
  mv_lds<XLD>(Xs + g * GSTR, mc, y);
  mv_lds<XLD>(ISQ, y, a);
  PHASE;
  float d;
  jacobi_os(a, d, c, SW_PASS);
  PHASE;
  float gc = 0.5f * __logf(fmaxf(d, 1e-30f)) * __builtin_amdgcn_rcpf(d);
  f2 b[8];
  mv_lds<XLD>(WSQ, a, b);   // fold outer Wsq sandwich into the recon columns
  float* RBg = Xs + g * GSTR;
  store_rows(RBg, c, b);
  GB[g * 16 + c] = gc;
  __builtin_amdgcn_wave_barrier();
  PHASE;
  f2 out[8];
  recon16<XLD>(RBg, GB + g * 16, c, out);
  PHASE;
  long ob = ((long)n * SS + s_base + g) * (long)D0;
  #pragma unroll
  for (int k = 0; k < 8; ++k) {
    int r0 = 2 * k, r1 = 2 * k + 1;
    if (r0 >= c) xc[ob + (r0 * (r0 + 1) / 2) + c] = out[k].x * ((r0 == c) ? 1.f : SQRT2F);
    if (r1 >= c) xc[ob + (r1 * (r1 + 1) / 2) + c] = out[k].y * ((r1 == c) ? 1.f : SQRT2F);
  }
}

// ---------------- Step 6: covariance SYRK (symmetric: 15 of 25 tile pairs) ----------------
__global__ __launch_bounds__(256) void syrk_kernel(const float* __restrict__ xc, float* __restrict__ cov) {
  __shared__ float Ap[32][33];
  __shared__ float Bp[32][33];
  const int TI[15] = {0,0,0,0,0,1,1,1,1,2,2,2,3,3,4};
  const int TJ[15] = {0,1,2,3,4,1,2,3,4,2,3,4,3,4,4};
  int n = blockIdx.y;
  int ti = TI[blockIdx.x], tj = TJ[blockIdx.x];
  int tid = threadIdx.x;
  int tx = tid & 15, ty = tid >> 4;
  float a00 = 0.f, a01 = 0.f, a10 = 0.f, a11 = 0.f;
  const float* xb = xc + (long)n * SS * D0;
  for (int s0 = 0; s0 < SS; s0 += 32) {
    for (int l = tid; l < 1024; l += 256) {
      int ss = l >> 5, ii = l & 31;
      int gi = ti * 32 + ii, gj = tj * 32 + ii;
      const float* row = xb + (long)(s0 + ss) * D0;
      Ap[ss][ii] = (gi < D0) ? row[gi] : 0.f;
      Bp[ss][ii] = (gj < D0) ? row[gj] : 0.f;
    }
    __syncthreads();
    #pragma unroll 8
    for (int ss = 0; ss < 32; ++ss) {
      float x0 = Ap[ss][2 * ty], x1 = Ap[ss][2 * ty + 1];
      float y0 = Bp[ss][2 * tx], y1 = Bp[ss][2 * tx + 1];
      a00 += x0 * y0; a01 += x0 * y1; a10 += x1 * y0; a11 += x1 * y1;
    }
    __syncthreads();
  }
  int i0 = ti * 32 + 2 * ty, j0 = tj * 32 + 2 * tx;
  const float sc = 1.f / (float)(SS - 1);
  long base = (long)n * D0 * D0;
  if (i0 < D0 && j0 < D0)         cov[base + (long)i0 * D0 + j0]           = a00 * sc;
  if (i0 < D0 && j0 + 1 < D0)     cov[base + (long)i0 * D0 + j0 + 1]       = a01 * sc;
  if (i0 + 1 < D0 && j0 < D0)     cov[base + (long)(i0 + 1) * D0 + j0]     = a10 * sc;
  if (i0 + 1 < D0 && j0 + 1 < D0) cov[base + (long)(i0 + 1) * D0 + j0 + 1] = a11 * sc;
  if (ti != tj) {
    if (i0 < D0 && j0 < D0)         cov[base + (long)j0 * D0 + i0]           = a00 * sc;
    if (i0 < D0 && j0 + 1 < D0)     cov[base + (long)(j0 + 1) * D0 + i0]     = a01 * sc;
    if (i0 + 1 < D0 && j0 < D0)     cov[base + (long)j0 * D0 + i0 + 1]       = a10 * sc;
    if (i0 + 1 < D0 && j0 + 1 < D0) cov[base + (long)(j0 + 1) * D0 + i0 + 1] = a11 * sc;
  }
}

// ---------------- Step 7: assemble E skeleton ----------------
__global__ __launch_bounds__(256) void ebuild_kernel(const float* __restrict__ ltmean, float* __restrict__ E) {
  int n = blockIdx.x;
  for (int idx = threadIdx.x; idx < DD * DD; idx += 256) {
    int r = idx / DD, c = idx % DD;
    float v = 0.f;
    if (r >= D0) {
      if (c < D0) v = ltmean[n * D0 + c];
      else        v = (r == c) ? 1.f : 0.f;
    }
    E[(long)n * DD * DD + idx] = v;
  }
}

// ---------------- Cholesky (triangular LDS storage) ----------------
template<int D, int NORM, int WRITE_UPPER>
__global__ __launch_bounds__(256) void chol_kernel(const float* __restrict__ in, long inStride,
                                                   float* __restrict__ out, long outStride, int outLd) {
  __shared__ float As[D * (D + 1) / 2];
  __shared__ float red[256];
  int b = blockIdx.x;
  int tid = threadIdx.x;
  const float* inp = in + (long)b * inStride;
  for (int idx = tid; idx < D * D; idx += 256) {
    int r = idx / D, c2 = idx % D;
    if (c2 <= r) As[(r * (r + 1) / 2) + c2] = inp[idx];
  }
  __syncthreads();
  if (NORM) {
    float p = 0.f;
    for (int i = tid; i < D; i += 256) p += As[(i * (i + 1) / 2) + i];
    red[tid] = p;
    __syncthreads();
    for (int off = 128; off >= 1; off >>= 1) {
      if (tid < off) red[tid] += red[tid + off];
      __syncthreads();
    }
    float inv = 1.f / red[0];
    for (int idx = tid; idx < D * (D + 1) / 2; idx += 256) As[idx] *= inv;
    __syncthreads();
    for (int i = tid; i < D; i += 256) As[(i * (i + 1) / 2) + i] += 1e-5f;
    __syncthreads();
  }
  int tx = tid & 15, ty = tid >> 4;
  for (int k = 0; k < D; ++k) {
    float dkk = As[(k * (k + 1) / 2) + k];
    float dv = sqrtf(dkk);
    float invd = 1.f / dv;
    __syncthreads();
    for (int i = k + 1 + tid; i < D; i += 256) As[(i * (i + 1) / 2) + k] *= invd;
    if (tid == 0) As[(k * (k + 1) / 2) + k] = dv;
    __syncthreads();
    for (int i = k + 1 + ty; i < D; i += 16) {
      float aik = As[(i * (i + 1) / 2) + k];
      int ibase = i * (i + 1) / 2;
      for (int j = k + 1 + tx; j <= i; j += 16) {
        As[ibase + j] -= aik * As[(j * (j + 1) / 2) + k];
      }
    }
    __syncthreads();
  }
  float* op = out + (long)b * outStride;
  for (int idx = tid; idx < D * D; idx += 256) {
    int r = idx / D, c2 = idx % D;
    if (c2 <= r)          op[r * outLd + c2] = As[(r * (r + 1) / 2) + c2];
    else if (WRITE_UPPER) op[r * outLd + c2] = 0.f;
  }
}

// ---------------- generic 152x152 GEMM: C = alpha*A@B (+I) ----------------
__global__ __launch_bounds__(256) void gemm152_kernel(const float* __restrict__ A, long sA,
                                                      const float* __restrict__ B, float* __restrict__ Cm,
                                                      long sC, float alpha, int addI) {
  __shared__ float As[16][17];
  __shared__ float Bs[16][17];
  int b = blockIdx.y;
  const float* Ab_ = A + (long)b * sA;
  float* Cb = Cm + (long)b * sC;
  int tid = threadIdx.x;
  int tx = tid & 15, ty = tid >> 4;
  int row0 = (blockIdx.x / 10) * 16, col0 = (blockIdx.x % 10) * 16;
  float acc = 0.f;
  for (int k0 = 0; k0 < DD; k0 += 16) {
    int ar = row0 + ty, ac = k0 + tx;
    As[ty][tx] = (ar < DD && ac < DD) ? Ab_[ar * DD + ac] : 0.f;
    int br = k0 + ty, bc = col0 + tx;
    Bs[ty][tx] = (br < DD && bc < DD) ? B[br * DD + bc] : 0.f;
    __syncthreads();
    #pragma unroll
    for (int kk = 0; kk < 16; ++kk) acc += As[ty][kk] * Bs[kk][tx];
    __syncthreads();
  }
  int r = row0 + ty, c2 = col0 + tx;
  if (r < DD && c2 < DD) Cb[r * DD + c2] = alpha * acc + ((addI && r == c2) ? 1.f : 0.f);
}

__global__ __launch_bounds__(256) void wlw_prep_kernel(const float* __restrict__ Wlw, float* __restrict__ Bm) {
  int idx = blockIdx.x * 256 + threadIdx.x;
  if (idx < DD * DD) {
    int r = idx / DD, c = idx % DD;
    Bm[idx] = 0.5f * (Wlw[idx] + Wlw[c * DD + r]) * (1.f / 16.f);
  }
}

__global__ __launch_bounds__(256) void taylor_init_kernel(const float* __restrict__ Bm, float* __restrict__ P) {
  int idx = blockIdx.x * 256 + threadIdx.x;
  if (idx < DD * DD) {
    int r = idx / DD, c = idx % DD;
    P[idx] = Bm[idx] * (1.f / 6.f) + ((r == c) ? 1.f : 0.f);
  }
}

extern "C" void kernel_launch(void* const* d_in, const int* in_sizes, int n_in,
                              void* d_out, int out_size, void* d_ws, size_t ws_size,
                              hipStream_t stream) {
  (void)in_sizes; (void)n_in; (void)out_size; (void)ws_size;
  const float* x   = (const float*)d_in[0];
  const float* W   = (const float*)d_in[1];
  const float* Wlw = (const float*)d_in[2];
  float* ws = (float*)d_ws;
  size_t off = 0;
  float* rmsum  = ws + off; off += 32 * 256;
  float* gtsum  = ws + off; off += 32 * 256;
  float* sqrm   = ws + off; off += 32 * 256;
  float* isqrm  = ws + off; off += 32 * 256;
  float* wsqb   = ws + off; off += 256;
  float* isqm   = ws + off; off += 32 * 256;
  float* ltmean = ws + off; off += 32 * D0;
  float* cov    = ws + off; off += (size_t)32 * D0 * D0;
  float* E      = ws + off; off += (size_t)32 * DD * DD;
  float* Bm     = ws + off; off += DD * DD;
  float* Pa     = ws + off; off += DD * DD;
  float* Pb     = ws + off; off += DD * DD;
  float* Rm     = ws + off; off += DD * DD;
  float* xcbuf  = ws + off; off += (size_t)32 * SS * D0;
  float* outp   = (float*)d_out;

  hipMemsetAsync(rmsum, 0, 2 * 32 * 256 * sizeof(float), stream);

  rm_mean_kernel    <<<dim3(25, 32),  256, 0, stream>>>(x, rmsum);
  eigh_rm_kernel    <<<3,             256, 0, stream>>>(rmsum, W, sqrm, isqrm, wsqb);
  pass1_kernel      <<<dim3(200, 32), 256, 0, stream>>>(x, isqrm, gtsum);
  mean_update_kernel<<<2,             256, 0, stream>>>(gtsum, sqrm, isqm, ltmean);
  pass2_kernel      <<<dim3(200, 32), 256, 0, stream>>>(x, isqm, wsqb, xcbuf);
  syrk_kernel       <<<dim3(15, 32),  256, 0, stream>>>(xcbuf, cov);
  ebuild_kernel     <<<32,            256, 0, stream>>>(ltmean, E);
  chol_kernel<D0, 1, 0><<<32,         256, 0, stream>>>(cov, (long)D0 * D0, E, (long)DD * DD, DD);

  // R = chol(expm(sym(W_lw))): scaling 1/16, Taylor order 6 (err ~7e-10), square 4x
  wlw_prep_kernel   <<<(DD * DD + 255) / 256, 256, 0, stream>>>(Wlw, Bm);
  taylor_init_kernel<<<(DD * DD + 255) / 256, 256, 0, stream>>>(Bm, Pa);
  float* Pcur = Pa; float* Pnext = Pb;
  for (int k = 5; k >= 1; --k) {
    gemm152_kernel<<<dim3(100, 1), 256, 0, stream>>>(Bm, 0L, Pcur, Pnext, 0L, 1.f / (float)k, 1);
    float* t = Pcur; Pcur = Pnext; Pnext = t;
  }
  for (int i = 0; i < 4; ++i) {
    gemm152_kernel<<<dim3(100, 1), 256, 0, stream>>>(Pcur, 0L, Pcur, Pnext, 0L, 1.f, 0);
    float* t = Pcur; Pcur = Pnext; Pnext = t;
  }
  chol_kernel<DD, 0, 1><<<1, 256, 0, stream>>>(Pcur, 0L, Rm, 0L, DD);

  gemm152_kernel<<<dim3(100, 32), 256, 0, stream>>>(E, (long)DD * DD, Rm, outp, (long)DD * DD, 1.f, 0);
}

// Round 7
// 1646.569 us; speedup vs baseline: 7.9810x; 1.2137x over previous
//
#include <hip/hip_runtime.h>
#include <math.h>

// Problem constants (fixed by setup_inputs)
#define NN   32
#define SS   3200
#define CC   16
#define XLD  20      // row stride (floats) inside a 16x16 matrix slot
#define GSTR 328     // per-group matrix slot stride: bank offsets {0,8,16,24} across groups
#define D0   136     // C*(C+1)/2
#define DD   152     // D0 + k
#define SQRT2F 1.41421356237309515f
#define SW_PASS 5    // sweeps for the two big per-sample passes (4 FAILED: absmax 3.8e-2)
#define SW_SMALL 8   // sweeps for the tiny per-n chains

typedef float f2 __attribute__((ext_vector_type(2)));
__device__ __forceinline__ f2 mk2(float x, float y) { f2 r; r.x = x; r.y = y; return r; }

#define PHASE __builtin_amdgcn_sched_barrier(0)

// ---------------- cross-lane xor within 16-lane groups ----------------
template<int M> __device__ __forceinline__ float lxor(float x) {
  int v = __float_as_int(x);
  int r;
  if      constexpr (M == 1)  r = __builtin_amdgcn_update_dpp(0, v, 0xB1, 0xF, 0xF, true);  // quad_perm [1,0,3,2]
  else if constexpr (M == 2)  r = __builtin_amdgcn_update_dpp(0, v, 0x4E, 0xF, 0xF, true);  // quad_perm [2,3,0,1]
  else if constexpr (M == 3)  r = __builtin_amdgcn_update_dpp(0, v, 0x1B, 0xF, 0xF, true);  // quad_perm [3,2,1,0]
  else if constexpr (M == 7)  r = __builtin_amdgcn_update_dpp(0, v, 0x141, 0xF, 0xF, true); // row_half_mirror
  else if constexpr (M == 8)  r = __builtin_amdgcn_update_dpp(0, v, 0x128, 0xF, 0xF, true); // row_ror:8
  else if constexpr (M == 15) r = __builtin_amdgcn_update_dpp(0, v, 0x140, 0xF, 0xF, true); // row_mirror
  else r = __builtin_amdgcn_ds_swizzle(v, 0x1F | (M << 10));                                // BitMode xor
  return __int_as_float(r);
}

// ---------------- one-sided Jacobi round: pairs (i, i^M) ----------------
template<int M>
__device__ __forceinline__ void js_round(f2 a[8], float& d, int c) {
  f2 part[8];
  #pragma unroll
  for (int r = 0; r < 8; ++r) {
    part[r].x = lxor<M>(a[r].x);
    part[r].y = lxor<M>(a[r].y);
  }
  float pd = lxor<M>(d);
  f2 s0 = a[0] * part[0];
  f2 s1 = a[1] * part[1];
  f2 s2 = a[2] * part[2];
  f2 s3 = a[3] * part[3];
  s0 += a[4] * part[4];
  s1 += a[5] * part[5];
  s2 += a[6] * part[6];
  s3 += a[7] * part[7];
  f2 sv = (s0 + s1) + (s2 + s3);
  float apq = sv.x + sv.y;
  int partner = c ^ M;
  bool isp = c < partner;
  float app = isp ? d : pd;
  float aqq = isp ? pd : d;
  // NOTE: keep the rcp form — t = 1/(|θ|+√(θ²+1)). The algebraically-equal
  // √(θ²+1)−|θ| cancels catastrophically at large θ (R6 FAILED: absmax 3.8e-2).
  float theta = (aqq - app) * 0.5f * __builtin_amdgcn_rcpf(apq);
  float t = copysignf(__builtin_amdgcn_rcpf(fabsf(theta) + __builtin_amdgcn_sqrtf(fmaf(theta, theta, 1.f))), theta);
  t = (apq == 0.f) ? 0.f : t;
  float cs = __builtin_amdgcn_rsqf(fmaf(t, t, 1.f));
  float sn = t * cs;
  float se = isp ? -sn : sn;
  f2 pcs = mk2(cs, cs);
  f2 pse = mk2(se, se);
  #pragma unroll
  for (int r = 0; r < 8; ++r) a[r] = pcs * a[r] + pse * part[r];
  d = isp ? (app - t * apq) : (aqq + t * apq);
}

__device__ __forceinline__ void js_sweep(f2 a[8], float& d, int c) {
  js_round<1>(a, d, c);  js_round<2>(a, d, c);  js_round<3>(a, d, c);
  js_round<4>(a, d, c);  js_round<5>(a, d, c);  js_round<6>(a, d, c);
  js_round<7>(a, d, c);  js_round<8>(a, d, c);  js_round<9>(a, d, c);
  js_round<10>(a, d, c); js_round<11>(a, d, c); js_round<12>(a, d, c);
  js_round<13>(a, d, c); js_round<14>(a, d, c); js_round<15>(a, d, c);
}

__device__ __forceinline__ float colnorm2(const f2 a[8]) {
  f2 s0 = a[0] * a[0], s1 = a[1] * a[1], s2 = a[2] * a[2], s3 = a[3] * a[3];
  s0 += a[4] * a[4]; s1 += a[5] * a[5]; s2 += a[6] * a[6]; s3 += a[7] * a[7];
  f2 s = (s0 + s1) + (s2 + s3);
  return s.x + s.y;
}

// a: column c of symmetric M (packed pairs). Exit: a = lam_c * v_c, d = lam_c^2.
__device__ __forceinline__ void jacobi_os(f2 a[8], float& d, int c, int sweeps) {
  d = colnorm2(a);
  #pragma unroll 1
  for (int s = 0; s < sweeps; ++s) js_sweep(a, d, c);
  d = colnorm2(a);
}

// ---------------- row dot: dot(M_row, v) ----------------
__device__ __forceinline__ float dotrow(const float* __restrict__ row, const f2 v[8]) {
  const float4 q0 = *(const float4*)(row + 0);
  const float4 q1 = *(const float4*)(row + 4);
  const float4 q2 = *(const float4*)(row + 8);
  const float4 q3 = *(const float4*)(row + 12);
  f2 s0 = mk2(q0.x, q0.y) * v[0] + mk2(q0.z, q0.w) * v[1];
  f2 s1 = mk2(q1.x, q1.y) * v[2] + mk2(q1.z, q1.w) * v[3];
  s0 += mk2(q2.x, q2.y) * v[4] + mk2(q2.z, q2.w) * v[5];
  s1 += mk2(q3.x, q3.y) * v[6] + mk2(q3.z, q3.w) * v[7];
  f2 s = s0 + s1;
  return s.x + s.y;
}

// y = Mat(16x16, LDS rows stride S) * v  (v, y packed by row pairs)
template<int S>
__device__ __forceinline__ void mv_lds(const float* __restrict__ M, const f2 v[8], f2 y[8]) {
  #pragma unroll
  for (int k = 0; k < 8; ++k) {
    float r0 = dotrow(M + (2 * k) * S, v);
    float r1 = dotrow(M + (2 * k + 1) * S, v);
    y[k] = mk2(r0, r1);
  }
}

// out (packed rows) = col c of Sum_i gb[i] * b_i b_i^T ; B row i = b_i (row stride S)
template<int S>
__device__ __forceinline__ void recon16(const float* __restrict__ B, const float* __restrict__ gb,
                                        int c, f2 o[8]) {
  #pragma unroll
  for (int k = 0; k < 8; ++k) o[k] = mk2(0.f, 0.f);
  #pragma unroll
  for (int i = 0; i < CC; ++i) {
    const float* row = B + i * S;
    float coef = gb[i] * row[c];
    f2 pc = mk2(coef, coef);
    const float4 q0 = *(const float4*)(row + 0);
    const float4 q1 = *(const float4*)(row + 4);
    const float4 q2 = *(const float4*)(row + 8);
    const float4 q3 = *(const float4*)(row + 12);
    o[0] += pc * mk2(q0.x, q0.y); o[1] += pc * mk2(q0.z, q0.w);
    o[2] += pc * mk2(q1.x, q1.y); o[3] += pc * mk2(q1.z, q1.w);
    o[4] += pc * mk2(q2.x, q2.y); o[5] += pc * mk2(q2.z, q2.w);
    o[6] += pc * mk2(q3.x, q3.y); o[7] += pc * mk2(q3.z, q3.w);
  }
}

template<int S>
__device__ __forceinline__ void recon2_16(const float* __restrict__ B, const float* __restrict__ g1,
                                          const float* __restrict__ g2, int c,
                                          f2 o1[8], f2 o2[8]) {
  #pragma unroll
  for (int k = 0; k < 8; ++k) { o1[k] = mk2(0.f, 0.f); o2[k] = mk2(0.f, 0.f); }
  #pragma unroll
  for (int i = 0; i < CC; ++i) {
    const float* row = B + i * S;
    float bic = row[c];
    f2 c1 = mk2(g1[i] * bic, g1[i] * bic);
    f2 c2 = mk2(g2[i] * bic, g2[i] * bic);
    const float4 q0 = *(const float4*)(row + 0);
    const float4 q1 = *(const float4*)(row + 4);
    const float4 q2 = *(const float4*)(row + 8);
    const float4 q3 = *(const float4*)(row + 12);
    f2 b0 = mk2(q0.x, q0.y), b1 = mk2(q0.z, q0.w), b2 = mk2(q1.x, q1.y), b3 = mk2(q1.z, q1.w);
    f2 b4 = mk2(q2.x, q2.y), b5 = mk2(q2.z, q2.w), b6 = mk2(q3.x, q3.y), b7 = mk2(q3.z, q3.w);
    o1[0] += c1 * b0; o1[1] += c1 * b1; o1[2] += c1 * b2; o1[3] += c1 * b3;
    o1[4] += c1 * b4; o1[5] += c1 * b5; o1[6] += c1 * b6; o1[7] += c1 * b7;
    o2[0] += c2 * b0; o2[1] += c2 * b1; o2[2] += c2 * b2; o2[3] += c2 * b3;
    o2[4] += c2 * b4; o2[5] += c2 * b5; o2[6] += c2 * b6; o2[7] += c2 * b7;
  }
}

// stage 4 contiguous 16x16 matrices (1024 floats) from global into XLD/GSTR layout
__device__ __forceinline__ void stage4(const float* __restrict__ src, float* __restrict__ dst, int lid) {
  #pragma unroll
  for (int i = 0; i < 4; ++i) {
    int f = (i * 64 + lid) * 4;       // float index in the contiguous source
    int m = f >> 8, w = f & 255;      // matrix, within-matrix
    *(float4*)(dst + m * GSTR + (w >> 4) * XLD + (w & 15)) = *(const float4*)(src + f);
  }
}

__device__ __forceinline__ void store_rows(float* __restrict__ RBg, int c, const f2 a[8]) {
  #pragma unroll
  for (int i = 0; i < 4; ++i)
    *(float4*)(RBg + c * XLD + 4 * i) = make_float4(a[2 * i].x, a[2 * i].y, a[2 * i + 1].x, a[2 * i + 1].y);
}

__device__ __forceinline__ void load_pairs(const float* __restrict__ src, f2 a[8], float scale) {
  #pragma unroll
  for (int i = 0; i < 4; ++i) {
    float4 v = *(const float4*)(src + 4 * i);
    a[2 * i]     = mk2(v.x * scale, v.y * scale);
    a[2 * i + 1] = mk2(v.z * scale, v.w * scale);
  }
}

__device__ __forceinline__ void store_pairs_g(float* __restrict__ dst, const f2 a[8]) {
  #pragma unroll
  for (int i = 0; i < 4; ++i)
    *(float4*)(dst + 4 * i) = make_float4(a[2 * i].x, a[2 * i].y, a[2 * i + 1].x, a[2 * i + 1].y);
}

// ---------------- Step 1: rm accumulation (float4 loads) ----------------
__global__ __launch_bounds__(256) void rm_mean_kernel(const float* __restrict__ x, float* __restrict__ rmsum) {
  int n = blockIdx.y;
  int tid = threadIdx.x;
  long base = (long)n * SS * 256 + (long)blockIdx.x * 128 * 256 + tid * 4;
  float4 s = make_float4(0.f, 0.f, 0.f, 0.f);
  for (int i = 0; i < 32; ++i) {
    float4 v = *(const float4*)(x + base + (long)i * 1024);
    s.x += v.x; s.y += v.y; s.z += v.z; s.w += v.w;
  }
  int o = (tid * 4) & 255;
  atomicAdd(&rmsum[n * 256 + o],     s.x);
  atomicAdd(&rmsum[n * 256 + o + 1], s.y);
  atomicAdd(&rmsum[n * 256 + o + 2], s.z);
  atomicAdd(&rmsum[n * 256 + o + 3], s.w);
}

// ---------------- Step 2: eigh(rm) -> sq,isq ; Wsq = expm(sym(W)/2) ----------------
__global__ __launch_bounds__(256) void eigh_rm_kernel(const float* __restrict__ rmsum, const float* __restrict__ Wg,
                                                      float* __restrict__ sqrm, float* __restrict__ isqrm,
                                                      float* __restrict__ wsqo) {
  __shared__ __align__(16) float lds[4 * 1440];
  int tid = threadIdx.x;
  int wv = tid >> 6, lid = tid & 63, g = lid >> 4, c = lid & 15;
  float* Wr = lds + wv * 1440;
  float* RB = Wr;                 // 4 x GSTR
  float* G1 = Wr + 4 * GSTR;      // 64
  float* G2 = Wr + 4 * GSTR + 64; // 64
  int gid_raw = blockIdx.x * 16 + wv * 4 + g;
  int gid = gid_raw > 32 ? 32 : gid_raw;
  f2 a[8];
  if (gid < 32) {
    load_pairs(rmsum + gid * 256 + c * 16, a, 1.f / (float)SS);
  } else {
    #pragma unroll
    for (int k = 0; k < 8; ++k) {
      a[k].x = 0.5f * (Wg[c * 16 + 2 * k]     + Wg[(2 * k) * 16 + c]);
      a[k].y = 0.5f * (Wg[c * 16 + 2 * k + 1] + Wg[(2 * k + 1) * 16 + c]);
    }
  }
  // Gershgorin shift (only applied to the possibly-indefinite W matrix)
  float rs = 0.f;
  #pragma unroll
  for (int k = 0; k < 8; ++k) rs += fabsf(a[k].x) + fabsf(a[k].y);
  rs = fmaxf(rs, lxor<1>(rs)); rs = fmaxf(rs, lxor<2>(rs));
  rs = fmaxf(rs, lxor<4>(rs)); rs = fmaxf(rs, lxor<8>(rs));
  float sig = (gid == 32) ? (rs + 0.001f) : 0.f;
  #pragma unroll
  for (int k = 0; k < 8; ++k) {
    a[k].x += (2 * k     == c) ? sig : 0.f;
    a[k].y += (2 * k + 1 == c) ? sig : 0.f;
  }
  float d;
  jacobi_os(a, d, c, SW_SMALL);
  float g1c, g2c;
  if (gid < 32) {
    float sqd = __builtin_amdgcn_sqrtf(d);
    float qd  = __builtin_amdgcn_sqrtf(sqd);            // d^{1/4}
    g1c = qd * __builtin_amdgcn_rcpf(d);                // d^{-3/4}: sqrtm
    g2c = __builtin_amdgcn_rcpf(d * qd);                // d^{-5/4}: invsqrtm
  } else {
    float lam = __builtin_amdgcn_sqrtf(d);
    g1c = __expf(0.5f * (lam - sig)) * __builtin_amdgcn_rcpf(fmaxf(d, 1e-30f));
    g2c = 0.f;
  }
  float* RBg = RB + g * GSTR;
  store_rows(RBg, c, a);
  G1[g * 16 + c] = g1c;
  G2[g * 16 + c] = g2c;
  __builtin_amdgcn_wave_barrier();
  f2 o1[8], o2[8];
  recon2_16<XLD>(RBg, G1 + g * 16, G2 + g * 16, c, o1, o2);
  if (gid_raw < 32) {
    store_pairs_g(sqrm  + gid * 256 + c * 16, o1);
    store_pairs_g(isqrm + gid * 256 + c * 16, o2);
  } else if (gid_raw == 32) {
    store_pairs_g(wsqo + c * 16, o1);
  }
}

// ---------------- Step 3: pass 1 — sum_s logm(isq_rm X isq_rm) ----------------
#define WSZ1 (4 * GSTR + XLD * 16 + 64)   // 1696
__global__ __launch_bounds__(256) __attribute__((amdgpu_num_vgpr(128)))
void pass1_kernel(const float* __restrict__ x, const float* __restrict__ isqrm,
                  float* __restrict__ gtsum) {
  __shared__ __align__(16) float lds[4 * WSZ1 + 1024];
  int tid = threadIdx.x;
  int wv = tid >> 6, lid = tid & 63, g = lid >> 4, c = lid & 15;
  int n = blockIdx.y;
  int s_base = blockIdx.x * 16 + wv * 4;
  float* Wr  = lds + wv * WSZ1;
  float* Xs  = Wr;                      // 4 x GSTR; reused as recon buf
  float* ISQ = Wr + 4 * GSTR;           // 16 x XLD
  float* GB  = Wr + 4 * GSTR + XLD * 16;// 64
  float* red = lds + 4 * WSZ1;          // 1024 (cross-wave reduce)
  stage4(x + ((long)n * SS + s_base) * 256, Xs, lid);
  const float* isqn = isqrm + n * 256;
  for (int i = lid; i < 256; i += 64) ISQ[(i >> 4) * XLD + (i & 15)] = isqn[i];
  __builtin_amdgcn_wave_barrier();
  PHASE;
  f2 mc[8], y[8], a[8];
  load_pairs(ISQ + c * XLD, mc, 1.f);
  mv_lds<XLD>(Xs + g * GSTR, mc, y);
  mv_lds<XLD>(ISQ, y, a);
  PHASE;
  float d;
  jacobi_os(a, d, c, SW_PASS);
  PHASE;
  float gc = 0.5f * __logf(fmaxf(d, 1e-30f)) * __builtin_amdgcn_rcpf(d);
  float* RBg = Xs + g * GSTR;   // X is dead; reuse
  store_rows(RBg, c, a);
  GB[g * 16 + c] = gc;
  __builtin_amdgcn_wave_barrier();
  PHASE;
  f2 out[8];
  recon16<XLD>(RBg, GB + g * 16, c, out);
  PHASE;
  #pragma unroll
  for (int k = 0; k < 8; ++k) {
    out[k].x += __shfl_xor(out[k].x, 16);
    out[k].y += __shfl_xor(out[k].y, 16);
  }
  #pragma unroll
  for (int k = 0; k < 8; ++k) {
    out[k].x += __shfl_xor(out[k].x, 32);
    out[k].y += __shfl_xor(out[k].y, 32);
  }
  if (g == 0) store_pairs_g(red + wv * 256 + c * 16, out);
  __syncthreads();
  float v = red[tid] + red[256 + tid] + red[512 + tid] + red[768 + tid];
  atomicAdd(&gtsum[n * 256 + tid], v);
}

// ---------------- Step 4: x_mean chain -> isq_m, lt_mean ----------------
#define WSZ4 (8 * GSTR + 128)   // 2752
__global__ __launch_bounds__(256) void mean_update_kernel(const float* __restrict__ gtsum, const float* __restrict__ sqrm,
                                                          float* __restrict__ isqm, float* __restrict__ ltmean) {
  __shared__ __align__(16) float lds[4 * WSZ4];
  int tid = threadIdx.x;
  int wv = tid >> 6, lid = tid & 63, g = lid >> 4, c = lid & 15;
  int n0 = blockIdx.x * 16 + wv * 4 + g;
  float* Wr = lds + wv * WSZ4;
  float* RB = Wr;                  // 4 x GSTR
  float* SQ = Wr + 4 * GSTR;       // 4 x GSTR
  float* G1 = Wr + 8 * GSTR;       // 64
  float* G2 = Wr + 8 * GSTR + 64;  // 64
  // ---- eigh(gt) (indefinite -> shift), expm ----
  f2 a[8];
  load_pairs(gtsum + n0 * 256 + c * 16, a, 1.f / (float)SS);
  float rs = 0.f;
  #pragma unroll
  for (int k = 0; k < 8; ++k) rs += fabsf(a[k].x) + fabsf(a[k].y);
  rs = fmaxf(rs, lxor<1>(rs)); rs = fmaxf(rs, lxor<2>(rs));
  rs = fmaxf(rs, lxor<4>(rs)); rs = fmaxf(rs, lxor<8>(rs));
  float sig = rs + 0.001f;
  #pragma unroll
  for (int k = 0; k < 8; ++k) {
    a[k].x += (2 * k     == c) ? sig : 0.f;
    a[k].y += (2 * k + 1 == c) ? sig : 0.f;
  }
  float d;
  jacobi_os(a, d, c, SW_SMALL);
  float lam = __builtin_amdgcn_sqrtf(d);
  float gc = __expf(lam - sig) * __builtin_amdgcn_rcpf(fmaxf(d, 1e-30f));
  float* RBg = RB + g * GSTR;
  store_rows(RBg, c, a);
  G1[g * 16 + c] = gc;
  __builtin_amdgcn_wave_barrier();
  f2 e1[8];
  recon16<XLD>(RBg, G1 + g * 16, c, e1);
  // ---- stage sq_rm (4 consecutive n for this wave) ----
  stage4(sqrm + (blockIdx.x * 16 + wv * 4) * 256, SQ, lid);
  __builtin_amdgcn_wave_barrier();
  store_rows(RBg, c, e1);
  __builtin_amdgcn_wave_barrier();
  float* SQg = SQ + g * GSTR;
  f2 mc[8], y[8], a2[8];
  load_pairs(SQg + c * XLD, mc, 1.f);
  mv_lds<XLD>(RBg, mc, y);    // expm(gt) * sq_col
  mv_lds<XLD>(SQg, y, a2);    // sq * y -> col c of x_mean
  float d2;
  jacobi_os(a2, d2, c, SW_SMALL);
  float sqd = __builtin_amdgcn_sqrtf(d2);
  float qd  = __builtin_amdgcn_sqrtf(sqd);
  float g1c = __builtin_amdgcn_rcpf(d2 * qd);                                  // d^{-5/4}: invsqrtm
  float g2c = 0.5f * __logf(fmaxf(d2, 1e-30f)) * __builtin_amdgcn_rcpf(d2);   // logm
  store_rows(RBg, c, a2);
  G1[g * 16 + c] = g1c;
  G2[g * 16 + c] = g2c;
  __builtin_amdgcn_wave_barrier();
  f2 o1[8], o2[8];
  recon2_16<XLD>(RBg, G1 + g * 16, G2 + g * 16, c, o1, o2);
  store_pairs_g(isqm + n0 * 256 + c * 16, o1);
  #pragma unroll
  for (int k = 0; k < 8; ++k) {
    int r0 = 2 * k, r1 = 2 * k + 1;
    if (r0 >= c) ltmean[n0 * D0 + (r0 * (r0 + 1) / 2) + c] = o2[k].x * ((r0 == c) ? 1.f : SQRT2F);
    if (r1 >= c) ltmean[n0 * D0 + (r1 * (r1 + 1) / 2) + c] = o2[k].y * ((r1 == c) ? 1.f : SQRT2F);
  }
}

// ---------------- Step 5: pass 2 — xc = tril(Wsq logm(isq_m X isq_m) Wsq) ----------------
#define WSZ2 (4 * GSTR + 2 * XLD * 16 + 64)   // 2016
__global__ __launch_bounds__(256) __attribute__((amdgpu_num_vgpr(128)))
void pass2_kernel(const float* __restrict__ x, const float* __restrict__ isqm,
                  const float* __restrict__ wsqg, float* __restrict__ xc) {
  __shared__ __align__(16) float lds[4 * WSZ2];
  int tid = threadIdx.x;
  int wv = tid >> 6, lid = tid & 63, g = lid >> 4, c = lid & 15;
  int n = blockIdx.y;
  int s_base = blockIdx.x * 16 + wv * 4;
  float* Wr  = lds + wv * WSZ2;
  float* Xs  = Wr;                           // 4 x GSTR; reused as recon buf
  float* ISQ = Wr + 4 * GSTR;                // 16 x XLD
  float* WSQ = Wr + 4 * GSTR + XLD * 16;     // 16 x XLD
  float* GB  = Wr + 4 * GSTR + 2 * XLD * 16; // 64
  stage4(x + ((long)n * SS + s_base) * 256, Xs, lid);
  const float* isqn = isqm + n * 256;
  for (int i = lid; i < 256; i += 64) {
    int r = i >> 4, cc = i & 15;
    ISQ[r * XLD + cc] = isqn[i];
    WSQ[r * XLD + cc] = wsqg[i];
  }
  __builtin_amdgcn_wave_barrier();
  PHASE;
  f2 mc[8], y[8], a[8];
  load_pairs(ISQ + c * XLD, mc, 1.f);
  mv_lds<XLD>(Xs + g * GSTR, mc, y);
  mv_lds<XLD>(ISQ, y, a);
  PHASE;
  float d;
  jacobi_os(a, d, c, SW_PASS);
  PHASE;
  float gc = 0.5f * __logf(fmaxf(d, 1e-30f)) * __builtin_amdgcn_rcpf(d);
  f2 b[8];
  mv_lds<XLD>(WSQ, a, b);   // fold outer Wsq sandwich into the recon columns
  float* RBg = Xs + g * GSTR;
  store_rows(RBg, c, b);
  GB[g * 16 + c] = gc;
  __builtin_amdgcn_wave_barrier();
  PHASE;
  f2 out[8];
  recon16<XLD>(RBg, GB + g * 16, c, out);
  PHASE;
  long ob = ((long)n * SS + s_base + g) * (long)D0;
  #pragma unroll
  for (int k = 0; k < 8; ++k) {
    int r0 = 2 * k, r1 = 2 * k + 1;
    if (r0 >= c) xc[ob + (r0 * (r0 + 1) / 2) + c] = out[k].x * ((r0 == c) ? 1.f : SQRT2F);
    if (r1 >= c) xc[ob + (r1 * (r1 + 1) / 2) + c] = out[k].y * ((r1 == c) ? 1.f : SQRT2F);
  }
}

// ---------------- Step 6: covariance SYRK (symmetric: 15 of 25 tile pairs) ----------------
__global__ __launch_bounds__(256) void syrk_kernel(const float* __restrict__ xc, float* __restrict__ cov) {
  __shared__ float Ap[32][34];
  __shared__ float Bp[32][34];
  const int TI[15] = {0,0,0,0,0,1,1,1,1,2,2,2,3,3,4};
  const int TJ[15] = {0,1,2,3,4,1,2,3,4,2,3,4,3,4,4};
  int n = blockIdx.y;
  int ti = TI[blockIdx.x], tj = TJ[blockIdx.x];
  int tid = threadIdx.x;
  int tx = tid & 15, ty = tid >> 4;
  float a00 = 0.f, a01 = 0.f, a10 = 0.f, a11 = 0.f;
  const float* xb = xc + (long)n * SS * D0;
  for (int s0 = 0; s0 < SS; s0 += 32) {
    for (int l = tid; l < 1024; l += 256) {
      int ss = l >> 5, ii = l & 31;
      int gi = ti * 32 + ii, gj = tj * 32 + ii;
      const float* row = xb + (long)(s0 + ss) * D0;
      Ap[ss][ii] = (gi < D0) ? row[gi] : 0.f;
      Bp[ss][ii] = (gj < D0) ? row[gj] : 0.f;
    }
    __syncthreads();
    #pragma unroll 8
    for (int ss = 0; ss < 32; ++ss) {
      f2 xa = *(const f2*)&Ap[ss][2 * ty];   // 8B-aligned (even stride 34)
      f2 yb = *(const f2*)&Bp[ss][2 * tx];
      a00 += xa.x * yb.x; a01 += xa.x * yb.y; a10 += xa.y * yb.x; a11 += xa.y * yb.y;
    }
    __syncthreads();
  }
  int i0 = ti * 32 + 2 * ty, j0 = tj * 32 + 2 * tx;
  const float sc = 1.f / (float)(SS - 1);
  long base = (long)n * D0 * D0;
  if (i0 < D0 && j0 < D0)         cov[base + (long)i0 * D0 + j0]           = a00 * sc;
  if (i0 < D0 && j0 + 1 < D0)     cov[base + (long)i0 * D0 + j0 + 1]       = a01 * sc;
  if (i0 + 1 < D0 && j0 < D0)     cov[base + (long)(i0 + 1) * D0 + j0]     = a10 * sc;
  if (i0 + 1 < D0 && j0 + 1 < D0) cov[base + (long)(i0 + 1) * D0 + j0 + 1] = a11 * sc;
  if (ti != tj) {
    if (i0 < D0 && j0 < D0)         cov[base + (long)j0 * D0 + i0]           = a00 * sc;
    if (i0 < D0 && j0 + 1 < D0)     cov[base + (long)(j0 + 1) * D0 + i0]     = a01 * sc;
    if (i0 + 1 < D0 && j0 < D0)     cov[base + (long)j0 * D0 + i0 + 1]       = a10 * sc;
    if (i0 + 1 < D0 && j0 + 1 < D0) cov[base + (long)(j0 + 1) * D0 + i0 + 1] = a11 * sc;
  }
}

// ---------------- Step 7: assemble E skeleton ----------------
__global__ __launch_bounds__(256) void ebuild_kernel(const float* __restrict__ ltmean, float* __restrict__ E) {
  int n = blockIdx.x;
  for (int idx = threadIdx.x; idx < DD * DD; idx += 256) {
    int r = idx / DD, c = idx % DD;
    float v = 0.f;
    if (r >= D0) {
      if (c < D0) v = ltmean[n * D0 + c];
      else        v = (r == c) ? 1.f : 0.f;
    }
    E[(long)n * DD * DD + idx] = v;
  }
}

// ---------------- Cholesky (triangular LDS storage) ----------------
template<int D, int NORM, int WRITE_UPPER, int THREADS>
__global__ __launch_bounds__(THREADS) void chol_kernel(const float* __restrict__ in, long inStride,
                                                       float* __restrict__ out, long outStride, int outLd) {
  __shared__ float As[D * (D + 1) / 2];
  __shared__ float red[THREADS];
  int b = blockIdx.x;
  int tid = threadIdx.x;
  const float* inp = in + (long)b * inStride;
  for (int idx = tid; idx < D * D; idx += THREADS) {
    int r = idx / D, c2 = idx % D;
    if (c2 <= r) As[(r * (r + 1) / 2) + c2] = inp[idx];
  }
  __syncthreads();
  if (NORM) {
    float p = 0.f;
    for (int i = tid; i < D; i += THREADS) p += As[(i * (i + 1) / 2) + i];
    red[tid] = p;
    __syncthreads();
    for (int off = THREADS / 2; off >= 1; off >>= 1) {
      if (tid < off) red[tid] += red[tid + off];
      __syncthreads();
    }
    float inv = 1.f / red[0];
    for (int idx = tid; idx < D * (D + 1) / 2; idx += THREADS) As[idx] *= inv;
    __syncthreads();
    for (int i = tid; i < D; i += THREADS) As[(i * (i + 1) / 2) + i] += 1e-5f;
    __syncthreads();
  }
  const int TY = THREADS / 16;
  int tx = tid & 15, ty = tid >> 4;
  for (int k = 0; k < D; ++k) {
    float dkk = As[(k * (k + 1) / 2) + k];
    float dv = sqrtf(dkk);
    float invd = 1.f / dv;
    __syncthreads();
    for (int i = k + 1 + tid; i < D; i += THREADS) As[(i * (i + 1) / 2) + k] *= invd;
    if (tid == 0) As[(k * (k + 1) / 2) + k] = dv;
    __syncthreads();
    for (int i = k + 1 + ty; i < D; i += TY) {
      float aik = As[(i * (i + 1) / 2) + k];
      int ibase = i * (i + 1) / 2;
      for (int j = k + 1 + tx; j <= i; j += 16) {
        As[ibase + j] -= aik * As[(j * (j + 1) / 2) + k];
      }
    }
    __syncthreads();
  }
  float* op = out + (long)b * outStride;
  for (int idx = tid; idx < D * D; idx += THREADS) {
    int r = idx / D, c2 = idx % D;
    if (c2 <= r)          op[r * outLd + c2] = As[(r * (r + 1) / 2) + c2];
    else if (WRITE_UPPER) op[r * outLd + c2] = 0.f;
  }
}

// ---------------- generic 152x152 GEMM: C = alpha*A@B (+I) ----------------
__global__ __launch_bounds__(256) void gemm152_kernel(const float* __restrict__ A, long sA,
                                                      const float* __restrict__ B, float* __restrict__ Cm,
                                                      long sC, float alpha, int addI) {
  __shared__ float As[16][17];
  __shared__ float Bs[16][17];
  int b = blockIdx.y;
  const float* Ab_ = A + (long)b * sA;
  float* Cb = Cm + (long)b * sC;
  int tid = threadIdx.x;
  int tx = tid & 15, ty = tid >> 4;
  int row0 = (blockIdx.x / 10) * 16, col0 = (blockIdx.x % 10) * 16;
  float acc = 0.f;
  for (int k0 = 0; k0 < DD; k0 += 16) {
    int ar = row0 + ty, ac = k0 + tx;
    As[ty][tx] = (ar < DD && ac < DD) ? Ab_[ar * DD + ac] : 0.f;
    int br = k0 + ty, bc = col0 + tx;
    Bs[ty][tx] = (br < DD && bc < DD) ? B[br * DD + bc] : 0.f;
    __syncthreads();
    #pragma unroll
    for (int kk = 0; kk < 16; ++kk) acc += As[ty][kk] * Bs[kk][tx];
    __syncthreads();
  }
  int r = row0 + ty, c2 = col0 + tx;
  if (r < DD && c2 < DD) Cb[r * DD + c2] = alpha * acc + ((addI && r == c2) ? 1.f : 0.f);
}

__global__ __launch_bounds__(256) void wlw_prep_kernel(const float* __restrict__ Wlw, float* __restrict__ Bm) {
  int idx = blockIdx.x * 256 + threadIdx.x;
  if (idx < DD * DD) {
    int r = idx / DD, c = idx % DD;
    Bm[idx] = 0.5f * (Wlw[idx] + Wlw[c * DD + r]) * (1.f / 8.f);
  }
}

__global__ __launch_bounds__(256) void taylor_init_kernel(const float* __restrict__ Bm, float* __restrict__ P) {
  int idx = blockIdx.x * 256 + threadIdx.x;
  if (idx < DD * DD) {
    int r = idx / DD, c = idx % DD;
    P[idx] = Bm[idx] * (1.f / 6.f) + ((r == c) ? 1.f : 0.f);
  }
}

extern "C" void kernel_launch(void* const* d_in, const int* in_sizes, int n_in,
                              void* d_out, int out_size, void* d_ws, size_t ws_size,
                              hipStream_t stream) {
  (void)in_sizes; (void)n_in; (void)out_size; (void)ws_size;
  const float* x   = (const float*)d_in[0];
  const float* W   = (const float*)d_in[1];
  const float* Wlw = (const float*)d_in[2];
  float* ws = (float*)d_ws;
  size_t off = 0;
  float* rmsum  = ws + off; off += 32 * 256;
  float* gtsum  = ws + off; off += 32 * 256;
  float* sqrm   = ws + off; off += 32 * 256;
  float* isqrm  = ws + off; off += 32 * 256;
  float* wsqb   = ws + off; off += 256;
  float* isqm   = ws + off; off += 32 * 256;
  float* ltmean = ws + off; off += 32 * D0;
  float* cov    = ws + off; off += (size_t)32 * D0 * D0;
  float* E      = ws + off; off += (size_t)32 * DD * DD;
  float* Bm     = ws + off; off += DD * DD;
  float* Pa     = ws + off; off += DD * DD;
  float* Pb     = ws + off; off += DD * DD;
  float* Rm     = ws + off; off += DD * DD;
  float* xcbuf  = ws + off; off += (size_t)32 * SS * D0;
  float* outp   = (float*)d_out;

  hipMemsetAsync(rmsum, 0, 2 * 32 * 256 * sizeof(float), stream);

  rm_mean_kernel    <<<dim3(25, 32),  256, 0, stream>>>(x, rmsum);
  eigh_rm_kernel    <<<3,             256, 0, stream>>>(rmsum, W, sqrm, isqrm, wsqb);
  pass1_kernel      <<<dim3(200, 32), 256, 0, stream>>>(x, isqrm, gtsum);
  mean_update_kernel<<<2,             256, 0, stream>>>(gtsum, sqrm, isqm, ltmean);
  pass2_kernel      <<<dim3(200, 32), 256, 0, stream>>>(x, isqm, wsqb, xcbuf);
  syrk_kernel       <<<dim3(15, 32),  256, 0, stream>>>(xcbuf, cov);
  ebuild_kernel     <<<32,            256, 0, stream>>>(ltmean, E);
  chol_kernel<D0, 1, 0, 256><<<32,    256, 0, stream>>>(cov, (long)D0 * D0, E, (long)DD * DD, DD);

  // R = chol(expm(sym(W_lw))): scaling 1/8, Taylor order 6 (err ~3e-8), square 3x
  wlw_prep_kernel   <<<(DD * DD + 255) / 256, 256, 0, stream>>>(Wlw, Bm);
  taylor_init_kernel<<<(DD * DD + 255) / 256, 256, 0, stream>>>(Bm, Pa);
  float* Pcur = Pa; float* Pnext = Pb;
  for (int k = 5; k >= 1; --k) {
    gemm152_kernel<<<dim3(100, 1), 256, 0, stream>>>(Bm, 0L, Pcur, Pnext, 0L, 1.f / (float)k, 1);
    float* t = Pcur; Pcur = Pnext; Pnext = t;
  }
  for (int i = 0; i < 3; ++i) {
    gemm152_kernel<<<dim3(100, 1), 256, 0, stream>>>(Pcur, 0L, Pcur, Pnext, 0L, 1.f, 0);
    float* t = Pcur; Pcur = Pnext; Pnext = t;
  }
  chol_kernel<DD, 0, 1, 1024><<<1,   1024, 0, stream>>>(Pcur, 0L, Rm, 0L, DD);

  gemm152_kernel<<<dim3(100, 32), 256, 0, stream>>>(E, (long)DD * DD, Rm, outp, (long)DD * DD, 1.f, 0);
}

// Round 8
// 1503.663 us; speedup vs baseline: 8.7395x; 1.0950x over previous
//
#include <hip/hip_runtime.h>
#include <math.h>

// Problem constants (fixed by setup_inputs)
#define NN   32
#define SS   3200
#define CC   16
#define XLD  20      // row stride (floats) inside a 16x16 matrix slot
#define GSTR 328     // per-group matrix slot stride: bank offsets {0,8,16,24} across groups
#define D0   136     // C*(C+1)/2
#define DD   152     // D0 + k
#define SQRT2F 1.41421356237309515f
#define SW_PASS 4    // retry 4 with the STABLE t-formula (R6 failure was the formula, not sweeps)
#define SW_SMALL 8   // sweeps for the tiny per-n chains

typedef float f2 __attribute__((ext_vector_type(2)));
__device__ __forceinline__ f2 mk2(float x, float y) { f2 r; r.x = x; r.y = y; return r; }

#define PHASE __builtin_amdgcn_sched_barrier(0)

// ---------------- cross-lane xor within 16-lane groups ----------------
template<int M> __device__ __forceinline__ float lxor(float x) {
  int v = __float_as_int(x);
  int r;
  if      constexpr (M == 1)  r = __builtin_amdgcn_update_dpp(0, v, 0xB1, 0xF, 0xF, true);  // quad_perm [1,0,3,2]
  else if constexpr (M == 2)  r = __builtin_amdgcn_update_dpp(0, v, 0x4E, 0xF, 0xF, true);  // quad_perm [2,3,0,1]
  else if constexpr (M == 3)  r = __builtin_amdgcn_update_dpp(0, v, 0x1B, 0xF, 0xF, true);  // quad_perm [3,2,1,0]
  else if constexpr (M == 7)  r = __builtin_amdgcn_update_dpp(0, v, 0x141, 0xF, 0xF, true); // row_half_mirror
  else if constexpr (M == 8)  r = __builtin_amdgcn_update_dpp(0, v, 0x128, 0xF, 0xF, true); // row_ror:8
  else if constexpr (M == 15) r = __builtin_amdgcn_update_dpp(0, v, 0x140, 0xF, 0xF, true); // row_mirror
  else r = __builtin_amdgcn_ds_swizzle(v, 0x1F | (M << 10));                                // BitMode xor
  return __int_as_float(r);
}

// ---------------- one-sided Jacobi round: pairs (i, i^M) ----------------
template<int M>
__device__ __forceinline__ void js_round(f2 a[8], float& d, int c) {
  f2 part[8];
  #pragma unroll
  for (int r = 0; r < 8; ++r) {
    part[r].x = lxor<M>(a[r].x);
    part[r].y = lxor<M>(a[r].y);
  }
  float pd = lxor<M>(d);
  f2 s0 = a[0] * part[0];
  f2 s1 = a[1] * part[1];
  f2 s2 = a[2] * part[2];
  f2 s3 = a[3] * part[3];
  s0 += a[4] * part[4];
  s1 += a[5] * part[5];
  s2 += a[6] * part[6];
  s3 += a[7] * part[7];
  f2 sv = (s0 + s1) + (s2 + s3);
  float apq = sv.x + sv.y;
  int partner = c ^ M;
  bool isp = c < partner;
  float app = isp ? d : pd;
  float aqq = isp ? pd : d;
  // NOTE: keep the rcp form — t = 1/(|θ|+√(θ²+1)). The algebraically-equal
  // √(θ²+1)−|θ| cancels catastrophically at large θ (R6 FAILED: absmax 3.8e-2).
  float theta = (aqq - app) * 0.5f * __builtin_amdgcn_rcpf(apq);
  float t = copysignf(__builtin_amdgcn_rcpf(fabsf(theta) + __builtin_amdgcn_sqrtf(fmaf(theta, theta, 1.f))), theta);
  t = (apq == 0.f) ? 0.f : t;
  float cs = __builtin_amdgcn_rsqf(fmaf(t, t, 1.f));
  float sn = t * cs;
  float se = isp ? -sn : sn;
  f2 pcs = mk2(cs, cs);
  f2 pse = mk2(se, se);
  #pragma unroll
  for (int r = 0; r < 8; ++r) a[r] = pcs * a[r] + pse * part[r];
  d = isp ? (app - t * apq) : (aqq + t * apq);
}

__device__ __forceinline__ void js_sweep(f2 a[8], float& d, int c) {
  js_round<1>(a, d, c);  js_round<2>(a, d, c);  js_round<3>(a, d, c);
  js_round<4>(a, d, c);  js_round<5>(a, d, c);  js_round<6>(a, d, c);
  js_round<7>(a, d, c);  js_round<8>(a, d, c);  js_round<9>(a, d, c);
  js_round<10>(a, d, c); js_round<11>(a, d, c); js_round<12>(a, d, c);
  js_round<13>(a, d, c); js_round<14>(a, d, c); js_round<15>(a, d, c);
}

__device__ __forceinline__ float colnorm2(const f2 a[8]) {
  f2 s0 = a[0] * a[0], s1 = a[1] * a[1], s2 = a[2] * a[2], s3 = a[3] * a[3];
  s0 += a[4] * a[4]; s1 += a[5] * a[5]; s2 += a[6] * a[6]; s3 += a[7] * a[7];
  f2 s = (s0 + s1) + (s2 + s3);
  return s.x + s.y;
}

// a: column c of symmetric M (packed pairs). Exit: a = lam_c * v_c, d = lam_c^2.
__device__ __forceinline__ void jacobi_os(f2 a[8], float& d, int c, int sweeps) {
  d = colnorm2(a);
  #pragma unroll 1
  for (int s = 0; s < sweeps; ++s) js_sweep(a, d, c);
  d = colnorm2(a);
}

// ---------------- row dot: dot(M_row, v) ----------------
__device__ __forceinline__ float dotrow(const float* __restrict__ row, const f2 v[8]) {
  const float4 q0 = *(const float4*)(row + 0);
  const float4 q1 = *(const float4*)(row + 4);
  const float4 q2 = *(const float4*)(row + 8);
  const float4 q3 = *(const float4*)(row + 12);
  f2 s0 = mk2(q0.x, q0.y) * v[0] + mk2(q0.z, q0.w) * v[1];
  f2 s1 = mk2(q1.x, q1.y) * v[2] + mk2(q1.z, q1.w) * v[3];
  s0 += mk2(q2.x, q2.y) * v[4] + mk2(q2.z, q2.w) * v[5];
  s1 += mk2(q3.x, q3.y) * v[6] + mk2(q3.z, q3.w) * v[7];
  f2 s = s0 + s1;
  return s.x + s.y;
}

// y = Mat(16x16, LDS rows stride S) * v  (v, y packed by row pairs)
template<int S>
__device__ __forceinline__ void mv_lds(const float* __restrict__ M, const f2 v[8], f2 y[8]) {
  #pragma unroll
  for (int k = 0; k < 8; ++k) {
    float r0 = dotrow(M + (2 * k) * S, v);
    float r1 = dotrow(M + (2 * k + 1) * S, v);
    y[k] = mk2(r0, r1);
  }
}

// out (packed rows) = col c of Sum_i gb[i] * b_i b_i^T ; B row i = b_i (row stride S)
template<int S>
__device__ __forceinline__ void recon16(const float* __restrict__ B, const float* __restrict__ gb,
                                        int c, f2 o[8]) {
  #pragma unroll
  for (int k = 0; k < 8; ++k) o[k] = mk2(0.f, 0.f);
  #pragma unroll
  for (int i = 0; i < CC; ++i) {
    const float* row = B + i * S;
    float coef = gb[i] * row[c];
    f2 pc = mk2(coef, coef);
    const float4 q0 = *(const float4*)(row + 0);
    const float4 q1 = *(const float4*)(row + 4);
    const float4 q2 = *(const float4*)(row + 8);
    const float4 q3 = *(const float4*)(row + 12);
    o[0] += pc * mk2(q0.x, q0.y); o[1] += pc * mk2(q0.z, q0.w);
    o[2] += pc * mk2(q1.x, q1.y); o[3] += pc * mk2(q1.z, q1.w);
    o[4] += pc * mk2(q2.x, q2.y); o[5] += pc * mk2(q2.z, q2.w);
    o[6] += pc * mk2(q3.x, q3.y); o[7] += pc * mk2(q3.z, q3.w);
  }
}

template<int S>
__device__ __forceinline__ void recon2_16(const float* __restrict__ B, const float* __restrict__ g1,
                                          const float* __restrict__ g2, int c,
                                          f2 o1[8], f2 o2[8]) {
  #pragma unroll
  for (int k = 0; k < 8; ++k) { o1[k] = mk2(0.f, 0.f); o2[k] = mk2(0.f, 0.f); }
  #pragma unroll
  for (int i = 0; i < CC; ++i) {
    const float* row = B + i * S;
    float bic = row[c];
    f2 c1 = mk2(g1[i] * bic, g1[i] * bic);
    f2 c2 = mk2(g2[i] * bic, g2[i] * bic);
    const float4 q0 = *(const float4*)(row + 0);
    const float4 q1 = *(const float4*)(row + 4);
    const float4 q2 = *(const float4*)(row + 8);
    const float4 q3 = *(const float4*)(row + 12);
    f2 b0 = mk2(q0.x, q0.y), b1 = mk2(q0.z, q0.w), b2 = mk2(q1.x, q1.y), b3 = mk2(q1.z, q1.w);
    f2 b4 = mk2(q2.x, q2.y), b5 = mk2(q2.z, q2.w), b6 = mk2(q3.x, q3.y), b7 = mk2(q3.z, q3.w);
    o1[0] += c1 * b0; o1[1] += c1 * b1; o1[2] += c1 * b2; o1[3] += c1 * b3;
    o1[4] += c1 * b4; o1[5] += c1 * b5; o1[6] += c1 * b6; o1[7] += c1 * b7;
    o2[0] += c2 * b0; o2[1] += c2 * b1; o2[2] += c2 * b2; o2[3] += c2 * b3;
    o2[4] += c2 * b4; o2[5] += c2 * b5; o2[6] += c2 * b6; o2[7] += c2 * b7;
  }
}

// stage 4 contiguous 16x16 matrices (1024 floats) from global into XLD/GSTR layout
__device__ __forceinline__ void stage4(const float* __restrict__ src, float* __restrict__ dst, int lid) {
  #pragma unroll
  for (int i = 0; i < 4; ++i) {
    int f = (i * 64 + lid) * 4;       // float index in the contiguous source
    int m = f >> 8, w = f & 255;      // matrix, within-matrix
    *(float4*)(dst + m * GSTR + (w >> 4) * XLD + (w & 15)) = *(const float4*)(src + f);
  }
}

__device__ __forceinline__ void store_rows(float* __restrict__ RBg, int c, const f2 a[8]) {
  #pragma unroll
  for (int i = 0; i < 4; ++i)
    *(float4*)(RBg + c * XLD + 4 * i) = make_float4(a[2 * i].x, a[2 * i].y, a[2 * i + 1].x, a[2 * i + 1].y);
}

__device__ __forceinline__ void load_pairs(const float* __restrict__ src, f2 a[8], float scale) {
  #pragma unroll
  for (int i = 0; i < 4; ++i) {
    float4 v = *(const float4*)(src + 4 * i);
    a[2 * i]     = mk2(v.x * scale, v.y * scale);
    a[2 * i + 1] = mk2(v.z * scale, v.w * scale);
  }
}

__device__ __forceinline__ void store_pairs_g(float* __restrict__ dst, const f2 a[8]) {
  #pragma unroll
  for (int i = 0; i < 4; ++i)
    *(float4*)(dst + 4 * i) = make_float4(a[2 * i].x, a[2 * i].y, a[2 * i + 1].x, a[2 * i + 1].y);
}

// ---------------- Step 1: rm accumulation (float4 loads) ----------------
__global__ __launch_bounds__(256) void rm_mean_kernel(const float* __restrict__ x, float* __restrict__ rmsum) {
  int n = blockIdx.y;
  int tid = threadIdx.x;
  long base = (long)n * SS * 256 + (long)blockIdx.x * 128 * 256 + tid * 4;
  float4 s = make_float4(0.f, 0.f, 0.f, 0.f);
  for (int i = 0; i < 32; ++i) {
    float4 v = *(const float4*)(x + base + (long)i * 1024);
    s.x += v.x; s.y += v.y; s.z += v.z; s.w += v.w;
  }
  int o = (tid * 4) & 255;
  atomicAdd(&rmsum[n * 256 + o],     s.x);
  atomicAdd(&rmsum[n * 256 + o + 1], s.y);
  atomicAdd(&rmsum[n * 256 + o + 2], s.z);
  atomicAdd(&rmsum[n * 256 + o + 3], s.w);
}

// ---------------- Step 2: eigh(rm) -> sq,isq ; Wsq = expm(sym(W)/2) ----------------
__global__ __launch_bounds__(256) void eigh_rm_kernel(const float* __restrict__ rmsum, const float* __restrict__ Wg,
                                                      float* __restrict__ sqrm, float* __restrict__ isqrm,
                                                      float* __restrict__ wsqo) {
  __shared__ __align__(16) float lds[4 * 1440];
  int tid = threadIdx.x;
  int wv = tid >> 6, lid = tid & 63, g = lid >> 4, c = lid & 15;
  float* Wr = lds + wv * 1440;
  float* RB = Wr;                 // 4 x GSTR
  float* G1 = Wr + 4 * GSTR;      // 64
  float* G2 = Wr + 4 * GSTR + 64; // 64
  int gid_raw = blockIdx.x * 16 + wv * 4 + g;
  int gid = gid_raw > 32 ? 32 : gid_raw;
  f2 a[8];
  if (gid < 32) {
    load_pairs(rmsum + gid * 256 + c * 16, a, 1.f / (float)SS);
  } else {
    #pragma unroll
    for (int k = 0; k < 8; ++k) {
      a[k].x = 0.5f * (Wg[c * 16 + 2 * k]     + Wg[(2 * k) * 16 + c]);
      a[k].y = 0.5f * (Wg[c * 16 + 2 * k + 1] + Wg[(2 * k + 1) * 16 + c]);
    }
  }
  // Gershgorin shift (only applied to the possibly-indefinite W matrix)
  float rs = 0.f;
  #pragma unroll
  for (int k = 0; k < 8; ++k) rs += fabsf(a[k].x) + fabsf(a[k].y);
  rs = fmaxf(rs, lxor<1>(rs)); rs = fmaxf(rs, lxor<2>(rs));
  rs = fmaxf(rs, lxor<4>(rs)); rs = fmaxf(rs, lxor<8>(rs));
  float sig = (gid == 32) ? (rs + 0.001f) : 0.f;
  #pragma unroll
  for (int k = 0; k < 8; ++k) {
    a[k].x += (2 * k     == c) ? sig : 0.f;
    a[k].y += (2 * k + 1 == c) ? sig : 0.f;
  }
  float d;
  jacobi_os(a, d, c, SW_SMALL);
  float g1c, g2c;
  if (gid < 32) {
    float sqd = __builtin_amdgcn_sqrtf(d);
    float qd  = __builtin_amdgcn_sqrtf(sqd);            // d^{1/4}
    g1c = qd * __builtin_amdgcn_rcpf(d);                // d^{-3/4}: sqrtm
    g2c = __builtin_amdgcn_rcpf(d * qd);                // d^{-5/4}: invsqrtm
  } else {
    float lam = __builtin_amdgcn_sqrtf(d);
    g1c = __expf(0.5f * (lam - sig)) * __builtin_amdgcn_rcpf(fmaxf(d, 1e-30f));
    g2c = 0.f;
  }
  float* RBg = RB + g * GSTR;
  store_rows(RBg, c, a);
  G1[g * 16 + c] = g1c;
  G2[g * 16 + c] = g2c;
  __builtin_amdgcn_wave_barrier();
  f2 o1[8], o2[8];
  recon2_16<XLD>(RBg, G1 + g * 16, G2 + g * 16, c, o1, o2);
  if (gid_raw < 32) {
    store_pairs_g(sqrm  + gid * 256 + c * 16, o1);
    store_pairs_g(isqrm + gid * 256 + c * 16, o2);
  } else if (gid_raw == 32) {
    store_pairs_g(wsqo + c * 16, o1);
  }
}

// ---------------- Step 3: pass 1 — sum_s logm(isq_rm X isq_rm) ----------------
#define WSZ1 (4 * GSTR + XLD * 16 + 64)   // 1696
__global__ __launch_bounds__(256) __attribute__((amdgpu_num_vgpr(128)))
void pass1_kernel(const float* __restrict__ x, const float* __restrict__ isqrm,
                  float* __restrict__ gtsum) {
  __shared__ __align__(16) float lds[4 * WSZ1 + 1024];
  int tid = threadIdx.x;
  int wv = tid >> 6, lid = tid & 63, g = lid >> 4, c = lid & 15;
  int n = blockIdx.y;
  int s_base = blockIdx.x * 16 + wv * 4;
  float* Wr  = lds + wv * WSZ1;
  float* Xs  = Wr;                      // 4 x GSTR; reused as recon buf
  float* ISQ = Wr + 4 * GSTR;           // 16 x XLD
  float* GB  = Wr + 4 * GSTR + XLD * 16;// 64
  float* red = lds + 4 * WSZ1;          // 1024 (cross-wave reduce)
  stage4(x + ((long)n * SS + s_base) * 256, Xs, lid);
  const float* isqn = isqrm + n * 256;
  for (int i = lid; i < 256; i += 64) ISQ[(i >> 4) * XLD + (i & 15)] = isqn[i];
  __builtin_amdgcn_wave_barrier();
  PHASE;
  f2 mc[8], y[8], a[8];
  load_pairs(ISQ + c * XLD, mc, 1.f);
  mv_lds<XLD>(Xs + g * GSTR, mc, y);
  mv_lds<XLD>(ISQ, y, a);
  PHASE;
  float d;
  jacobi_os(a, d, c, SW_PASS);
  PHASE;
  float gc = 0.5f * __logf(fmaxf(d, 1e-30f)) * __builtin_amdgcn_rcpf(d);
  float* RBg = Xs + g * GSTR;   // X is dead; reuse
  store_rows(RBg, c, a);
  GB[g * 16 + c] = gc;
  __builtin_amdgcn_wave_barrier();
  PHASE;
  f2 out[8];
  recon16<XLD>(RBg, GB + g * 16, c, out);
  PHASE;
  #pragma unroll
  for (int k = 0; k < 8; ++k) {
    out[k].x += __shfl_xor(out[k].x, 16);
    out[k].y += __shfl_xor(out[k].y, 16);
  }
  #pragma unroll
  for (int k = 0; k < 8; ++k) {
    out[k].x += __shfl_xor(out[k].x, 32);
    out[k].y += __shfl_xor(out[k].y, 32);
  }
  if (g == 0) store_pairs_g(red + wv * 256 + c * 16, out);
  __syncthreads();
  float v = red[tid] + red[256 + tid] + red[512 + tid] + red[768 + tid];
  atomicAdd(&gtsum[n * 256 + tid], v);
}

// ---------------- Step 4: x_mean chain -> isq_m, lt_mean ----------------
#define WSZ4 (8 * GSTR + 128)   // 2752
__global__ __launch_bounds__(256) void mean_update_kernel(const float* __restrict__ gtsum, const float* __restrict__ sqrm,
                                                          float* __restrict__ isqm, float* __restrict__ ltmean) {
  __shared__ __align__(16) float lds[4 * WSZ4];
  int tid = threadIdx.x;
  int wv = tid >> 6, lid = tid & 63, g = lid >> 4, c = lid & 15;
  int n0 = blockIdx.x * 16 + wv * 4 + g;
  float* Wr = lds + wv * WSZ4;
  float* RB = Wr;                  // 4 x GSTR
  float* SQ = Wr + 4 * GSTR;       // 4 x GSTR
  float* G1 = Wr + 8 * GSTR;       // 64
  float* G2 = Wr + 8 * GSTR + 64;  // 64
  // ---- eigh(gt) (indefinite -> shift), expm ----
  f2 a[8];
  load_pairs(gtsum + n0 * 256 + c * 16, a, 1.f / (float)SS);
  float rs = 0.f;
  #pragma unroll
  for (int k = 0; k < 8; ++k) rs += fabsf(a[k].x) + fabsf(a[k].y);
  rs = fmaxf(rs, lxor<1>(rs)); rs = fmaxf(rs, lxor<2>(rs));
  rs = fmaxf(rs, lxor<4>(rs)); rs = fmaxf(rs, lxor<8>(rs));
  float sig = rs + 0.001f;
  #pragma unroll
  for (int k = 0; k < 8; ++k) {
    a[k].x += (2 * k     == c) ? sig : 0.f;
    a[k].y += (2 * k + 1 == c) ? sig : 0.f;
  }
  float d;
  jacobi_os(a, d, c, SW_SMALL);
  float lam = __builtin_amdgcn_sqrtf(d);
  float gc = __expf(lam - sig) * __builtin_amdgcn_rcpf(fmaxf(d, 1e-30f));
  float* RBg = RB + g * GSTR;
  store_rows(RBg, c, a);
  G1[g * 16 + c] = gc;
  __builtin_amdgcn_wave_barrier();
  f2 e1[8];
  recon16<XLD>(RBg, G1 + g * 16, c, e1);
  // ---- stage sq_rm (4 consecutive n for this wave) ----
  stage4(sqrm + (blockIdx.x * 16 + wv * 4) * 256, SQ, lid);
  __builtin_amdgcn_wave_barrier();
  store_rows(RBg, c, e1);
  __builtin_amdgcn_wave_barrier();
  float* SQg = SQ + g * GSTR;
  f2 mc[8], y[8], a2[8];
  load_pairs(SQg + c * XLD, mc, 1.f);
  mv_lds<XLD>(RBg, mc, y);    // expm(gt) * sq_col
  mv_lds<XLD>(SQg, y, a2);    // sq * y -> col c of x_mean
  float d2;
  jacobi_os(a2, d2, c, SW_SMALL);
  float sqd = __builtin_amdgcn_sqrtf(d2);
  float qd  = __builtin_amdgcn_sqrtf(sqd);
  float g1c = __builtin_amdgcn_rcpf(d2 * qd);                                  // d^{-5/4}: invsqrtm
  float g2c = 0.5f * __logf(fmaxf(d2, 1e-30f)) * __builtin_amdgcn_rcpf(d2);   // logm
  store_rows(RBg, c, a2);
  G1[g * 16 + c] = g1c;
  G2[g * 16 + c] = g2c;
  __builtin_amdgcn_wave_barrier();
  f2 o1[8], o2[8];
  recon2_16<XLD>(RBg, G1 + g * 16, G2 + g * 16, c, o1, o2);
  store_pairs_g(isqm + n0 * 256 + c * 16, o1);
  #pragma unroll
  for (int k = 0; k < 8; ++k) {
    int r0 = 2 * k, r1 = 2 * k + 1;
    if (r0 >= c) ltmean[n0 * D0 + (r0 * (r0 + 1) / 2) + c] = o2[k].x * ((r0 == c) ? 1.f : SQRT2F);
    if (r1 >= c) ltmean[n0 * D0 + (r1 * (r1 + 1) / 2) + c] = o2[k].y * ((r1 == c) ? 1.f : SQRT2F);
  }
}

// ---------------- Step 5: pass 2 — xc = tril(Wsq logm(isq_m X isq_m) Wsq) ----------------
#define WSZ2 (4 * GSTR + 2 * XLD * 16 + 64)   // 2016
__global__ __launch_bounds__(256) __attribute__((amdgpu_num_vgpr(128)))
void pass2_kernel(const float* __restrict__ x, const float* __restrict__ isqm,
                  const float* __restrict__ wsqg, float* __restrict__ xc) {
  __shared__ __align__(16) float lds[4 * WSZ2];
  int tid = threadIdx.x;
  int wv = tid >> 6, lid = tid & 63, g = lid >> 4, c = lid & 15;
  int n = blockIdx.y;
  int s_base = blockIdx.x * 16 + wv * 4;
  float* Wr  = lds + wv * WSZ2;
  float* Xs  = Wr;                           // 4 x GSTR; reused as recon buf
  float* ISQ = Wr + 4 * GSTR;                // 16 x XLD
  float* WSQ = Wr + 4 * GSTR + XLD * 16;     // 16 x XLD
  float* GB  = Wr + 4 * GSTR + 2 * XLD * 16; // 64
  stage4(x + ((long)n * SS + s_base) * 256, Xs, lid);
  const float* isqn = isqm + n * 256;
  for (int i = lid; i < 256; i += 64) {
    int r = i >> 4, cc = i & 15;
    ISQ[r * XLD + cc] = isqn[i];
    WSQ[r * XLD + cc] = wsqg[i];
  }
  __builtin_amdgcn_wave_barrier();
  PHASE;
  f2 mc[8], y[8], a[8];
  load_pairs(ISQ + c * XLD, mc, 1.f);
  mv_lds<XLD>(Xs + g * GSTR, mc, y);
  mv_lds<XLD>(ISQ, y, a);
  PHASE;
  float d;
  jacobi_os(a, d, c, SW_PASS);
  PHASE;
  float gc = 0.5f * __logf(fmaxf(d, 1e-30f)) * __builtin_amdgcn_rcpf(d);
  f2 b[8];
  mv_lds<XLD>(WSQ, a, b);   // fold outer Wsq sandwich into the recon columns
  float* RBg = Xs + g * GSTR;
  store_rows(RBg, c, b);
  GB[g * 16 + c] = gc;
  __builtin_amdgcn_wave_barrier();
  PHASE;
  f2 out[8];
  recon16<XLD>(RBg, GB + g * 16, c, out);
  PHASE;
  long ob = ((long)n * SS + s_base + g) * (long)D0;
  #pragma unroll
  for (int k = 0; k < 8; ++k) {
    int r0 = 2 * k, r1 = 2 * k + 1;
    if (r0 >= c) xc[ob + (r0 * (r0 + 1) / 2) + c] = out[k].x * ((r0 == c) ? 1.f : SQRT2F);
    if (r1 >= c) xc[ob + (r1 * (r1 + 1) / 2) + c] = out[k].y * ((r1 == c) ? 1.f : SQRT2F);
  }
}

// ---------------- Step 6: covariance SYRK — 64x64 tiles, 4x4 per-thread ----------------
__global__ __launch_bounds__(256) void syrk_kernel(const float* __restrict__ xc, float* __restrict__ cov) {
  __shared__ float Ap[32][68];
  __shared__ float Bp[32][68];
  const int TI[6] = {0,0,0,1,1,2};
  const int TJ[6] = {0,1,2,1,2,2};
  int n = blockIdx.y;
  int ti = TI[blockIdx.x], tj = TJ[blockIdx.x];
  int tid = threadIdx.x;
  int tx = tid & 15, ty = tid >> 4;
  float acc[4][4] = {{0.f}};
  const float* xb = xc + (long)n * SS * D0;
  for (int s0 = 0; s0 < SS; s0 += 32) {
    #pragma unroll
    for (int i = 0; i < 2; ++i) {
      int idx = tid + i * 256;          // 0..511 (512 float4 per tile)
      int ss = idx >> 4;                // 0..31
      int c4 = (idx & 15) * 4;          // 0..60
      const float* row = xb + (long)(s0 + ss) * D0;
      int gi = ti * 64 + c4;
      int gj = tj * 64 + c4;
      float4 av = (gi + 4 <= D0) ? *(const float4*)(row + gi) : make_float4(0.f, 0.f, 0.f, 0.f);
      float4 bv = (gj + 4 <= D0) ? *(const float4*)(row + gj) : make_float4(0.f, 0.f, 0.f, 0.f);
      *(float4*)&Ap[ss][c4] = av;
      *(float4*)&Bp[ss][c4] = bv;
    }
    __syncthreads();
    #pragma unroll 8
    for (int ss = 0; ss < 32; ++ss) {
      float4 a4 = *(const float4*)&Ap[ss][ty * 4];
      float4 b4 = *(const float4*)&Bp[ss][tx * 4];
      acc[0][0] += a4.x * b4.x; acc[0][1] += a4.x * b4.y; acc[0][2] += a4.x * b4.z; acc[0][3] += a4.x * b4.w;
      acc[1][0] += a4.y * b4.x; acc[1][1] += a4.y * b4.y; acc[1][2] += a4.y * b4.z; acc[1][3] += a4.y * b4.w;
      acc[2][0] += a4.z * b4.x; acc[2][1] += a4.z * b4.y; acc[2][2] += a4.z * b4.z; acc[2][3] += a4.z * b4.w;
      acc[3][0] += a4.w * b4.x; acc[3][1] += a4.w * b4.y; acc[3][2] += a4.w * b4.z; acc[3][3] += a4.w * b4.w;
    }
    __syncthreads();
  }
  const float sc = 1.f / (float)(SS - 1);
  long base = (long)n * D0 * D0;
  #pragma unroll
  for (int r = 0; r < 4; ++r) {
    #pragma unroll
    for (int c = 0; c < 4; ++c) {
      int i = ti * 64 + ty * 4 + r;
      int j = tj * 64 + tx * 4 + c;
      if (i < D0 && j < D0) {
        cov[base + (long)i * D0 + j] = acc[r][c] * sc;
        if (ti != tj) cov[base + (long)j * D0 + i] = acc[r][c] * sc;
      }
    }
  }
}

// ---------------- Cholesky (triangular LDS storage); EMB: also build E skeleton ----------------
template<int D, int NORM, int WRITE_UPPER, int EMB, int THREADS>
__global__ __launch_bounds__(THREADS) void chol_kernel(const float* __restrict__ in, long inStride,
                                                       float* __restrict__ out, long outStride, int outLd,
                                                       const float* __restrict__ ltmean) {
  __shared__ float As[D * (D + 1) / 2];
  __shared__ float red[THREADS];
  int b = blockIdx.x;
  int tid = threadIdx.x;
  const float* inp = in + (long)b * inStride;
  for (int idx = tid; idx < D * D; idx += THREADS) {
    int r = idx / D, c2 = idx % D;
    if (c2 <= r) As[(r * (r + 1) / 2) + c2] = inp[idx];
  }
  __syncthreads();
  if (NORM) {
    float p = 0.f;
    for (int i = tid; i < D; i += THREADS) p += As[(i * (i + 1) / 2) + i];
    red[tid] = p;
    __syncthreads();
    for (int off = THREADS / 2; off >= 1; off >>= 1) {
      if (tid < off) red[tid] += red[tid + off];
      __syncthreads();
    }
    float inv = 1.f / red[0];
    for (int idx = tid; idx < D * (D + 1) / 2; idx += THREADS) As[idx] *= inv;
    __syncthreads();
    for (int i = tid; i < D; i += THREADS) As[(i * (i + 1) / 2) + i] += 1e-5f;
    __syncthreads();
  }
  const int TY = THREADS / 16;
  int tx = tid & 15, ty = tid >> 4;
  for (int k = 0; k < D; ++k) {
    float dkk = As[(k * (k + 1) / 2) + k];
    float dv = sqrtf(dkk);
    float invd = 1.f / dv;
    __syncthreads();
    for (int i = k + 1 + tid; i < D; i += THREADS) As[(i * (i + 1) / 2) + k] *= invd;
    if (tid == 0) As[(k * (k + 1) / 2) + k] = dv;
    __syncthreads();
    for (int i = k + 1 + ty; i < D; i += TY) {
      float aik = As[(i * (i + 1) / 2) + k];
      int ibase = i * (i + 1) / 2;
      for (int j = k + 1 + tx; j <= i; j += 16) {
        As[ibase + j] -= aik * As[(j * (j + 1) / 2) + k];
      }
    }
    __syncthreads();
  }
  float* op = out + (long)b * outStride;
  for (int idx = tid; idx < D * D; idx += THREADS) {
    int r = idx / D, c2 = idx % D;
    if (c2 <= r)          op[r * outLd + c2] = As[(r * (r + 1) / 2) + c2];
    else if (WRITE_UPPER) op[r * outLd + c2] = 0.f;
    else                  op[r * outLd + c2] = 0.f;   // zero upper triangle of the D-block
  }
  if (EMB) {
    // E skeleton: cols D0..DD-1 for rows<D0 are 0; rows D0..DD-1 = [ltmean | I_k]
    const float* ltm = ltmean + b * D0;
    for (int idx = tid; idx < D0 * (DD - D0); idx += THREADS) {
      int r = idx / (DD - D0), c2 = D0 + idx % (DD - D0);
      op[r * outLd + c2] = 0.f;
    }
    for (int idx = tid; idx < (DD - D0) * DD; idx += THREADS) {
      int r = D0 + idx / DD, c2 = idx % DD;
      op[r * outLd + c2] = (c2 < D0) ? ltm[c2] : ((r == c2) ? 1.f : 0.f);
    }
  }
}

// ---------------- 152x152 GEMM: C = alpha*A@B (+I) (+Cadd) ----------------
__global__ __launch_bounds__(256) void gemm152_kernel(const float* __restrict__ A, long sA,
                                                      const float* __restrict__ B, float* __restrict__ Cm,
                                                      long sC, float alpha, int addI,
                                                      const float* __restrict__ Cadd) {
  __shared__ float As[16][17];
  __shared__ float Bs[16][17];
  int b = blockIdx.y;
  const float* Ab_ = A + (long)b * sA;
  float* Cb = Cm + (long)b * sC;
  int tid = threadIdx.x;
  int tx = tid & 15, ty = tid >> 4;
  int row0 = (blockIdx.x / 10) * 16, col0 = (blockIdx.x % 10) * 16;
  float acc = 0.f;
  for (int k0 = 0; k0 < DD; k0 += 16) {
    int ar = row0 + ty, ac = k0 + tx;
    As[ty][tx] = (ar < DD && ac < DD) ? Ab_[ar * DD + ac] : 0.f;
    int br = k0 + ty, bc = col0 + tx;
    Bs[ty][tx] = (br < DD && bc < DD) ? B[br * DD + bc] : 0.f;
    __syncthreads();
    #pragma unroll
    for (int kk = 0; kk < 16; ++kk) acc += As[ty][kk] * Bs[kk][tx];
    __syncthreads();
  }
  int r = row0 + ty, c2 = col0 + tx;
  if (r < DD && c2 < DD) {
    float v = alpha * acc + ((addI && r == c2) ? 1.f : 0.f);
    if (Cadd) v += Cadd[r * DD + c2];
    Cb[r * DD + c2] = v;
  }
}

__global__ __launch_bounds__(256) void wlw_prep_kernel(const float* __restrict__ Wlw, float* __restrict__ Bm) {
  int idx = blockIdx.x * 256 + threadIdx.x;
  if (idx < DD * DD) {
    int r = idx / DD, c = idx % DD;
    Bm[idx] = 0.5f * (Wlw[idx] + Wlw[c * DD + r]) * (1.f / 8.f);
  }
}

// Rq = B/24 + A2/120 + A3/720 ; Cd = I + B + A2/2 + A3/6   (Paterson-Stockmeyer deg-6)
__global__ __launch_bounds__(256) void ps_combo_kernel(const float* __restrict__ Bm, const float* __restrict__ A2,
                                                       const float* __restrict__ A3, float* __restrict__ Rq,
                                                       float* __restrict__ Cd) {
  int idx = blockIdx.x * 256 + threadIdx.x;
  if (idx < DD * DD) {
    int r = idx / DD, c = idx % DD;
    float bm = Bm[idx], a2 = A2[idx], a3 = A3[idx];
    Rq[idx] = bm * (1.f / 24.f) + a2 * (1.f / 120.f) + a3 * (1.f / 720.f);
    Cd[idx] = ((r == c) ? 1.f : 0.f) + bm + a2 * 0.5f + a3 * (1.f / 6.f);
  }
}

extern "C" void kernel_launch(void* const* d_in, const int* in_sizes, int n_in,
                              void* d_out, int out_size, void* d_ws, size_t ws_size,
                              hipStream_t stream) {
  (void)in_sizes; (void)n_in; (void)out_size; (void)ws_size;
  const float* x   = (const float*)d_in[0];
  const float* W   = (const float*)d_in[1];
  const float* Wlw = (const float*)d_in[2];
  float* ws = (float*)d_ws;
  size_t off = 0;
  float* rmsum  = ws + off; off += 32 * 256;
  float* gtsum  = ws + off; off += 32 * 256;
  float* sqrm   = ws + off; off += 32 * 256;
  float* isqrm  = ws + off; off += 32 * 256;
  float* wsqb   = ws + off; off += 256;
  float* isqm   = ws + off; off += 32 * 256;
  float* ltmean = ws + off; off += 32 * D0;
  float* cov    = ws + off; off += (size_t)32 * D0 * D0;
  float* E      = ws + off; off += (size_t)32 * DD * DD;
  float* Bm     = ws + off; off += DD * DD;
  float* A2     = ws + off; off += DD * DD;
  float* A3     = ws + off; off += DD * DD;
  float* Rq     = ws + off; off += DD * DD;
  float* Cd     = ws + off; off += DD * DD;
  float* P1     = ws + off; off += DD * DD;
  float* P2     = ws + off; off += DD * DD;
  float* Rm     = ws + off; off += DD * DD;
  float* xcbuf  = ws + off; off += (size_t)32 * SS * D0;
  float* outp   = (float*)d_out;

  hipMemsetAsync(rmsum, 0, 2 * 32 * 256 * sizeof(float), stream);

  rm_mean_kernel    <<<dim3(25, 32),  256, 0, stream>>>(x, rmsum);
  eigh_rm_kernel    <<<3,             256, 0, stream>>>(rmsum, W, sqrm, isqrm, wsqb);
  pass1_kernel      <<<dim3(200, 32), 256, 0, stream>>>(x, isqrm, gtsum);
  mean_update_kernel<<<2,             256, 0, stream>>>(gtsum, sqrm, isqm, ltmean);
  pass2_kernel      <<<dim3(200, 32), 256, 0, stream>>>(x, isqm, wsqb, xcbuf);
  syrk_kernel       <<<dim3(6, 32),   256, 0, stream>>>(xcbuf, cov);
  chol_kernel<D0, 1, 0, 1, 256><<<32, 256, 0, stream>>>(cov, (long)D0 * D0, E, (long)DD * DD, DD, ltmean);

  // R = chol(expm(sym(W_lw))): scale 1/8, Paterson-Stockmeyer deg-6 (3 GEMMs), square 3x
  wlw_prep_kernel <<<(DD * DD + 255) / 256, 256, 0, stream>>>(Wlw, Bm);
  gemm152_kernel  <<<dim3(100, 1), 256, 0, stream>>>(Bm, 0L, Bm, A2, 0L, 1.f, 0, nullptr);   // A2 = B^2
  gemm152_kernel  <<<dim3(100, 1), 256, 0, stream>>>(Bm, 0L, A2, A3, 0L, 1.f, 0, nullptr);   // A3 = B^3
  ps_combo_kernel <<<(DD * DD + 255) / 256, 256, 0, stream>>>(Bm, A2, A3, Rq, Cd);
  gemm152_kernel  <<<dim3(100, 1), 256, 0, stream>>>(A3, 0L, Rq, P1, 0L, 1.f, 0, Cd);        // P = Cd + A3@Rq
  gemm152_kernel  <<<dim3(100, 1), 256, 0, stream>>>(P1, 0L, P1, P2, 0L, 1.f, 0, nullptr);   // square x3
  gemm152_kernel  <<<dim3(100, 1), 256, 0, stream>>>(P2, 0L, P2, P1, 0L, 1.f, 0, nullptr);
  gemm152_kernel  <<<dim3(100, 1), 256, 0, stream>>>(P1, 0L, P1, P2, 0L, 1.f, 0, nullptr);
  chol_kernel<DD, 0, 1, 0, 1024><<<1, 1024, 0, stream>>>(P2, 0L, Rm, 0L, DD, nullptr);

  gemm152_kernel  <<<dim3(100, 32), 256, 0, stream>>>(E, (long)DD * DD, Rm, outp, (long)DD * DD, 1.f, 0, nullptr);
}